// Round 5
// baseline (427.274 us; speedup 1.0000x reference)
//
#include <hip/hip_runtime.h>
#include <math.h>

// Problem constants (B=2, L=2048, D=1024, H=16, FACTOR=5)
#define B_ 2
#define L_ 2048
#define D_ 1024
#define H_ 16
#define DH_ 64
#define U_ 40
#define SCALE_ 0.125f

typedef __attribute__((ext_vector_type(8))) short short8v;            // 8 bf16
typedef __attribute__((ext_vector_type(4))) float f32x4;
typedef __attribute__((ext_vector_type(4))) unsigned short ushort4v;  // 8 B

static __device__ __forceinline__ unsigned short bf16_rne(float f) {
  unsigned int u = __float_as_uint(f);
  u += 0x7fff + ((u >> 16) & 1);
  return (unsigned short)(u >> 16);
}
static __device__ __forceinline__ float bf16_f32(unsigned short h) {
  return __uint_as_float(((unsigned int)h) << 16);
}

// ---------------------------------------------------------------------------
// Pre-split f32 -> (hi,lo) bf16 for W=[Wq;Wkv] (quads [0,nW)) and X (rest).
// ---------------------------------------------------------------------------
__global__ __launch_bounds__(256) void split_all(
    const float* __restrict__ Wq, const float* __restrict__ Wkv,
    const float* __restrict__ X, unsigned short* __restrict__ Whi,
    unsigned short* __restrict__ Wlo, unsigned short* __restrict__ Xhi,
    unsigned short* __restrict__ Xlo, int nW) {
  int i = blockIdx.x * 256 + threadIdx.x;
  const int nq_q = (D_ * D_) / 4;
  float4 v;
  unsigned short *hi, *lo;
  int off;
  if (i < nW) {
    v = (i < nq_q) ? ((const float4*)Wq)[i] : ((const float4*)Wkv)[i - nq_q];
    hi = Whi; lo = Wlo; off = i;
  } else {
    off = i - nW;
    v = ((const float4*)X)[off];
    hi = Xhi; lo = Xlo;
  }
  float vv[4] = {v.x, v.y, v.z, v.w};
  ushort4v h, l;
#pragma unroll
  for (int e = 0; e < 4; ++e) {
    unsigned short hh = bf16_rne(vv[e]);
    h[e] = hh;
    l[e] = bf16_rne(vv[e] - bf16_f32(hh));
  }
  ((ushort4v*)hi)[off] = h;
  ((ushort4v*)lo)[off] = l;
}

// ---------------------------------------------------------------------------
// Split-bf16 MFMA GEMM for QKV: C = X @ W^T + bias, M=4096 N=3072 K=1024.
// 128x128 tile, BK=32, 4 waves. Staging task = (row, 16B-seg): each 16-lane
// phase covers every bank exactly 2x (conflict-free ds_write_b128).
// ---------------------------------------------------------------------------
template <bool XS>
__global__ __launch_bounds__(256) void gemm_qkv_mfma(
    const float* __restrict__ X,
    const unsigned short* __restrict__ Xhi,
    const unsigned short* __restrict__ Xlo,
    const unsigned short* __restrict__ Whi,
    const unsigned short* __restrict__ Wlo,
    const float* __restrict__ bq, const float* __restrict__ bkv,
    float* __restrict__ Qo, float* __restrict__ Ko, float* __restrict__ Vo) {
  __shared__ unsigned short As[128][72];
  __shared__ unsigned short Bs[128][72];
  const int tid = threadIdx.x;
  const int lane = tid & 63;
  const int wave = tid >> 6;
  const int wm = wave >> 1, wn = wave & 1;
  const int row0 = blockIdx.y * 128;
  const int col0 = blockIdx.x * 128;

  f32x4 acc[4][4] = {};

  // 1024 segment-tasks per operand: r = task>>3 (0..127), seg = task&7
  // (seg<4 -> hi halves cols 0..31, seg>=4 -> lo halves cols 32..63).
  const unsigned short* srcA[4];
  const float* srcAf[4];
  bool loA[4];
  const unsigned short* srcB[4];
  unsigned short* dstA[4];
  unsigned short* dstB[4];
#pragma unroll
  for (int rep = 0; rep < 4; ++rep) {
    int task = tid + rep * 256;
    int r = task >> 3, seg = task & 7;
    size_t aoff = (size_t)(row0 + r) * D_ + (seg & 3) * 8;
    if (XS) {
      srcA[rep] = ((seg < 4) ? Xhi : Xlo) + aoff;
      srcAf[rep] = 0;
    } else {
      srcAf[rep] = X + aoff;
      srcA[rep] = 0;
    }
    loA[rep] = seg >= 4;
    srcB[rep] = ((seg < 4) ? Whi : Wlo) + (size_t)(col0 + r) * D_ +
                (seg & 3) * 8;
    dstA[rep] = &As[r][seg * 8];
    dstB[rep] = &Bs[r][seg * 8];
  }

  for (int k0 = 0; k0 < D_; k0 += 32) {
#pragma unroll
    for (int rep = 0; rep < 4; ++rep) {
      short8v a;
      if (XS) {
        a = *(const short8v*)(srcA[rep] + k0);
      } else {
        float4 a0 = *(const float4*)(srcAf[rep] + k0);
        float4 a1 = *(const float4*)(srcAf[rep] + k0 + 4);
        float av[8] = {a0.x, a0.y, a0.z, a0.w, a1.x, a1.y, a1.z, a1.w};
#pragma unroll
        for (int i = 0; i < 8; ++i) {
          unsigned short h = bf16_rne(av[i]);
          a[i] = loA[rep] ? (short)bf16_rne(av[i] - bf16_f32(h)) : (short)h;
        }
      }
      short8v b = *(const short8v*)(srcB[rep] + k0);
      *(short8v*)dstA[rep] = a;
      *(short8v*)dstB[rep] = b;
    }
    __syncthreads();

    short8v af[4][2], bf[4][2];
#pragma unroll
    for (int mi = 0; mi < 4; ++mi) {
      int rr = wm * 64 + mi * 16 + (lane & 15);
      int hs = lane >> 4;
      af[mi][0] = *(const short8v*)&As[rr][hs * 8];
      af[mi][1] = *(const short8v*)&As[rr][32 + hs * 8];
    }
#pragma unroll
    for (int ni = 0; ni < 4; ++ni) {
      int rr = wn * 64 + ni * 16 + (lane & 15);
      int hs = lane >> 4;
      bf[ni][0] = *(const short8v*)&Bs[rr][hs * 8];
      bf[ni][1] = *(const short8v*)&Bs[rr][32 + hs * 8];
    }
#pragma unroll
    for (int mi = 0; mi < 4; ++mi)
#pragma unroll
      for (int ni = 0; ni < 4; ++ni) {
        acc[mi][ni] = __builtin_amdgcn_mfma_f32_16x16x32_bf16(
            af[mi][0], bf[ni][0], acc[mi][ni], 0, 0, 0);
        acc[mi][ni] = __builtin_amdgcn_mfma_f32_16x16x32_bf16(
            af[mi][0], bf[ni][1], acc[mi][ni], 0, 0, 0);
        acc[mi][ni] = __builtin_amdgcn_mfma_f32_16x16x32_bf16(
            af[mi][1], bf[ni][0], acc[mi][ni], 0, 0, 0);
      }
    __syncthreads();
  }

  // Epilogue: C/D layout col=lane&15, row=(lane>>4)*4+reg.
#pragma unroll
  for (int ni = 0; ni < 4; ++ni) {
    int c = col0 + wn * 64 + ni * 16 + (lane & 15);
    int which = c >> 10;
    int jj = c & (D_ - 1);
    int h = jj >> 6, dh = jj & 63;
    float bias = (c < D_) ? bq[c] : bkv[c - D_];
    float* dst = (which == 0) ? Qo : ((which == 1) ? Ko : Vo);
#pragma unroll
    for (int mi = 0; mi < 4; ++mi) {
#pragma unroll
      for (int reg = 0; reg < 4; ++reg) {
        int r = row0 + wm * 64 + mi * 16 + ((lane >> 4) << 2) + reg;
        int b = r >> 11, l = r & (L_ - 1);
        dst[(((size_t)b * H_ + h) * L_ + l) * DH_ + dh] =
            acc[mi][ni][reg] + bias;
      }
    }
  }
}

// ---------------------------------------------------------------------------
// M[b,h,l] = max_u(QK) - mean_u(QK). Wave per l; 40 K-rows staged into LDS
// COALESCED (lane=d), then lane=u computes its dot from LDS (pad 65 ->
// conflict-free). Replaces the 40-line-per-instruction gather pattern.
// ---------------------------------------------------------------------------
__global__ __launch_bounds__(256) void sample_m(
    const float* __restrict__ Q, const float* __restrict__ Kt,
    const int* __restrict__ idx, float* __restrict__ Mv) {
  __shared__ float Kst[4][U_][65];
  __shared__ float qs[4][DH_];
  int w = threadIdx.x >> 6, lane = threadIdx.x & 63;
  int gl = blockIdx.x * 4 + w;  // bh*L + l
  int bh = gl >> 11, l = gl & (L_ - 1);
  const float* Kb = Kt + (size_t)bh * L_ * DH_;
  qs[w][lane] = Q[(size_t)gl * DH_ + lane];
  const int* irow = idx + l * U_;
  int kls[U_];
#pragma unroll
  for (int u = 0; u < U_; ++u) kls[u] = irow[u];
#pragma unroll 8
  for (int u = 0; u < U_; ++u)
    Kst[w][u][lane] = Kb[(size_t)kls[u] * DH_ + lane];
  __syncthreads();
  float mx = -INFINITY, sm = 0.f;
  if (lane < U_) {
    const float* kr = Kst[w][lane];
    const float* qq = qs[w];
    float d = 0.f;
#pragma unroll
    for (int i = 0; i < DH_; ++i) d += qq[i] * kr[i];
    mx = d;
    sm = d;
  }
#pragma unroll
  for (int off = 1; off < 64; off <<= 1) {
    mx = fmaxf(mx, __shfl_xor(mx, off));
    sm += __shfl_xor(sm, off);
  }
  if (lane == 0) Mv[gl] = mx - sm * (1.0f / U_);
}

// ---------------------------------------------------------------------------
// Per-(b,h) top-U_ of M: ONE WAVE per bh, shfl-only argmax (no barriers).
// Min-index tie-break matches jax.lax.top_k's selected set.
// ---------------------------------------------------------------------------
__global__ __launch_bounds__(256) void topk_kernel(
    const float* __restrict__ Mv, int* __restrict__ topIdx) {
  __shared__ float vals[4][L_];
  int w = threadIdx.x >> 6, lane = threadIdx.x & 63;
  int bh = blockIdx.x * 4 + w;
  for (int j = 0; j < 32; ++j)
    vals[w][j * 64 + lane] = Mv[(size_t)bh * L_ + j * 64 + lane];
  for (int it = 0; it < U_; ++it) {
    float bv = -INFINITY;
    int bi = 0x7fffffff;
    for (int j = 0; j < 32; ++j) {
      int i = j * 64 + lane;
      float v = vals[w][i];
      if (v > bv) { bv = v; bi = i; }  // j ascending -> ties keep lower index
    }
#pragma unroll
    for (int off = 32; off > 0; off >>= 1) {
      float ov = __shfl_xor(bv, off);
      int oi = __shfl_xor(bi, off);
      if (ov > bv || (ov == bv && oi < bi)) { bv = ov; bi = oi; }
    }
    if (lane == 0) {
      topIdx[bh * U_ + it] = bi;
      vals[w][bi] = -INFINITY;
    }
  }
}

// ---------------------------------------------------------------------------
// scores[bh][q][k] = scale * Qtop[q] . K[k]. Thread = one key, acc[40] regs.
// ---------------------------------------------------------------------------
__global__ __launch_bounds__(256) void score_kernel(
    const float* __restrict__ Q, const float* __restrict__ Kt,
    const int* __restrict__ topIdx, float* __restrict__ S) {
  int kc = blockIdx.x, bh = blockIdx.y;
  int t = threadIdx.x;
  __shared__ float Qs[U_][DH_];
  for (int task = t; task < U_ * 16; task += 256) {
    int q = task >> 4, c4 = task & 15;
    int ql = topIdx[bh * U_ + q];
    *(float4*)&Qs[q][c4 * 4] =
        *(const float4*)&Q[((size_t)bh * L_ + ql) * DH_ + c4 * 4];
  }
  __syncthreads();

  const float* kr = Kt + ((size_t)bh * L_ + kc * 256 + t) * DH_;
  float acc[U_];
#pragma unroll
  for (int q = 0; q < U_; ++q) acc[q] = 0.f;

  float4 ka = *(const float4*)kr;
  for (int i4 = 0; i4 < 16; ++i4) {
    float4 kb = ka;
    if (i4 < 15) kb = *(const float4*)(kr + (i4 + 1) * 4);
#pragma unroll
    for (int q = 0; q < U_; ++q) {
      float4 qv = *(const float4*)&Qs[q][i4 * 4];
      acc[q] += ka.x * qv.x + ka.y * qv.y + ka.z * qv.z + ka.w * qv.w;
    }
    ka = kb;
  }
  float* srow = S + ((size_t)bh * U_) * L_ + kc * 256 + t;
#pragma unroll
  for (int q = 0; q < U_; ++q) srow[(size_t)q * L_] = acc[q] * SCALE_;
}

// ---------------------------------------------------------------------------
// Row softmax over S (in place). One block per row.
// ---------------------------------------------------------------------------
__global__ __launch_bounds__(256) void softmax_kernel(float* __restrict__ S) {
  float* r = S + (size_t)blockIdx.x * L_;
  int t = threadIdx.x;
  __shared__ float red[256];
  float v[8];
#pragma unroll
  for (int j = 0; j < 8; ++j) v[j] = r[t + j * 256];
  float mx = v[0];
#pragma unroll
  for (int j = 1; j < 8; ++j) mx = fmaxf(mx, v[j]);
  red[t] = mx; __syncthreads();
  for (int s = 128; s > 0; s >>= 1) {
    if (t < s) red[t] = fmaxf(red[t], red[t + s]);
    __syncthreads();
  }
  mx = red[0]; __syncthreads();
  float sm = 0.f;
#pragma unroll
  for (int j = 0; j < 8; ++j) { v[j] = __expf(v[j] - mx); sm += v[j]; }
  red[t] = sm; __syncthreads();
  for (int s = 128; s > 0; s >>= 1) {
    if (t < s) red[t] += red[t + s];
    __syncthreads();
  }
  float inv = 1.0f / red[0];
#pragma unroll
  for (int j = 0; j < 8; ++j) r[t + j * 256] = v[j] * inv;
}

// ---------------------------------------------------------------------------
// Partial PV (+ fused vmean partials): grid (kchunk=8, bh=32).
// ---------------------------------------------------------------------------
__global__ __launch_bounds__(256) void pv_kernel(
    const float* __restrict__ P, const float* __restrict__ Vt,
    float* __restrict__ ctxPart, float* __restrict__ vmeanP) {
  int kc = blockIdx.x, bh = blockIdx.y;
  int t = threadIdx.x;
  __shared__ float Ps[U_][256];
  for (int task = t; task < U_ * 64; task += 256) {
    int q = task >> 6, c4 = task & 63;
    *(float4*)&Ps[q][c4 * 4] =
        *(const float4*)&P[((size_t)(bh * U_ + q)) * L_ + kc * 256 + c4 * 4];
  }
  __syncthreads();
  int dh = t & 63, w = t >> 6;
  const float* vb = Vt + ((size_t)bh * L_ + kc * 256) * DH_ + dh;
  float acc[10];
#pragma unroll
  for (int j = 0; j < 10; ++j) acc[j] = 0.f;
  float vsum = 0.f;
  for (int k4 = 0; k4 < 64; ++k4) {
    float v0 = vb[(k4 * 4 + 0) * DH_];
    float v1 = vb[(k4 * 4 + 1) * DH_];
    float v2 = vb[(k4 * 4 + 2) * DH_];
    float v3 = vb[(k4 * 4 + 3) * DH_];
    vsum += (v0 + v1) + (v2 + v3);
#pragma unroll
    for (int j = 0; j < 10; ++j) {
      float4 p4 = *(const float4*)&Ps[w + 4 * j][k4 * 4];
      acc[j] += p4.x * v0 + p4.y * v1 + p4.z * v2 + p4.w * v3;
    }
  }
#pragma unroll
  for (int j = 0; j < 10; ++j) {
    int q = w + 4 * j;
    ctxPart[(((size_t)kc * 32 + bh) * U_ + q) * DH_ + dh] = acc[j];
  }
  if (w == 0) vmeanP[(bh * 8 + kc) * DH_ + dh] = vsum;
}

// ---------------------------------------------------------------------------
// base[b][j] = vmean_flat[b] . Wout[j] + bout[j]; vmean from partials.
// ---------------------------------------------------------------------------
__global__ __launch_bounds__(256) void base_kernel(
    const float* __restrict__ vmeanP, const float* __restrict__ Wout,
    const float* __restrict__ bout, float* __restrict__ baseOut) {
  int bid = blockIdx.x;
  int b = bid >> 4, jc = bid & 15;
  int t = threadIdx.x;
  int j = jc * 64 + (t & 63);
  int isl = t >> 6;
  __shared__ float vm[D_];
  __shared__ float red[256];
  for (int i = t; i < D_; i += 256) {
    int bh = b * H_ + (i >> 6), dh = i & 63;
    float s = 0.f;
#pragma unroll
    for (int kc = 0; kc < 8; ++kc) s += vmeanP[(bh * 8 + kc) * DH_ + dh];
    vm[i] = s * (1.0f / L_);
  }
  __syncthreads();
  float s = 0.f;
  const float* wr = Wout + (size_t)j * D_ + isl * 256;
  const float* vv = vm + isl * 256;
  for (int i = 0; i < 256; i += 4) {
    float4 w = *(const float4*)(wr + i);
    s += vv[i] * w.x + vv[i + 1] * w.y + vv[i + 2] * w.z + vv[i + 3] * w.w;
  }
  red[t] = s; __syncthreads();
  if (isl == 0)
    baseOut[b * D_ + j] =
        red[t] + red[t + 64] + red[t + 128] + red[t + 192] + bout[j];
}

// ---------------------------------------------------------------------------
// out[b,l,:] = base[b,:]
// ---------------------------------------------------------------------------
__global__ __launch_bounds__(256) void bcast_out(
    const float* __restrict__ baseIn, float* __restrict__ out) {
  size_t i4 = (size_t)blockIdx.x * 256 + threadIdx.x;
  size_t i = i4 * 4;
  int b = (int)(i >> 21);
  int col = (int)(i & (D_ - 1));
  *(float4*)(out + i) = *(const float4*)(baseIn + b * D_ + col);
}

// ---------------------------------------------------------------------------
// out[b, l_u, :] += (ctx_upd - vmean) . Wout[:, h*64:(h+1)*64]^T
// ctx_upd merged in-kernel from the 8 ctxPart chunks (merge_ctx fused away).
// ---------------------------------------------------------------------------
__global__ __launch_bounds__(256) void corr_kernel(
    const int* __restrict__ topIdx, const float* __restrict__ ctxPart,
    const float* __restrict__ vmeanP, const float* __restrict__ Wout,
    float* __restrict__ out) {
  int bhu = blockIdx.x;
  int bh = bhu / U_;
  int u = bhu - bh * U_;
  int h = bh & (H_ - 1), b = bh >> 4;
  int l = topIdx[bhu];
  __shared__ float dv[DH_];
  int t = threadIdx.x;
  if (t < DH_) {
    float sc = 0.f, vm = 0.f;
#pragma unroll
    for (int c = 0; c < 8; ++c) {
      sc += ctxPart[(((size_t)c * 32 + bh) * U_ + u) * DH_ + t];
      vm += vmeanP[(bh * 8 + c) * DH_ + t];
    }
    dv[t] = sc - vm * (1.0f / L_);
  }
  __syncthreads();
  int sub = t & 3;
  int jbase = t >> 2;
  float* orow = out + ((size_t)b * L_ + l) * D_;
  const float* dvs = dv + sub * 16;
#pragma unroll
  for (int jc = 0; jc < 16; ++jc) {
    int j = jc * 64 + jbase;
    const float* wr = Wout + (size_t)j * D_ + h * DH_ + sub * 16;
    float s = 0.f;
#pragma unroll
    for (int i = 0; i < 16; i += 4) {
      float4 w = *(const float4*)(wr + i);
      s += dvs[i] * w.x + dvs[i + 1] * w.y + dvs[i + 2] * w.z +
           dvs[i + 3] * w.w;
    }
    s += __shfl_xor(s, 1);
    s += __shfl_xor(s, 2);
    if (sub == 0) atomicAdd(orow + j, s);
  }
}

// ---------------------------------------------------------------------------
extern "C" void kernel_launch(void* const* d_in, const int* in_sizes, int n_in,
                              void* d_out, int out_size, void* d_ws,
                              size_t ws_size, hipStream_t stream) {
  const float* x    = (const float*)d_in[0];
  const float* Wq   = (const float*)d_in[1];
  const float* bq   = (const float*)d_in[2];
  const float* Wkv  = (const float*)d_in[3];
  const float* bkv  = (const float*)d_in[4];
  const float* Wout = (const float*)d_in[5];
  const float* bout = (const float*)d_in[6];
  const int*   idx  = (const int*)d_in[7];
  float* out = (float*)d_out;

  float* ws = (float*)d_ws;
  const size_t NQ = (size_t)B_ * H_ * L_ * DH_;  // 4,194,304 floats
  float* Q  = ws;
  float* Kt = Q + NQ;
  float* Vt = Kt + NQ;
  // W/X split region (live only through the GEMM)
  unsigned short* Whi = (unsigned short*)(Vt + NQ);  // 6 MB
  unsigned short* Wlo = Whi + (size_t)3 * D_ * D_;   // 6 MB
  unsigned short* Xhi = Wlo + (size_t)3 * D_ * D_;   // 8 MB (optional)
  unsigned short* Xlo = Xhi + NQ;                    // 8 MB (optional)
  // phase-2 region (overlaps split region; used only after the GEMM)
  float* S       = Vt + NQ;                          // 10 MB
  float* Mv      = S + (size_t)32 * U_ * L_;
  float* ctxPart = Mv + (size_t)B_ * H_ * L_;
  float* vmeanP  = ctxPart + (size_t)8 * 32 * U_ * DH_;
  float* baseB   = vmeanP + 32 * 8 * DH_;
  int*   topIdx  = (int*)(baseB + B_ * D_);

  const bool xsplit = ws_size >= ((size_t)76 << 20);  // Xhi/Xlo fit?
  const int nW = 3 * D_ * D_ / 4;                     // W quads
  const int nX = (int)(NQ / 4);                       // X quads

  if (xsplit) {
    split_all<<<dim3((nW + nX) / 256), dim3(256), 0, stream>>>(
        Wq, Wkv, x, Whi, Wlo, Xhi, Xlo, nW);
    gemm_qkv_mfma<true>
        <<<dim3(3 * D_ / 128, B_ * L_ / 128), dim3(256), 0, stream>>>(
            x, Xhi, Xlo, Whi, Wlo, bq, bkv, Q, Kt, Vt);
  } else {
    split_all<<<dim3(nW / 256), dim3(256), 0, stream>>>(Wq, Wkv, x, Whi, Wlo,
                                                        Xhi, Xlo, nW);
    gemm_qkv_mfma<false>
        <<<dim3(3 * D_ / 128, B_ * L_ / 128), dim3(256), 0, stream>>>(
            x, Xhi, Xlo, Whi, Wlo, bq, bkv, Q, Kt, Vt);
  }
  sample_m<<<dim3(B_ * H_ * L_ / 4), dim3(256), 0, stream>>>(Q, Kt, idx, Mv);
  topk_kernel<<<dim3(B_ * H_ / 4), dim3(256), 0, stream>>>(Mv, topIdx);
  score_kernel<<<dim3(8, 32), dim3(256), 0, stream>>>(Q, Kt, topIdx, S);
  softmax_kernel<<<dim3(32 * U_), dim3(256), 0, stream>>>(S);
  pv_kernel<<<dim3(8, 32), dim3(256), 0, stream>>>(S, Vt, ctxPart, vmeanP);
  base_kernel<<<dim3(B_ * 16), dim3(256), 0, stream>>>(vmeanP, Wout, bout,
                                                       baseB);
  bcast_out<<<dim3(B_ * L_ * D_ / 1024), dim3(256), 0, stream>>>(baseB, out);
  corr_kernel<<<dim3(B_ * H_ * U_), dim3(256), 0, stream>>>(topIdx, ctxPart,
                                                            vmeanP, Wout, out);
}

// Round 6
// 322.554 us; speedup vs baseline: 1.3247x; 1.3247x over previous
//
#include <hip/hip_runtime.h>
#include <math.h>

// Problem constants (B=2, L=2048, D=1024, H=16, FACTOR=5)
#define B_ 2
#define L_ 2048
#define D_ 1024
#define H_ 16
#define DH_ 64
#define U_ 40
#define SCALE_ 0.125f

typedef __attribute__((ext_vector_type(8))) short short8v;            // 8 bf16
typedef __attribute__((ext_vector_type(4))) float f32x4;
typedef __attribute__((ext_vector_type(4))) unsigned short ushort4v;  // 8 B

static __device__ __forceinline__ unsigned short bf16_rne(float f) {
  unsigned int u = __float_as_uint(f);
  u += 0x7fff + ((u >> 16) & 1);
  return (unsigned short)(u >> 16);
}
static __device__ __forceinline__ float bf16_f32(unsigned short h) {
  return __uint_as_float(((unsigned int)h) << 16);
}

// ---------------------------------------------------------------------------
// Pre-split f32 -> (hi,lo) bf16 for W=[Wq;Wkv] (quads [0,nW)) and X (rest).
// ---------------------------------------------------------------------------
__global__ __launch_bounds__(256) void split_all(
    const float* __restrict__ Wq, const float* __restrict__ Wkv,
    const float* __restrict__ X, unsigned short* __restrict__ Whi,
    unsigned short* __restrict__ Wlo, unsigned short* __restrict__ Xhi,
    unsigned short* __restrict__ Xlo, int nW) {
  int i = blockIdx.x * 256 + threadIdx.x;
  const int nq_q = (D_ * D_) / 4;
  float4 v;
  unsigned short *hi, *lo;
  int off;
  if (i < nW) {
    v = (i < nq_q) ? ((const float4*)Wq)[i] : ((const float4*)Wkv)[i - nq_q];
    hi = Whi; lo = Wlo; off = i;
  } else {
    off = i - nW;
    v = ((const float4*)X)[off];
    hi = Xhi; lo = Xlo;
  }
  float vv[4] = {v.x, v.y, v.z, v.w};
  ushort4v h, l;
#pragma unroll
  for (int e = 0; e < 4; ++e) {
    unsigned short hh = bf16_rne(vv[e]);
    h[e] = hh;
    l[e] = bf16_rne(vv[e] - bf16_f32(hh));
  }
  ((ushort4v*)hi)[off] = h;
  ((ushort4v*)lo)[off] = l;
}

// ---------------------------------------------------------------------------
// Split-bf16 MFMA GEMM for QKV: C = X @ W^T + bias, M=4096 N=3072 K=1024.
// 128x128 tile, BK=32, 4 waves. Staging task = (row, 16B-seg).
// ---------------------------------------------------------------------------
template <bool XS>
__global__ __launch_bounds__(256) void gemm_qkv_mfma(
    const float* __restrict__ X,
    const unsigned short* __restrict__ Xhi,
    const unsigned short* __restrict__ Xlo,
    const unsigned short* __restrict__ Whi,
    const unsigned short* __restrict__ Wlo,
    const float* __restrict__ bq, const float* __restrict__ bkv,
    float* __restrict__ Qo, float* __restrict__ Ko, float* __restrict__ Vo) {
  __shared__ unsigned short As[128][72];
  __shared__ unsigned short Bs[128][72];
  const int tid = threadIdx.x;
  const int lane = tid & 63;
  const int wave = tid >> 6;
  const int wm = wave >> 1, wn = wave & 1;
  const int row0 = blockIdx.y * 128;
  const int col0 = blockIdx.x * 128;

  f32x4 acc[4][4] = {};

  const unsigned short* srcA[4];
  const float* srcAf[4];
  bool loA[4];
  const unsigned short* srcB[4];
  unsigned short* dstA[4];
  unsigned short* dstB[4];
#pragma unroll
  for (int rep = 0; rep < 4; ++rep) {
    int task = tid + rep * 256;
    int r = task >> 3, seg = task & 7;
    size_t aoff = (size_t)(row0 + r) * D_ + (seg & 3) * 8;
    if (XS) {
      srcA[rep] = ((seg < 4) ? Xhi : Xlo) + aoff;
      srcAf[rep] = 0;
    } else {
      srcAf[rep] = X + aoff;
      srcA[rep] = 0;
    }
    loA[rep] = seg >= 4;
    srcB[rep] = ((seg < 4) ? Whi : Wlo) + (size_t)(col0 + r) * D_ +
                (seg & 3) * 8;
    dstA[rep] = &As[r][seg * 8];
    dstB[rep] = &Bs[r][seg * 8];
  }

  for (int k0 = 0; k0 < D_; k0 += 32) {
#pragma unroll
    for (int rep = 0; rep < 4; ++rep) {
      short8v a;
      if (XS) {
        a = *(const short8v*)(srcA[rep] + k0);
      } else {
        float4 a0 = *(const float4*)(srcAf[rep] + k0);
        float4 a1 = *(const float4*)(srcAf[rep] + k0 + 4);
        float av[8] = {a0.x, a0.y, a0.z, a0.w, a1.x, a1.y, a1.z, a1.w};
#pragma unroll
        for (int i = 0; i < 8; ++i) {
          unsigned short h = bf16_rne(av[i]);
          a[i] = loA[rep] ? (short)bf16_rne(av[i] - bf16_f32(h)) : (short)h;
        }
      }
      short8v b = *(const short8v*)(srcB[rep] + k0);
      *(short8v*)dstA[rep] = a;
      *(short8v*)dstB[rep] = b;
    }
    __syncthreads();

    short8v af[4][2], bf[4][2];
#pragma unroll
    for (int mi = 0; mi < 4; ++mi) {
      int rr = wm * 64 + mi * 16 + (lane & 15);
      int hs = lane >> 4;
      af[mi][0] = *(const short8v*)&As[rr][hs * 8];
      af[mi][1] = *(const short8v*)&As[rr][32 + hs * 8];
    }
#pragma unroll
    for (int ni = 0; ni < 4; ++ni) {
      int rr = wn * 64 + ni * 16 + (lane & 15);
      int hs = lane >> 4;
      bf[ni][0] = *(const short8v*)&Bs[rr][hs * 8];
      bf[ni][1] = *(const short8v*)&Bs[rr][32 + hs * 8];
    }
#pragma unroll
    for (int mi = 0; mi < 4; ++mi)
#pragma unroll
      for (int ni = 0; ni < 4; ++ni) {
        acc[mi][ni] = __builtin_amdgcn_mfma_f32_16x16x32_bf16(
            af[mi][0], bf[ni][0], acc[mi][ni], 0, 0, 0);
        acc[mi][ni] = __builtin_amdgcn_mfma_f32_16x16x32_bf16(
            af[mi][0], bf[ni][1], acc[mi][ni], 0, 0, 0);
        acc[mi][ni] = __builtin_amdgcn_mfma_f32_16x16x32_bf16(
            af[mi][1], bf[ni][0], acc[mi][ni], 0, 0, 0);
      }
    __syncthreads();
  }

  // Epilogue: C/D layout col=lane&15, row=(lane>>4)*4+reg.
#pragma unroll
  for (int ni = 0; ni < 4; ++ni) {
    int c = col0 + wn * 64 + ni * 16 + (lane & 15);
    int which = c >> 10;
    int jj = c & (D_ - 1);
    int h = jj >> 6, dh = jj & 63;
    float bias = (c < D_) ? bq[c] : bkv[c - D_];
    float* dst = (which == 0) ? Qo : ((which == 1) ? Ko : Vo);
#pragma unroll
    for (int mi = 0; mi < 4; ++mi) {
#pragma unroll
      for (int reg = 0; reg < 4; ++reg) {
        int r = row0 + wm * 64 + mi * 16 + ((lane >> 4) << 2) + reg;
        int b = r >> 11, l = r & (L_ - 1);
        dst[(((size_t)b * H_ + h) * L_ + l) * DH_ + dh] =
            acc[mi][ni][reg] + bias;
      }
    }
  }
}

// ---------------------------------------------------------------------------
// M[b,h,l] = max_u(QK) - mean_u(QK). Wave per l. Lane u loads its sampled
// index; staging loop broadcasts it via __shfl (NO register array -> no
// scratch). 40 K-rows staged coalesced into LDS (pad 65, conflict-free).
// ---------------------------------------------------------------------------
__global__ __launch_bounds__(256) void sample_m(
    const float* __restrict__ Q, const float* __restrict__ Kt,
    const int* __restrict__ idx, float* __restrict__ Mv) {
  __shared__ float Kst[4][U_][65];
  __shared__ float qs[4][DH_];
  int w = threadIdx.x >> 6, lane = threadIdx.x & 63;
  int gl = blockIdx.x * 4 + w;  // bh*L + l
  int bh = gl >> 11, l = gl & (L_ - 1);
  const float* Kb = Kt + (size_t)bh * L_ * DH_;
  qs[w][lane] = Q[(size_t)gl * DH_ + lane];
  int myKl = (lane < U_) ? idx[l * U_ + lane] : 0;
#pragma unroll
  for (int u = 0; u < U_; ++u) {
    int kl = __shfl(myKl, u);
    Kst[w][u][lane] = Kb[(size_t)kl * DH_ + lane];
  }
  __syncthreads();
  float mx = -INFINITY, sm = 0.f;
  if (lane < U_) {
    const float* kr = Kst[w][lane];
    const float* qq = qs[w];
    float d = 0.f;
#pragma unroll
    for (int i = 0; i < DH_; ++i) d += qq[i] * kr[i];
    mx = d;
    sm = d;
  }
#pragma unroll
  for (int off = 1; off < 64; off <<= 1) {
    mx = fmaxf(mx, __shfl_xor(mx, off));
    sm += __shfl_xor(sm, off);
  }
  if (lane == 0) Mv[gl] = mx - sm * (1.0f / U_);
}

// ---------------------------------------------------------------------------
// Per-(b,h) top-U_ of M: ONE WAVE per bh, shfl-only argmax (no barriers).
// ---------------------------------------------------------------------------
__global__ __launch_bounds__(256) void topk_kernel(
    const float* __restrict__ Mv, int* __restrict__ topIdx) {
  __shared__ float vals[4][L_];
  int w = threadIdx.x >> 6, lane = threadIdx.x & 63;
  int bh = blockIdx.x * 4 + w;
  for (int j = 0; j < 32; ++j)
    vals[w][j * 64 + lane] = Mv[(size_t)bh * L_ + j * 64 + lane];
  for (int it = 0; it < U_; ++it) {
    float bv = -INFINITY;
    int bi = 0x7fffffff;
    for (int j = 0; j < 32; ++j) {
      int i = j * 64 + lane;
      float v = vals[w][i];
      if (v > bv) { bv = v; bi = i; }  // j ascending -> ties keep lower index
    }
#pragma unroll
    for (int off = 32; off > 0; off >>= 1) {
      float ov = __shfl_xor(bv, off);
      int oi = __shfl_xor(bi, off);
      if (ov > bv || (ov == bv && oi < bi)) { bv = ov; bi = oi; }
    }
    if (lane == 0) {
      topIdx[bh * U_ + it] = bi;
      vals[w][bi] = -INFINITY;
    }
  }
}

// ---------------------------------------------------------------------------
// scores[bh][q][k] = scale * Qtop[q] . K[k]. Thread = one key, acc[40] regs.
// ---------------------------------------------------------------------------
__global__ __launch_bounds__(256) void score_kernel(
    const float* __restrict__ Q, const float* __restrict__ Kt,
    const int* __restrict__ topIdx, float* __restrict__ S) {
  int kc = blockIdx.x, bh = blockIdx.y;
  int t = threadIdx.x;
  __shared__ float Qs[U_][DH_];
  for (int task = t; task < U_ * 16; task += 256) {
    int q = task >> 4, c4 = task & 15;
    int ql = topIdx[bh * U_ + q];
    *(float4*)&Qs[q][c4 * 4] =
        *(const float4*)&Q[((size_t)bh * L_ + ql) * DH_ + c4 * 4];
  }
  __syncthreads();

  const float* kr = Kt + ((size_t)bh * L_ + kc * 256 + t) * DH_;
  float acc[U_];
#pragma unroll
  for (int q = 0; q < U_; ++q) acc[q] = 0.f;

  float4 ka = *(const float4*)kr;
  for (int i4 = 0; i4 < 16; ++i4) {
    float4 kb = ka;
    if (i4 < 15) kb = *(const float4*)(kr + (i4 + 1) * 4);
#pragma unroll
    for (int q = 0; q < U_; ++q) {
      float4 qv = *(const float4*)&Qs[q][i4 * 4];
      acc[q] += ka.x * qv.x + ka.y * qv.y + ka.z * qv.z + ka.w * qv.w;
    }
    ka = kb;
  }
  float* srow = S + ((size_t)bh * U_) * L_ + kc * 256 + t;
#pragma unroll
  for (int q = 0; q < U_; ++q) srow[(size_t)q * L_] = acc[q] * SCALE_;
}

// ---------------------------------------------------------------------------
// Row softmax over S (in place). One block per row.
// ---------------------------------------------------------------------------
__global__ __launch_bounds__(256) void softmax_kernel(float* __restrict__ S) {
  float* r = S + (size_t)blockIdx.x * L_;
  int t = threadIdx.x;
  __shared__ float red[256];
  float v[8];
#pragma unroll
  for (int j = 0; j < 8; ++j) v[j] = r[t + j * 256];
  float mx = v[0];
#pragma unroll
  for (int j = 1; j < 8; ++j) mx = fmaxf(mx, v[j]);
  red[t] = mx; __syncthreads();
  for (int s = 128; s > 0; s >>= 1) {
    if (t < s) red[t] = fmaxf(red[t], red[t + s]);
    __syncthreads();
  }
  mx = red[0]; __syncthreads();
  float sm = 0.f;
#pragma unroll
  for (int j = 0; j < 8; ++j) { v[j] = __expf(v[j] - mx); sm += v[j]; }
  red[t] = sm; __syncthreads();
  for (int s = 128; s > 0; s >>= 1) {
    if (t < s) red[t] += red[t + s];
    __syncthreads();
  }
  float inv = 1.0f / red[0];
#pragma unroll
  for (int j = 0; j < 8; ++j) r[t + j * 256] = v[j] * inv;
}

// ---------------------------------------------------------------------------
// Partial PV (+ fused vmean partials): grid (kchunk=8, bh=32).
// ---------------------------------------------------------------------------
__global__ __launch_bounds__(256) void pv_kernel(
    const float* __restrict__ P, const float* __restrict__ Vt,
    float* __restrict__ ctxPart, float* __restrict__ vmeanP) {
  int kc = blockIdx.x, bh = blockIdx.y;
  int t = threadIdx.x;
  __shared__ float Ps[U_][256];
  for (int task = t; task < U_ * 64; task += 256) {
    int q = task >> 6, c4 = task & 63;
    *(float4*)&Ps[q][c4 * 4] =
        *(const float4*)&P[((size_t)(bh * U_ + q)) * L_ + kc * 256 + c4 * 4];
  }
  __syncthreads();
  int dh = t & 63, w = t >> 6;
  const float* vb = Vt + ((size_t)bh * L_ + kc * 256) * DH_ + dh;
  float acc[10];
#pragma unroll
  for (int j = 0; j < 10; ++j) acc[j] = 0.f;
  float vsum = 0.f;
  for (int k4 = 0; k4 < 64; ++k4) {
    float v0 = vb[(k4 * 4 + 0) * DH_];
    float v1 = vb[(k4 * 4 + 1) * DH_];
    float v2 = vb[(k4 * 4 + 2) * DH_];
    float v3 = vb[(k4 * 4 + 3) * DH_];
    vsum += (v0 + v1) + (v2 + v3);
#pragma unroll
    for (int j = 0; j < 10; ++j) {
      float4 p4 = *(const float4*)&Ps[w + 4 * j][k4 * 4];
      acc[j] += p4.x * v0 + p4.y * v1 + p4.z * v2 + p4.w * v3;
    }
  }
#pragma unroll
  for (int j = 0; j < 10; ++j) {
    int q = w + 4 * j;
    ctxPart[(((size_t)kc * 32 + bh) * U_ + q) * DH_ + dh] = acc[j];
  }
  if (w == 0) vmeanP[(bh * 8 + kc) * DH_ + dh] = vsum;
}

// ---------------------------------------------------------------------------
// base[b][j] = vmean_flat[b] . Wout[j] + bout[j]; vmean from partials.
// ---------------------------------------------------------------------------
__global__ __launch_bounds__(256) void base_kernel(
    const float* __restrict__ vmeanP, const float* __restrict__ Wout,
    const float* __restrict__ bout, float* __restrict__ baseOut) {
  int bid = blockIdx.x;
  int b = bid >> 4, jc = bid & 15;
  int t = threadIdx.x;
  int j = jc * 64 + (t & 63);
  int isl = t >> 6;
  __shared__ float vm[D_];
  __shared__ float red[256];
  for (int i = t; i < D_; i += 256) {
    int bh = b * H_ + (i >> 6), dh = i & 63;
    float s = 0.f;
#pragma unroll
    for (int kc = 0; kc < 8; ++kc) s += vmeanP[(bh * 8 + kc) * DH_ + dh];
    vm[i] = s * (1.0f / L_);
  }
  __syncthreads();
  float s = 0.f;
  const float* wr = Wout + (size_t)j * D_ + isl * 256;
  const float* vv = vm + isl * 256;
  for (int i = 0; i < 256; i += 4) {
    float4 w = *(const float4*)(wr + i);
    s += vv[i] * w.x + vv[i + 1] * w.y + vv[i + 2] * w.z + vv[i + 3] * w.w;
  }
  red[t] = s; __syncthreads();
  if (isl == 0)
    baseOut[b * D_ + j] =
        red[t] + red[t + 64] + red[t + 128] + red[t + 192] + bout[j];
}

// ---------------------------------------------------------------------------
// out[b,l,:] = base[b,:]
// ---------------------------------------------------------------------------
__global__ __launch_bounds__(256) void bcast_out(
    const float* __restrict__ baseIn, float* __restrict__ out) {
  size_t i4 = (size_t)blockIdx.x * 256 + threadIdx.x;
  size_t i = i4 * 4;
  int b = (int)(i >> 21);
  int col = (int)(i & (D_ - 1));
  *(float4*)(out + i) = *(const float4*)(baseIn + b * D_ + col);
}

// ---------------------------------------------------------------------------
// out[b, l_u, :] += (ctx_upd - vmean) . Wout[:, h*64:(h+1)*64]^T
// ---------------------------------------------------------------------------
__global__ __launch_bounds__(256) void corr_kernel(
    const int* __restrict__ topIdx, const float* __restrict__ ctxPart,
    const float* __restrict__ vmeanP, const float* __restrict__ Wout,
    float* __restrict__ out) {
  int bhu = blockIdx.x;
  int bh = bhu / U_;
  int u = bhu - bh * U_;
  int h = bh & (H_ - 1), b = bh >> 4;
  int l = topIdx[bhu];
  __shared__ float dv[DH_];
  int t = threadIdx.x;
  if (t < DH_) {
    float sc = 0.f, vm = 0.f;
#pragma unroll
    for (int c = 0; c < 8; ++c) {
      sc += ctxPart[(((size_t)c * 32 + bh) * U_ + u) * DH_ + t];
      vm += vmeanP[(bh * 8 + c) * DH_ + t];
    }
    dv[t] = sc - vm * (1.0f / L_);
  }
  __syncthreads();
  int sub = t & 3;
  int jbase = t >> 2;
  float* orow = out + ((size_t)b * L_ + l) * D_;
  const float* dvs = dv + sub * 16;
#pragma unroll
  for (int jc = 0; jc < 16; ++jc) {
    int j = jc * 64 + jbase;
    const float* wr = Wout + (size_t)j * D_ + h * DH_ + sub * 16;
    float s = 0.f;
#pragma unroll
    for (int i = 0; i < 16; i += 4) {
      float4 w = *(const float4*)(wr + i);
      s += dvs[i] * w.x + dvs[i + 1] * w.y + dvs[i + 2] * w.z +
           dvs[i + 3] * w.w;
    }
    s += __shfl_xor(s, 1);
    s += __shfl_xor(s, 2);
    if (sub == 0) atomicAdd(orow + j, s);
  }
}

// ---------------------------------------------------------------------------
extern "C" void kernel_launch(void* const* d_in, const int* in_sizes, int n_in,
                              void* d_out, int out_size, void* d_ws,
                              size_t ws_size, hipStream_t stream) {
  const float* x    = (const float*)d_in[0];
  const float* Wq   = (const float*)d_in[1];
  const float* bq   = (const float*)d_in[2];
  const float* Wkv  = (const float*)d_in[3];
  const float* bkv  = (const float*)d_in[4];
  const float* Wout = (const float*)d_in[5];
  const float* bout = (const float*)d_in[6];
  const int*   idx  = (const int*)d_in[7];
  float* out = (float*)d_out;

  float* ws = (float*)d_ws;
  const size_t NQ = (size_t)B_ * H_ * L_ * DH_;  // 4,194,304 floats
  float* Q  = ws;
  float* Kt = Q + NQ;
  float* Vt = Kt + NQ;
  // W/X split region (live only through the GEMM)
  unsigned short* Whi = (unsigned short*)(Vt + NQ);  // 6 MB
  unsigned short* Wlo = Whi + (size_t)3 * D_ * D_;   // 6 MB
  unsigned short* Xhi = Wlo + (size_t)3 * D_ * D_;   // 8 MB (optional)
  unsigned short* Xlo = Xhi + NQ;                    // 8 MB (optional)
  // phase-2 region (overlaps split region; used only after the GEMM)
  float* S       = Vt + NQ;                          // 10 MB
  float* Mv      = S + (size_t)32 * U_ * L_;
  float* ctxPart = Mv + (size_t)B_ * H_ * L_;
  float* vmeanP  = ctxPart + (size_t)8 * 32 * U_ * DH_;
  float* baseB   = vmeanP + 32 * 8 * DH_;
  int*   topIdx  = (int*)(baseB + B_ * D_);

  const bool xsplit = ws_size >= ((size_t)76 << 20);  // Xhi/Xlo fit?
  const int nW = 3 * D_ * D_ / 4;                     // W quads
  const int nX = (int)(NQ / 4);                       // X quads

  if (xsplit) {
    split_all<<<dim3((nW + nX) / 256), dim3(256), 0, stream>>>(
        Wq, Wkv, x, Whi, Wlo, Xhi, Xlo, nW);
    gemm_qkv_mfma<true>
        <<<dim3(3 * D_ / 128, B_ * L_ / 128), dim3(256), 0, stream>>>(
            x, Xhi, Xlo, Whi, Wlo, bq, bkv, Q, Kt, Vt);
  } else {
    split_all<<<dim3(nW / 256), dim3(256), 0, stream>>>(Wq, Wkv, x, Whi, Wlo,
                                                        Xhi, Xlo, nW);
    gemm_qkv_mfma<false>
        <<<dim3(3 * D_ / 128, B_ * L_ / 128), dim3(256), 0, stream>>>(
            x, Xhi, Xlo, Whi, Wlo, bq, bkv, Q, Kt, Vt);
  }
  sample_m<<<dim3(B_ * H_ * L_ / 4), dim3(256), 0, stream>>>(Q, Kt, idx, Mv);
  topk_kernel<<<dim3(B_ * H_ / 4), dim3(256), 0, stream>>>(Mv, topIdx);
  score_kernel<<<dim3(8, 32), dim3(256), 0, stream>>>(Q, Kt, topIdx, S);
  softmax_kernel<<<dim3(32 * U_), dim3(256), 0, stream>>>(S);
  pv_kernel<<<dim3(8, 32), dim3(256), 0, stream>>>(S, Vt, ctxPart, vmeanP);
  base_kernel<<<dim3(B_ * 16), dim3(256), 0, stream>>>(vmeanP, Wout, bout,
                                                       baseB);
  bcast_out<<<dim3(B_ * L_ * D_ / 1024), dim3(256), 0, stream>>>(baseB, out);
  corr_kernel<<<dim3(B_ * H_ * U_), dim3(256), 0, stream>>>(topIdx, ctxPart,
                                                            vmeanP, Wout, out);
}

// Round 7
// 318.684 us; speedup vs baseline: 1.3407x; 1.0121x over previous
//
#include <hip/hip_runtime.h>
#include <math.h>

// Problem constants (B=2, L=2048, D=1024, H=16, FACTOR=5)
#define B_ 2
#define L_ 2048
#define D_ 1024
#define H_ 16
#define DH_ 64
#define U_ 40
#define SCALE_ 0.125f

typedef __attribute__((ext_vector_type(8))) short short8v;            // 8 bf16
typedef __attribute__((ext_vector_type(4))) float f32x4;
typedef __attribute__((ext_vector_type(4))) unsigned short ushort4v;  // 8 B

static __device__ __forceinline__ unsigned short bf16_rne(float f) {
  unsigned int u = __float_as_uint(f);
  u += 0x7fff + ((u >> 16) & 1);
  return (unsigned short)(u >> 16);
}
static __device__ __forceinline__ float bf16_f32(unsigned short h) {
  return __uint_as_float(((unsigned int)h) << 16);
}

// Async global->LDS, 16 B per lane. LDS dest is wave-uniform base + lane*16
// (m104); global src is per-lane (pre-swizzled addresses give swizzled LDS).
static __device__ __forceinline__ void gload16(const unsigned short* src,
                                               unsigned short* lds) {
  __builtin_amdgcn_global_load_lds(
      (const __attribute__((address_space(1))) void*)src,
      (__attribute__((address_space(3))) void*)lds, 16, 0, 0);
}

// ---------------------------------------------------------------------------
// Pre-split f32 -> (hi,lo) bf16 for W=[Wq;Wkv] (quads [0,nW)) and X (rest).
// ---------------------------------------------------------------------------
__global__ __launch_bounds__(256) void split_all(
    const float* __restrict__ Wq, const float* __restrict__ Wkv,
    const float* __restrict__ X, unsigned short* __restrict__ Whi,
    unsigned short* __restrict__ Wlo, unsigned short* __restrict__ Xhi,
    unsigned short* __restrict__ Xlo, int nW) {
  int i = blockIdx.x * 256 + threadIdx.x;
  const int nq_q = (D_ * D_) / 4;
  float4 v;
  unsigned short *hi, *lo;
  int off;
  if (i < nW) {
    v = (i < nq_q) ? ((const float4*)Wq)[i] : ((const float4*)Wkv)[i - nq_q];
    hi = Whi; lo = Wlo; off = i;
  } else {
    off = i - nW;
    v = ((const float4*)X)[off];
    hi = Xhi; lo = Xlo;
  }
  float vv[4] = {v.x, v.y, v.z, v.w};
  ushort4v h, l;
#pragma unroll
  for (int e = 0; e < 4; ++e) {
    unsigned short hh = bf16_rne(vv[e]);
    h[e] = hh;
    l[e] = bf16_rne(vv[e] - bf16_f32(hh));
  }
  ((ushort4v*)hi)[off] = h;
  ((ushort4v*)lo)[off] = l;
}

// ---------------------------------------------------------------------------
// Split-bf16 MFMA GEMM for QKV: C = X @ W^T + bias, M=4096 N=3072 K=1024.
// 128x128 tile, BK=32, 4 waves. Operands staged via global_load_lds (w=16):
// linear LDS [128][32] shorts per part, XOR-swizzle col_group ^= (row>>1)&3
// applied on the SOURCE address (write side) and the ds_read address (read
// side) -> both 2-way bank aliasing = free (m136). 32 KB LDS total.
// ---------------------------------------------------------------------------
template <bool XS>
__global__ __launch_bounds__(256) void gemm_qkv_mfma(
    const float* __restrict__ X,
    const unsigned short* __restrict__ Xhi,
    const unsigned short* __restrict__ Xlo,
    const unsigned short* __restrict__ Whi,
    const unsigned short* __restrict__ Wlo,
    const float* __restrict__ bq, const float* __restrict__ bkv,
    float* __restrict__ Qo, float* __restrict__ Ko, float* __restrict__ Vo) {
  __shared__ unsigned short Ah[128 * 32];
  __shared__ unsigned short Al[128 * 32];
  __shared__ unsigned short Bh[128 * 32];
  __shared__ unsigned short Bl[128 * 32];
  const int tid = threadIdx.x;
  const int lane = tid & 63;
  const int wave = tid >> 6;
  const int wm = wave >> 1, wn = wave & 1;
  const int row0 = blockIdx.y * 128;
  const int col0 = blockIdx.x * 128;

  f32x4 acc[4][4] = {};

  // gload call geometry: call c covers rows c*16..c*16+15 (1 KB);
  // lane -> (row = c*16 + (lane>>2), group g = lane&3).
  const int grow = lane >> 2;
  const int gg = lane & 3;

  for (int k0 = 0; k0 < D_; k0 += 32) {
#pragma unroll
    for (int j = 0; j < 2; ++j) {
      int c = wave + 4 * j;                    // 0..7
      int row = c * 16 + grow;                 // 0..127
      int gsrc = (gg ^ ((row >> 1) & 3)) << 3; // swizzled source col (shorts)
      size_t soffB = (size_t)(col0 + row) * D_ + k0 + gsrc;
      gload16(Whi + soffB, Bh + c * 512);
      gload16(Wlo + soffB, Bl + c * 512);
      if (XS) {
        size_t soffA = (size_t)(row0 + row) * D_ + k0 + gsrc;
        gload16(Xhi + soffA, Ah + c * 512);
        gload16(Xlo + soffA, Al + c * 512);
      }
    }
    if (!XS) {
#pragma unroll
      for (int rep = 0; rep < 2; ++rep) {
        int task = tid + rep * 256;  // 0..511
        int row = task >> 2;         // 0..127
        int gt = task & 3;           // true col group
        const float* s = X + (size_t)(row0 + row) * D_ + k0 + gt * 8;
        float4 a0 = *(const float4*)s;
        float4 a1 = *(const float4*)(s + 4);
        float av[8] = {a0.x, a0.y, a0.z, a0.w, a1.x, a1.y, a1.z, a1.w};
        short8v hseg, lseg;
#pragma unroll
        for (int e = 0; e < 8; ++e) {
          unsigned short hh = bf16_rne(av[e]);
          hseg[e] = (short)hh;
          lseg[e] = (short)bf16_rne(av[e] - bf16_f32(hh));
        }
        int dst = row * 32 + ((gt ^ ((row >> 1) & 3)) << 3);
        *(short8v*)&Ah[dst] = hseg;
        *(short8v*)&Al[dst] = lseg;
      }
    }
    __syncthreads();

    short8v a_h[4], a_l[4], b_h[4], b_l[4];
    const int hs = lane >> 4;  // true k-group 0..3
#pragma unroll
    for (int mi = 0; mi < 4; ++mi) {
      int rr = wm * 64 + mi * 16 + (lane & 15);
      int off = rr * 32 + ((hs ^ ((rr >> 1) & 3)) << 3);
      a_h[mi] = *(const short8v*)&Ah[off];
      a_l[mi] = *(const short8v*)&Al[off];
    }
#pragma unroll
    for (int ni = 0; ni < 4; ++ni) {
      int rc = wn * 64 + ni * 16 + (lane & 15);
      int off = rc * 32 + ((hs ^ ((rc >> 1) & 3)) << 3);
      b_h[ni] = *(const short8v*)&Bh[off];
      b_l[ni] = *(const short8v*)&Bl[off];
    }
#pragma unroll
    for (int mi = 0; mi < 4; ++mi)
#pragma unroll
      for (int ni = 0; ni < 4; ++ni) {
        acc[mi][ni] = __builtin_amdgcn_mfma_f32_16x16x32_bf16(
            a_h[mi], b_h[ni], acc[mi][ni], 0, 0, 0);
        acc[mi][ni] = __builtin_amdgcn_mfma_f32_16x16x32_bf16(
            a_h[mi], b_l[ni], acc[mi][ni], 0, 0, 0);
        acc[mi][ni] = __builtin_amdgcn_mfma_f32_16x16x32_bf16(
            a_l[mi], b_h[ni], acc[mi][ni], 0, 0, 0);
      }
    __syncthreads();
  }

  // Epilogue: C/D layout col=lane&15, row=(lane>>4)*4+reg.
#pragma unroll
  for (int ni = 0; ni < 4; ++ni) {
    int c = col0 + wn * 64 + ni * 16 + (lane & 15);
    int which = c >> 10;
    int jj = c & (D_ - 1);
    int h = jj >> 6, dh = jj & 63;
    float bias = (c < D_) ? bq[c] : bkv[c - D_];
    float* dst = (which == 0) ? Qo : ((which == 1) ? Ko : Vo);
#pragma unroll
    for (int mi = 0; mi < 4; ++mi) {
#pragma unroll
      for (int reg = 0; reg < 4; ++reg) {
        int r = row0 + wm * 64 + mi * 16 + ((lane >> 4) << 2) + reg;
        int b = r >> 11, l = r & (L_ - 1);
        dst[(((size_t)b * H_ + h) * L_ + l) * DH_ + dh] =
            acc[mi][ni][reg] + bias;
      }
    }
  }
}

// ---------------------------------------------------------------------------
// M[b,h,l] = max_u(QK) - mean_u(QK). Wave per l. Lane u loads its sampled
// index; staging loop broadcasts it via __shfl (no register array -> no
// scratch). 40 K-rows staged coalesced into LDS (pad 65, conflict-free).
// ---------------------------------------------------------------------------
__global__ __launch_bounds__(256) void sample_m(
    const float* __restrict__ Q, const float* __restrict__ Kt,
    const int* __restrict__ idx, float* __restrict__ Mv) {
  __shared__ float Kst[4][U_][65];
  __shared__ float qs[4][DH_];
  int w = threadIdx.x >> 6, lane = threadIdx.x & 63;
  int gl = blockIdx.x * 4 + w;  // bh*L + l
  int bh = gl >> 11, l = gl & (L_ - 1);
  const float* Kb = Kt + (size_t)bh * L_ * DH_;
  qs[w][lane] = Q[(size_t)gl * DH_ + lane];
  int myKl = (lane < U_) ? idx[l * U_ + lane] : 0;
#pragma unroll
  for (int u = 0; u < U_; ++u) {
    int kl = __shfl(myKl, u);
    Kst[w][u][lane] = Kb[(size_t)kl * DH_ + lane];
  }
  __syncthreads();
  float mx = -INFINITY, sm = 0.f;
  if (lane < U_) {
    const float* kr = Kst[w][lane];
    const float* qq = qs[w];
    float d = 0.f;
#pragma unroll
    for (int i = 0; i < DH_; ++i) d += qq[i] * kr[i];
    mx = d;
    sm = d;
  }
#pragma unroll
  for (int off = 1; off < 64; off <<= 1) {
    mx = fmaxf(mx, __shfl_xor(mx, off));
    sm += __shfl_xor(sm, off);
  }
  if (lane == 0) Mv[gl] = mx - sm * (1.0f / U_);
}

// ---------------------------------------------------------------------------
// Per-(b,h) top-U_ of M: ONE WAVE per bh, shfl-only argmax (no barriers).
// ---------------------------------------------------------------------------
__global__ __launch_bounds__(256) void topk_kernel(
    const float* __restrict__ Mv, int* __restrict__ topIdx) {
  __shared__ float vals[4][L_];
  int w = threadIdx.x >> 6, lane = threadIdx.x & 63;
  int bh = blockIdx.x * 4 + w;
  for (int j = 0; j < 32; ++j)
    vals[w][j * 64 + lane] = Mv[(size_t)bh * L_ + j * 64 + lane];
  for (int it = 0; it < U_; ++it) {
    float bv = -INFINITY;
    int bi = 0x7fffffff;
    for (int j = 0; j < 32; ++j) {
      int i = j * 64 + lane;
      float v = vals[w][i];
      if (v > bv) { bv = v; bi = i; }  // j ascending -> ties keep lower index
    }
#pragma unroll
    for (int off = 32; off > 0; off >>= 1) {
      float ov = __shfl_xor(bv, off);
      int oi = __shfl_xor(bi, off);
      if (ov > bv || (ov == bv && oi < bi)) { bv = ov; bi = oi; }
    }
    if (lane == 0) {
      topIdx[bh * U_ + it] = bi;
      vals[w][bi] = -INFINITY;
    }
  }
}

// ---------------------------------------------------------------------------
// scores[bh][q][k] = scale * Qtop[q] . K[k]. Thread = one key, acc[40] regs.
// ---------------------------------------------------------------------------
__global__ __launch_bounds__(256) void score_kernel(
    const float* __restrict__ Q, const float* __restrict__ Kt,
    const int* __restrict__ topIdx, float* __restrict__ S) {
  int kc = blockIdx.x, bh = blockIdx.y;
  int t = threadIdx.x;
  __shared__ float Qs[U_][DH_];
  for (int task = t; task < U_ * 16; task += 256) {
    int q = task >> 4, c4 = task & 15;
    int ql = topIdx[bh * U_ + q];
    *(float4*)&Qs[q][c4 * 4] =
        *(const float4*)&Q[((size_t)bh * L_ + ql) * DH_ + c4 * 4];
  }
  __syncthreads();

  const float* kr = Kt + ((size_t)bh * L_ + kc * 256 + t) * DH_;
  float acc[U_];
#pragma unroll
  for (int q = 0; q < U_; ++q) acc[q] = 0.f;

  float4 ka = *(const float4*)kr;
  for (int i4 = 0; i4 < 16; ++i4) {
    float4 kb = ka;
    if (i4 < 15) kb = *(const float4*)(kr + (i4 + 1) * 4);
#pragma unroll
    for (int q = 0; q < U_; ++q) {
      float4 qv = *(const float4*)&Qs[q][i4 * 4];
      acc[q] += ka.x * qv.x + ka.y * qv.y + ka.z * qv.z + ka.w * qv.w;
    }
    ka = kb;
  }
  float* srow = S + ((size_t)bh * U_) * L_ + kc * 256 + t;
#pragma unroll
  for (int q = 0; q < U_; ++q) srow[(size_t)q * L_] = acc[q] * SCALE_;
}

// ---------------------------------------------------------------------------
// Row softmax over S (in place). One block per row.
// ---------------------------------------------------------------------------
__global__ __launch_bounds__(256) void softmax_kernel(float* __restrict__ S) {
  float* r = S + (size_t)blockIdx.x * L_;
  int t = threadIdx.x;
  __shared__ float red[256];
  float v[8];
#pragma unroll
  for (int j = 0; j < 8; ++j) v[j] = r[t + j * 256];
  float mx = v[0];
#pragma unroll
  for (int j = 1; j < 8; ++j) mx = fmaxf(mx, v[j]);
  red[t] = mx; __syncthreads();
  for (int s = 128; s > 0; s >>= 1) {
    if (t < s) red[t] = fmaxf(red[t], red[t + s]);
    __syncthreads();
  }
  mx = red[0]; __syncthreads();
  float sm = 0.f;
#pragma unroll
  for (int j = 0; j < 8; ++j) { v[j] = __expf(v[j] - mx); sm += v[j]; }
  red[t] = sm; __syncthreads();
  for (int s = 128; s > 0; s >>= 1) {
    if (t < s) red[t] += red[t + s];
    __syncthreads();
  }
  float inv = 1.0f / red[0];
#pragma unroll
  for (int j = 0; j < 8; ++j) r[t + j * 256] = v[j] * inv;
}

// ---------------------------------------------------------------------------
// Partial PV (+ fused vmean partials): grid (kchunk=8, bh=32).
// ---------------------------------------------------------------------------
__global__ __launch_bounds__(256) void pv_kernel(
    const float* __restrict__ P, const float* __restrict__ Vt,
    float* __restrict__ ctxPart, float* __restrict__ vmeanP) {
  int kc = blockIdx.x, bh = blockIdx.y;
  int t = threadIdx.x;
  __shared__ float Ps[U_][256];
  for (int task = t; task < U_ * 64; task += 256) {
    int q = task >> 6, c4 = task & 63;
    *(float4*)&Ps[q][c4 * 4] =
        *(const float4*)&P[((size_t)(bh * U_ + q)) * L_ + kc * 256 + c4 * 4];
  }
  __syncthreads();
  int dh = t & 63, w = t >> 6;
  const float* vb = Vt + ((size_t)bh * L_ + kc * 256) * DH_ + dh;
  float acc[10];
#pragma unroll
  for (int j = 0; j < 10; ++j) acc[j] = 0.f;
  float vsum = 0.f;
  for (int k4 = 0; k4 < 64; ++k4) {
    float v0 = vb[(k4 * 4 + 0) * DH_];
    float v1 = vb[(k4 * 4 + 1) * DH_];
    float v2 = vb[(k4 * 4 + 2) * DH_];
    float v3 = vb[(k4 * 4 + 3) * DH_];
    vsum += (v0 + v1) + (v2 + v3);
#pragma unroll
    for (int j = 0; j < 10; ++j) {
      float4 p4 = *(const float4*)&Ps[w + 4 * j][k4 * 4];
      acc[j] += p4.x * v0 + p4.y * v1 + p4.z * v2 + p4.w * v3;
    }
  }
#pragma unroll
  for (int j = 0; j < 10; ++j) {
    int q = w + 4 * j;
    ctxPart[(((size_t)kc * 32 + bh) * U_ + q) * DH_ + dh] = acc[j];
  }
  if (w == 0) vmeanP[(bh * 8 + kc) * DH_ + dh] = vsum;
}

// ---------------------------------------------------------------------------
// base[b][j] = vmean_flat[b] . Wout[j] + bout[j]; vmean from partials.
// ---------------------------------------------------------------------------
__global__ __launch_bounds__(256) void base_kernel(
    const float* __restrict__ vmeanP, const float* __restrict__ Wout,
    const float* __restrict__ bout, float* __restrict__ baseOut) {
  int bid = blockIdx.x;
  int b = bid >> 4, jc = bid & 15;
  int t = threadIdx.x;
  int j = jc * 64 + (t & 63);
  int isl = t >> 6;
  __shared__ float vm[D_];
  __shared__ float red[256];
  for (int i = t; i < D_; i += 256) {
    int bh = b * H_ + (i >> 6), dh = i & 63;
    float s = 0.f;
#pragma unroll
    for (int kc = 0; kc < 8; ++kc) s += vmeanP[(bh * 8 + kc) * DH_ + dh];
    vm[i] = s * (1.0f / L_);
  }
  __syncthreads();
  float s = 0.f;
  const float* wr = Wout + (size_t)j * D_ + isl * 256;
  const float* vv = vm + isl * 256;
  for (int i = 0; i < 256; i += 4) {
    float4 w = *(const float4*)(wr + i);
    s += vv[i] * w.x + vv[i + 1] * w.y + vv[i + 2] * w.z + vv[i + 3] * w.w;
  }
  red[t] = s; __syncthreads();
  if (isl == 0)
    baseOut[b * D_ + j] =
        red[t] + red[t + 64] + red[t + 128] + red[t + 192] + bout[j];
}

// ---------------------------------------------------------------------------
// out[b,l,:] = base[b,:]
// ---------------------------------------------------------------------------
__global__ __launch_bounds__(256) void bcast_out(
    const float* __restrict__ baseIn, float* __restrict__ out) {
  size_t i4 = (size_t)blockIdx.x * 256 + threadIdx.x;
  size_t i = i4 * 4;
  int b = (int)(i >> 21);
  int col = (int)(i & (D_ - 1));
  *(float4*)(out + i) = *(const float4*)(baseIn + b * D_ + col);
}

// ---------------------------------------------------------------------------
// out[b, l_u, :] += (ctx_upd - vmean) . Wout[:, h*64:(h+1)*64]^T
// ---------------------------------------------------------------------------
__global__ __launch_bounds__(256) void corr_kernel(
    const int* __restrict__ topIdx, const float* __restrict__ ctxPart,
    const float* __restrict__ vmeanP, const float* __restrict__ Wout,
    float* __restrict__ out) {
  int bhu = blockIdx.x;
  int bh = bhu / U_;
  int u = bhu - bh * U_;
  int h = bh & (H_ - 1), b = bh >> 4;
  int l = topIdx[bhu];
  __shared__ float dv[DH_];
  int t = threadIdx.x;
  if (t < DH_) {
    float sc = 0.f, vm = 0.f;
#pragma unroll
    for (int c = 0; c < 8; ++c) {
      sc += ctxPart[(((size_t)c * 32 + bh) * U_ + u) * DH_ + t];
      vm += vmeanP[(bh * 8 + c) * DH_ + t];
    }
    dv[t] = sc - vm * (1.0f / L_);
  }
  __syncthreads();
  int sub = t & 3;
  int jbase = t >> 2;
  float* orow = out + ((size_t)b * L_ + l) * D_;
  const float* dvs = dv + sub * 16;
#pragma unroll
  for (int jc = 0; jc < 16; ++jc) {
    int j = jc * 64 + jbase;
    const float* wr = Wout + (size_t)j * D_ + h * DH_ + sub * 16;
    float s = 0.f;
#pragma unroll
    for (int i = 0; i < 16; i += 4) {
      float4 w = *(const float4*)(wr + i);
      s += dvs[i] * w.x + dvs[i + 1] * w.y + dvs[i + 2] * w.z +
           dvs[i + 3] * w.w;
    }
    s += __shfl_xor(s, 1);
    s += __shfl_xor(s, 2);
    if (sub == 0) atomicAdd(orow + j, s);
  }
}

// ---------------------------------------------------------------------------
extern "C" void kernel_launch(void* const* d_in, const int* in_sizes, int n_in,
                              void* d_out, int out_size, void* d_ws,
                              size_t ws_size, hipStream_t stream) {
  const float* x    = (const float*)d_in[0];
  const float* Wq   = (const float*)d_in[1];
  const float* bq   = (const float*)d_in[2];
  const float* Wkv  = (const float*)d_in[3];
  const float* bkv  = (const float*)d_in[4];
  const float* Wout = (const float*)d_in[5];
  const float* bout = (const float*)d_in[6];
  const int*   idx  = (const int*)d_in[7];
  float* out = (float*)d_out;

  float* ws = (float*)d_ws;
  const size_t NQ = (size_t)B_ * H_ * L_ * DH_;  // 4,194,304 floats
  float* Q  = ws;
  float* Kt = Q + NQ;
  float* Vt = Kt + NQ;
  // W/X split region (live only through the GEMM)
  unsigned short* Whi = (unsigned short*)(Vt + NQ);  // 6 MB
  unsigned short* Wlo = Whi + (size_t)3 * D_ * D_;   // 6 MB
  unsigned short* Xhi = Wlo + (size_t)3 * D_ * D_;   // 8 MB (optional)
  unsigned short* Xlo = Xhi + NQ;                    // 8 MB (optional)
  // phase-2 region (overlaps split region; used only after the GEMM)
  float* S       = Vt + NQ;                          // 10 MB
  float* Mv      = S + (size_t)32 * U_ * L_;
  float* ctxPart = Mv + (size_t)B_ * H_ * L_;
  float* vmeanP  = ctxPart + (size_t)8 * 32 * U_ * DH_;
  float* baseB   = vmeanP + 32 * 8 * DH_;
  int*   topIdx  = (int*)(baseB + B_ * D_);

  const bool xsplit = ws_size >= ((size_t)76 << 20);  // Xhi/Xlo fit?
  const int nW = 3 * D_ * D_ / 4;                     // W quads
  const int nX = (int)(NQ / 4);                       // X quads

  if (xsplit) {
    split_all<<<dim3((nW + nX) / 256), dim3(256), 0, stream>>>(
        Wq, Wkv, x, Whi, Wlo, Xhi, Xlo, nW);
    gemm_qkv_mfma<true>
        <<<dim3(3 * D_ / 128, B_ * L_ / 128), dim3(256), 0, stream>>>(
            x, Xhi, Xlo, Whi, Wlo, bq, bkv, Q, Kt, Vt);
  } else {
    split_all<<<dim3(nW / 256), dim3(256), 0, stream>>>(Wq, Wkv, x, Whi, Wlo,
                                                        Xhi, Xlo, nW);
    gemm_qkv_mfma<false>
        <<<dim3(3 * D_ / 128, B_ * L_ / 128), dim3(256), 0, stream>>>(
            x, Xhi, Xlo, Whi, Wlo, bq, bkv, Q, Kt, Vt);
  }
  sample_m<<<dim3(B_ * H_ * L_ / 4), dim3(256), 0, stream>>>(Q, Kt, idx, Mv);
  topk_kernel<<<dim3(B_ * H_ / 4), dim3(256), 0, stream>>>(Mv, topIdx);
  score_kernel<<<dim3(8, 32), dim3(256), 0, stream>>>(Q, Kt, topIdx, S);
  softmax_kernel<<<dim3(32 * U_), dim3(256), 0, stream>>>(S);
  pv_kernel<<<dim3(8, 32), dim3(256), 0, stream>>>(S, Vt, ctxPart, vmeanP);
  base_kernel<<<dim3(B_ * 16), dim3(256), 0, stream>>>(vmeanP, Wout, bout,
                                                       baseB);
  bcast_out<<<dim3(B_ * L_ * D_ / 1024), dim3(256), 0, stream>>>(baseB, out);
  corr_kernel<<<dim3(B_ * H_ * U_), dim3(256), 0, stream>>>(topIdx, ctxPart,
                                                            vmeanP, Wout, out);
}

// Round 8
// 297.606 us; speedup vs baseline: 1.4357x; 1.0708x over previous
//
#include <hip/hip_runtime.h>
#include <math.h>

// Problem constants (B=2, L=2048, D=1024, H=16, FACTOR=5)
#define B_ 2
#define L_ 2048
#define D_ 1024
#define H_ 16
#define DH_ 64
#define U_ 40
#define SCALE_ 0.125f

typedef __attribute__((ext_vector_type(8))) short short8v;            // 8 bf16
typedef __attribute__((ext_vector_type(4))) float f32x4;
typedef __attribute__((ext_vector_type(4))) unsigned short ushort4v;  // 8 B

static __device__ __forceinline__ unsigned short bf16_rne(float f) {
  unsigned int u = __float_as_uint(f);
  u += 0x7fff + ((u >> 16) & 1);
  return (unsigned short)(u >> 16);
}
static __device__ __forceinline__ float bf16_f32(unsigned short h) {
  return __uint_as_float(((unsigned int)h) << 16);
}

// Async global->LDS, 16 B per lane. LDS dest is wave-uniform base + lane*16;
// global src is per-lane (pre-swizzled addresses give swizzled LDS).
static __device__ __forceinline__ void gload16(const unsigned short* src,
                                               unsigned short* lds) {
  __builtin_amdgcn_global_load_lds(
      (const __attribute__((address_space(1))) void*)src,
      (__attribute__((address_space(3))) void*)lds, 16, 0, 0);
}

// ---------------------------------------------------------------------------
// Pre-split f32 -> (hi,lo) bf16 for W=[Wq;Wkv] (quads [0,nW)) and X (rest).
// ---------------------------------------------------------------------------
__global__ __launch_bounds__(256) void split_all(
    const float* __restrict__ Wq, const float* __restrict__ Wkv,
    const float* __restrict__ X, unsigned short* __restrict__ Whi,
    unsigned short* __restrict__ Wlo, unsigned short* __restrict__ Xhi,
    unsigned short* __restrict__ Xlo, int nW) {
  int i = blockIdx.x * 256 + threadIdx.x;
  const int nq_q = (D_ * D_) / 4;
  float4 v;
  unsigned short *hi, *lo;
  int off;
  if (i < nW) {
    v = (i < nq_q) ? ((const float4*)Wq)[i] : ((const float4*)Wkv)[i - nq_q];
    hi = Whi; lo = Wlo; off = i;
  } else {
    off = i - nW;
    v = ((const float4*)X)[off];
    hi = Xhi; lo = Xlo;
  }
  float vv[4] = {v.x, v.y, v.z, v.w};
  ushort4v h, l;
#pragma unroll
  for (int e = 0; e < 4; ++e) {
    unsigned short hh = bf16_rne(vv[e]);
    h[e] = hh;
    l[e] = bf16_rne(vv[e] - bf16_f32(hh));
  }
  ((ushort4v*)hi)[off] = h;
  ((ushort4v*)lo)[off] = l;
}

// ---------------------------------------------------------------------------
// Split-bf16 MFMA GEMM for QKV (unchanged from round 7: gload_lds staging,
// XOR swizzle on source + read side, 0 bank conflicts).
// ---------------------------------------------------------------------------
template <bool XS>
__global__ __launch_bounds__(256) void gemm_qkv_mfma(
    const float* __restrict__ X,
    const unsigned short* __restrict__ Xhi,
    const unsigned short* __restrict__ Xlo,
    const unsigned short* __restrict__ Whi,
    const unsigned short* __restrict__ Wlo,
    const float* __restrict__ bq, const float* __restrict__ bkv,
    float* __restrict__ Qo, float* __restrict__ Ko, float* __restrict__ Vo) {
  __shared__ unsigned short Ah[128 * 32];
  __shared__ unsigned short Al[128 * 32];
  __shared__ unsigned short Bh[128 * 32];
  __shared__ unsigned short Bl[128 * 32];
  const int tid = threadIdx.x;
  const int lane = tid & 63;
  const int wave = tid >> 6;
  const int wm = wave >> 1, wn = wave & 1;
  const int row0 = blockIdx.y * 128;
  const int col0 = blockIdx.x * 128;

  f32x4 acc[4][4] = {};

  const int grow = lane >> 2;
  const int gg = lane & 3;

  for (int k0 = 0; k0 < D_; k0 += 32) {
#pragma unroll
    for (int j = 0; j < 2; ++j) {
      int c = wave + 4 * j;                     // 0..7
      int row = c * 16 + grow;                  // 0..127
      int gsrc = (gg ^ ((row >> 1) & 3)) << 3;  // swizzled source col
      size_t soffB = (size_t)(col0 + row) * D_ + k0 + gsrc;
      gload16(Whi + soffB, Bh + c * 512);
      gload16(Wlo + soffB, Bl + c * 512);
      if (XS) {
        size_t soffA = (size_t)(row0 + row) * D_ + k0 + gsrc;
        gload16(Xhi + soffA, Ah + c * 512);
        gload16(Xlo + soffA, Al + c * 512);
      }
    }
    if (!XS) {
#pragma unroll
      for (int rep = 0; rep < 2; ++rep) {
        int task = tid + rep * 256;  // 0..511
        int row = task >> 2;         // 0..127
        int gt = task & 3;           // true col group
        const float* s = X + (size_t)(row0 + row) * D_ + k0 + gt * 8;
        float4 a0 = *(const float4*)s;
        float4 a1 = *(const float4*)(s + 4);
        float av[8] = {a0.x, a0.y, a0.z, a0.w, a1.x, a1.y, a1.z, a1.w};
        short8v hseg, lseg;
#pragma unroll
        for (int e = 0; e < 8; ++e) {
          unsigned short hh = bf16_rne(av[e]);
          hseg[e] = (short)hh;
          lseg[e] = (short)bf16_rne(av[e] - bf16_f32(hh));
        }
        int dst = row * 32 + ((gt ^ ((row >> 1) & 3)) << 3);
        *(short8v*)&Ah[dst] = hseg;
        *(short8v*)&Al[dst] = lseg;
      }
    }
    __syncthreads();

    short8v a_h[4], a_l[4], b_h[4], b_l[4];
    const int hs = lane >> 4;  // true k-group 0..3
#pragma unroll
    for (int mi = 0; mi < 4; ++mi) {
      int rr = wm * 64 + mi * 16 + (lane & 15);
      int off = rr * 32 + ((hs ^ ((rr >> 1) & 3)) << 3);
      a_h[mi] = *(const short8v*)&Ah[off];
      a_l[mi] = *(const short8v*)&Al[off];
    }
#pragma unroll
    for (int ni = 0; ni < 4; ++ni) {
      int rc = wn * 64 + ni * 16 + (lane & 15);
      int off = rc * 32 + ((hs ^ ((rc >> 1) & 3)) << 3);
      b_h[ni] = *(const short8v*)&Bh[off];
      b_l[ni] = *(const short8v*)&Bl[off];
    }
#pragma unroll
    for (int mi = 0; mi < 4; ++mi)
#pragma unroll
      for (int ni = 0; ni < 4; ++ni) {
        acc[mi][ni] = __builtin_amdgcn_mfma_f32_16x16x32_bf16(
            a_h[mi], b_h[ni], acc[mi][ni], 0, 0, 0);
        acc[mi][ni] = __builtin_amdgcn_mfma_f32_16x16x32_bf16(
            a_h[mi], b_l[ni], acc[mi][ni], 0, 0, 0);
        acc[mi][ni] = __builtin_amdgcn_mfma_f32_16x16x32_bf16(
            a_l[mi], b_h[ni], acc[mi][ni], 0, 0, 0);
      }
    __syncthreads();
  }

#pragma unroll
  for (int ni = 0; ni < 4; ++ni) {
    int c = col0 + wn * 64 + ni * 16 + (lane & 15);
    int which = c >> 10;
    int jj = c & (D_ - 1);
    int h = jj >> 6, dh = jj & 63;
    float bias = (c < D_) ? bq[c] : bkv[c - D_];
    float* dst = (which == 0) ? Qo : ((which == 1) ? Ko : Vo);
#pragma unroll
    for (int mi = 0; mi < 4; ++mi) {
#pragma unroll
      for (int reg = 0; reg < 4; ++reg) {
        int r = row0 + wm * 64 + mi * 16 + ((lane >> 4) << 2) + reg;
        int b = r >> 11, l = r & (L_ - 1);
        dst[(((size_t)b * H_ + h) * L_ + l) * DH_ + dh] =
            acc[mi][ni][reg] + bias;
      }
    }
  }
}

// ---------------------------------------------------------------------------
// M[b,h,l] = max_u(QK) - mean_u(QK). Wave per l, shfl-broadcast indices,
// coalesced K staging into LDS (unchanged from round 6/7).
// ---------------------------------------------------------------------------
__global__ __launch_bounds__(256) void sample_m(
    const float* __restrict__ Q, const float* __restrict__ Kt,
    const int* __restrict__ idx, float* __restrict__ Mv) {
  __shared__ float Kst[4][U_][65];
  __shared__ float qs[4][DH_];
  int w = threadIdx.x >> 6, lane = threadIdx.x & 63;
  int gl = blockIdx.x * 4 + w;  // bh*L + l
  int bh = gl >> 11, l = gl & (L_ - 1);
  const float* Kb = Kt + (size_t)bh * L_ * DH_;
  qs[w][lane] = Q[(size_t)gl * DH_ + lane];
  int myKl = (lane < U_) ? idx[l * U_ + lane] : 0;
#pragma unroll
  for (int u = 0; u < U_; ++u) {
    int kl = __shfl(myKl, u);
    Kst[w][u][lane] = Kb[(size_t)kl * DH_ + lane];
  }
  __syncthreads();
  float mx = -INFINITY, sm = 0.f;
  if (lane < U_) {
    const float* kr = Kst[w][lane];
    const float* qq = qs[w];
    float d = 0.f;
#pragma unroll
    for (int i = 0; i < DH_; ++i) d += qq[i] * kr[i];
    mx = d;
    sm = d;
  }
#pragma unroll
  for (int off = 1; off < 64; off <<= 1) {
    mx = fmaxf(mx, __shfl_xor(mx, off));
    sm += __shfl_xor(sm, off);
  }
  if (lane == 0) Mv[gl] = mx - sm * (1.0f / U_);
}

// ---------------------------------------------------------------------------
// Per-(b,h) top-U_ of M: one wave per bh, shfl-only argmax.
// ---------------------------------------------------------------------------
__global__ __launch_bounds__(256) void topk_kernel(
    const float* __restrict__ Mv, int* __restrict__ topIdx) {
  __shared__ float vals[4][L_];
  int w = threadIdx.x >> 6, lane = threadIdx.x & 63;
  int bh = blockIdx.x * 4 + w;
  for (int j = 0; j < 32; ++j)
    vals[w][j * 64 + lane] = Mv[(size_t)bh * L_ + j * 64 + lane];
  for (int it = 0; it < U_; ++it) {
    float bv = -INFINITY;
    int bi = 0x7fffffff;
    for (int j = 0; j < 32; ++j) {
      int i = j * 64 + lane;
      float v = vals[w][i];
      if (v > bv) { bv = v; bi = i; }  // j ascending -> ties keep lower index
    }
#pragma unroll
    for (int off = 32; off > 0; off >>= 1) {
      float ov = __shfl_xor(bv, off);
      int oi = __shfl_xor(bi, off);
      if (ov > bv || (ov == bv && oi < bi)) { bv = ov; bi = oi; }
    }
    if (lane == 0) {
      topIdx[bh * U_ + it] = bi;
      vals[w][bi] = -INFINITY;
    }
  }
}

// ---------------------------------------------------------------------------
// Fused attention tail: per (qc, bh) block handles 5 selected queries:
//   pass 1: scores (5 x 2048) into LDS (thread = key)
//   pass 2: in-wave softmax (max/exp/sum, no barrier trees)
//   pass 3: PV with b128-broadcast P reads; wave = 512-key slice
// vmean computed by qc==0 blocks while streaming V. S never hits global.
// ---------------------------------------------------------------------------
__global__ __launch_bounds__(256) void attn_fused(
    const float* __restrict__ Q, const float* __restrict__ Kt,
    const float* __restrict__ Vt, const int* __restrict__ topIdx,
    float* __restrict__ ctxUpd, float* __restrict__ vmeanM) {
  int qc = blockIdx.x;  // 0..7 (5 queries each)
  int bh = blockIdx.y;  // 0..31
  __shared__ float Qs[5][DH_];
  __shared__ float Sv[5][L_];        // 40 KB
  __shared__ float part[4][5][DH_];  // 5 KB
  __shared__ float inv[5];
  __shared__ float vs[4][DH_];
  int t = threadIdx.x;
  int lane = t & 63, w = t >> 6;

  if (t < 80) {  // stage 5 Q rows (float4 tasks)
    int q = t >> 4, c4 = t & 15;
    int ql = topIdx[bh * U_ + qc * 5 + q];
    *(float4*)&Qs[q][c4 * 4] =
        *(const float4*)&Q[((size_t)bh * L_ + ql) * DH_ + c4 * 4];
  }
  __syncthreads();

  // ---- pass 1: scores, thread = key in chunk
  const float* Kb = Kt + (size_t)bh * L_ * DH_;
  for (int kc = 0; kc < 8; ++kc) {
    int key = kc * 256 + t;
    const float* kr = Kb + (size_t)key * DH_;
    float acc[5];
#pragma unroll
    for (int q = 0; q < 5; ++q) acc[q] = 0.f;
#pragma unroll
    for (int i4 = 0; i4 < 16; ++i4) {
      float4 k4 = *(const float4*)(kr + i4 * 4);
#pragma unroll
      for (int q = 0; q < 5; ++q) {
        float4 qv = *(const float4*)&Qs[q][i4 * 4];
        acc[q] += k4.x * qv.x + k4.y * qv.y + k4.z * qv.z + k4.w * qv.w;
      }
    }
#pragma unroll
    for (int q = 0; q < 5; ++q) Sv[q][key] = acc[q] * SCALE_;
  }
  __syncthreads();

  // ---- pass 2: softmax. Wave w owns row w; wave 0 also row 4. In-wave only.
#pragma unroll
  for (int rep = 0; rep < 2; ++rep) {
    int r = (rep == 0) ? w : (w == 0 ? 4 : -1);
    if (r >= 0) {
      float mx = -INFINITY;
      for (int j = 0; j < 32; ++j) mx = fmaxf(mx, Sv[r][j * 64 + lane]);
#pragma unroll
      for (int off = 1; off < 64; off <<= 1)
        mx = fmaxf(mx, __shfl_xor(mx, off));
      float sm = 0.f;
      for (int j = 0; j < 32; ++j) {
        float e = __expf(Sv[r][j * 64 + lane] - mx);
        Sv[r][j * 64 + lane] = e;
        sm += e;
      }
#pragma unroll
      for (int off = 1; off < 64; off <<= 1) sm += __shfl_xor(sm, off);
      if (lane == 0) inv[r] = 1.0f / sm;
    }
  }
  __syncthreads();

  // ---- pass 3: PV. Wave w covers keys [w*512, w*512+512), lane = dh.
  {
    const float* vb = Vt + ((size_t)bh * L_ + w * 512) * DH_ + lane;
    float acc[5];
#pragma unroll
    for (int q = 0; q < 5; ++q) acc[q] = 0.f;
    float vsum = 0.f;
    for (int k4 = 0; k4 < 128; ++k4) {
      float v0 = vb[(k4 * 4 + 0) * DH_];
      float v1 = vb[(k4 * 4 + 1) * DH_];
      float v2 = vb[(k4 * 4 + 2) * DH_];
      float v3 = vb[(k4 * 4 + 3) * DH_];
      vsum += (v0 + v1) + (v2 + v3);
      int k = w * 512 + k4 * 4;
#pragma unroll
      for (int q = 0; q < 5; ++q) {
        float4 p4 = *(const float4*)&Sv[q][k];
        acc[q] += p4.x * v0 + p4.y * v1 + p4.z * v2 + p4.w * v3;
      }
    }
#pragma unroll
    for (int q = 0; q < 5; ++q) part[w][q][lane] = acc[q];
    vs[w][lane] = vsum;
  }
  __syncthreads();

  // combine partials -> ctxUpd
  for (int o = t; o < 5 * DH_; o += 256) {
    int q = o >> 6, dh = o & 63;
    float s = (part[0][q][dh] + part[1][q][dh]) +
              (part[2][q][dh] + part[3][q][dh]);
    ctxUpd[((size_t)bh * U_ + qc * 5 + q) * DH_ + dh] = s * inv[q];
  }
  if (qc == 0 && t < DH_)
    vmeanM[bh * DH_ + t] =
        ((vs[0][t] + vs[1][t]) + (vs[2][t] + vs[3][t])) * (1.0f / L_);
}

// ---------------------------------------------------------------------------
// base[b][j] = vmean_flat[b] . Wout[j] + bout[j]
// ---------------------------------------------------------------------------
__global__ __launch_bounds__(256) void base_kernel(
    const float* __restrict__ vmeanM, const float* __restrict__ Wout,
    const float* __restrict__ bout, float* __restrict__ baseOut) {
  int bid = blockIdx.x;
  int b = bid >> 4, jc = bid & 15;
  int t = threadIdx.x;
  int j = jc * 64 + (t & 63);
  int isl = t >> 6;
  __shared__ float vm[D_];
  __shared__ float red[256];
  for (int i = t; i < D_; i += 256) vm[i] = vmeanM[b * D_ + i];
  __syncthreads();
  float s = 0.f;
  const float* wr = Wout + (size_t)j * D_ + isl * 256;
  const float* vv = vm + isl * 256;
  for (int i = 0; i < 256; i += 4) {
    float4 w = *(const float4*)(wr + i);
    s += vv[i] * w.x + vv[i + 1] * w.y + vv[i + 2] * w.z + vv[i + 3] * w.w;
  }
  red[t] = s; __syncthreads();
  if (isl == 0)
    baseOut[b * D_ + j] =
        red[t] + red[t + 64] + red[t + 128] + red[t + 192] + bout[j];
}

// ---------------------------------------------------------------------------
// out[b,l,:] = base[b,:]
// ---------------------------------------------------------------------------
__global__ __launch_bounds__(256) void bcast_out(
    const float* __restrict__ baseIn, float* __restrict__ out) {
  size_t i4 = (size_t)blockIdx.x * 256 + threadIdx.x;
  size_t i = i4 * 4;
  int b = (int)(i >> 21);
  int col = (int)(i & (D_ - 1));
  *(float4*)(out + i) = *(const float4*)(baseIn + b * D_ + col);
}

// ---------------------------------------------------------------------------
// out[b, l_u, :] += (ctxUpd[b,h,u] - vmean[b,h]) . Wout[:, h*64:(h+1)*64]^T
// ---------------------------------------------------------------------------
__global__ __launch_bounds__(256) void corr_kernel(
    const int* __restrict__ topIdx, const float* __restrict__ ctxUpd,
    const float* __restrict__ vmeanM, const float* __restrict__ Wout,
    float* __restrict__ out) {
  int bhu = blockIdx.x;
  int bh = bhu / U_;
  int u = bhu - bh * U_;
  int h = bh & (H_ - 1), b = bh >> 4;
  int l = topIdx[bhu];
  __shared__ float dv[DH_];
  int t = threadIdx.x;
  if (t < DH_)
    dv[t] = ctxUpd[(size_t)bhu * DH_ + t] - vmeanM[bh * DH_ + t];
  __syncthreads();
  int sub = t & 3;
  int jbase = t >> 2;
  float* orow = out + ((size_t)b * L_ + l) * D_;
  const float* dvs = dv + sub * 16;
#pragma unroll
  for (int jc = 0; jc < 16; ++jc) {
    int j = jc * 64 + jbase;
    const float* wr = Wout + (size_t)j * D_ + h * DH_ + sub * 16;
    float s = 0.f;
#pragma unroll
    for (int i = 0; i < 16; i += 4) {
      float4 w = *(const float4*)(wr + i);
      s += dvs[i] * w.x + dvs[i + 1] * w.y + dvs[i + 2] * w.z +
           dvs[i + 3] * w.w;
    }
    s += __shfl_xor(s, 1);
    s += __shfl_xor(s, 2);
    if (sub == 0) atomicAdd(orow + j, s);
  }
}

// ---------------------------------------------------------------------------
extern "C" void kernel_launch(void* const* d_in, const int* in_sizes, int n_in,
                              void* d_out, int out_size, void* d_ws,
                              size_t ws_size, hipStream_t stream) {
  const float* x    = (const float*)d_in[0];
  const float* Wq   = (const float*)d_in[1];
  const float* bq   = (const float*)d_in[2];
  const float* Wkv  = (const float*)d_in[3];
  const float* bkv  = (const float*)d_in[4];
  const float* Wout = (const float*)d_in[5];
  const float* bout = (const float*)d_in[6];
  const int*   idx  = (const int*)d_in[7];
  float* out = (float*)d_out;

  float* ws = (float*)d_ws;
  const size_t NQ = (size_t)B_ * H_ * L_ * DH_;  // 4,194,304 floats
  float* Q  = ws;
  float* Kt = Q + NQ;
  float* Vt = Kt + NQ;
  // W/X split region (live only through the GEMM)
  unsigned short* Whi = (unsigned short*)(Vt + NQ);  // 6 MB
  unsigned short* Wlo = Whi + (size_t)3 * D_ * D_;   // 6 MB
  unsigned short* Xhi = Wlo + (size_t)3 * D_ * D_;   // 8 MB (optional)
  unsigned short* Xlo = Xhi + NQ;                    // 8 MB (optional)
  // phase-2 region (overlaps split region; used only after the GEMM)
  float* Mv     = Vt + NQ;                           // 256 KB
  float* ctxUpd = Mv + (size_t)B_ * H_ * L_;         // 320 KB
  float* vmeanM = ctxUpd + (size_t)32 * U_ * DH_;    // 8 KB
  float* baseB  = vmeanM + 32 * DH_;                 // 8 KB
  int*   topIdx = (int*)(baseB + B_ * D_);           // 5 KB

  const bool xsplit = ws_size >= ((size_t)76 << 20);  // Xhi/Xlo fit?
  const int nW = 3 * D_ * D_ / 4;                     // W quads
  const int nX = (int)(NQ / 4);                       // X quads

  if (xsplit) {
    split_all<<<dim3((nW + nX) / 256), dim3(256), 0, stream>>>(
        Wq, Wkv, x, Whi, Wlo, Xhi, Xlo, nW);
    gemm_qkv_mfma<true>
        <<<dim3(3 * D_ / 128, B_ * L_ / 128), dim3(256), 0, stream>>>(
            x, Xhi, Xlo, Whi, Wlo, bq, bkv, Q, Kt, Vt);
  } else {
    split_all<<<dim3(nW / 256), dim3(256), 0, stream>>>(Wq, Wkv, x, Whi, Wlo,
                                                        Xhi, Xlo, nW);
    gemm_qkv_mfma<false>
        <<<dim3(3 * D_ / 128, B_ * L_ / 128), dim3(256), 0, stream>>>(
            x, Xhi, Xlo, Whi, Wlo, bq, bkv, Q, Kt, Vt);
  }
  sample_m<<<dim3(B_ * H_ * L_ / 4), dim3(256), 0, stream>>>(Q, Kt, idx, Mv);
  topk_kernel<<<dim3(B_ * H_ / 4), dim3(256), 0, stream>>>(Mv, topIdx);
  attn_fused<<<dim3(8, 32), dim3(256), 0, stream>>>(Q, Kt, Vt, topIdx, ctxUpd,
                                                    vmeanM);
  base_kernel<<<dim3(B_ * 16), dim3(256), 0, stream>>>(vmeanM, Wout, bout,
                                                       baseB);
  bcast_out<<<dim3(B_ * L_ * D_ / 1024), dim3(256), 0, stream>>>(baseB, out);
  corr_kernel<<<dim3(B_ * H_ * U_), dim3(256), 0, stream>>>(topIdx, ctxUpd,
                                                            vmeanM, Wout, out);
}

// Round 9
// 264.321 us; speedup vs baseline: 1.6165x; 1.1259x over previous
//
#include <hip/hip_runtime.h>
#include <math.h>

// Problem constants (B=2, L=2048, D=1024, H=16, FACTOR=5)
#define B_ 2
#define L_ 2048
#define D_ 1024
#define H_ 16
#define DH_ 64
#define U_ 40
#define SCALE_ 0.125f

typedef __attribute__((ext_vector_type(8))) short short8v;            // 8 bf16
typedef __attribute__((ext_vector_type(4))) float f32x4;
typedef __attribute__((ext_vector_type(4))) unsigned short ushort4v;  // 8 B

static __device__ __forceinline__ unsigned short bf16_rne(float f) {
  unsigned int u = __float_as_uint(f);
  u += 0x7fff + ((u >> 16) & 1);
  return (unsigned short)(u >> 16);
}
static __device__ __forceinline__ float bf16_f32(unsigned short h) {
  return __uint_as_float(((unsigned int)h) << 16);
}

// Async global->LDS, 16 B per lane. LDS dest is wave-uniform base + lane*16;
// global src is per-lane (pre-swizzled addresses give swizzled LDS).
static __device__ __forceinline__ void gload16(const unsigned short* src,
                                               unsigned short* lds) {
  __builtin_amdgcn_global_load_lds(
      (const __attribute__((address_space(1))) void*)src,
      (__attribute__((address_space(3))) void*)lds, 16, 0, 0);
}

// ---------------------------------------------------------------------------
// Pre-split f32 -> (hi,lo) bf16 for W=[Wq;Wkv] (quads [0,nW)) and X (rest).
// ---------------------------------------------------------------------------
__global__ __launch_bounds__(256) void split_all(
    const float* __restrict__ Wq, const float* __restrict__ Wkv,
    const float* __restrict__ X, unsigned short* __restrict__ Whi,
    unsigned short* __restrict__ Wlo, unsigned short* __restrict__ Xhi,
    unsigned short* __restrict__ Xlo, int nW) {
  int i = blockIdx.x * 256 + threadIdx.x;
  const int nq_q = (D_ * D_) / 4;
  float4 v;
  unsigned short *hi, *lo;
  int off;
  if (i < nW) {
    v = (i < nq_q) ? ((const float4*)Wq)[i] : ((const float4*)Wkv)[i - nq_q];
    hi = Whi; lo = Wlo; off = i;
  } else {
    off = i - nW;
    v = ((const float4*)X)[off];
    hi = Xhi; lo = Xlo;
  }
  float vv[4] = {v.x, v.y, v.z, v.w};
  ushort4v h, l;
#pragma unroll
  for (int e = 0; e < 4; ++e) {
    unsigned short hh = bf16_rne(vv[e]);
    h[e] = hh;
    l[e] = bf16_rne(vv[e] - bf16_f32(hh));
  }
  ((ushort4v*)hi)[off] = h;
  ((ushort4v*)lo)[off] = l;
}

// ---------------------------------------------------------------------------
// Split-bf16 MFMA GEMM for QKV (unchanged from round 7: gload_lds staging,
// XOR swizzle on source + read side, 0 bank conflicts).
// ---------------------------------------------------------------------------
template <bool XS>
__global__ __launch_bounds__(256) void gemm_qkv_mfma(
    const float* __restrict__ X,
    const unsigned short* __restrict__ Xhi,
    const unsigned short* __restrict__ Xlo,
    const unsigned short* __restrict__ Whi,
    const unsigned short* __restrict__ Wlo,
    const float* __restrict__ bq, const float* __restrict__ bkv,
    float* __restrict__ Qo, float* __restrict__ Ko, float* __restrict__ Vo) {
  __shared__ unsigned short Ah[128 * 32];
  __shared__ unsigned short Al[128 * 32];
  __shared__ unsigned short Bh[128 * 32];
  __shared__ unsigned short Bl[128 * 32];
  const int tid = threadIdx.x;
  const int lane = tid & 63;
  const int wave = tid >> 6;
  const int wm = wave >> 1, wn = wave & 1;
  const int row0 = blockIdx.y * 128;
  const int col0 = blockIdx.x * 128;

  f32x4 acc[4][4] = {};

  const int grow = lane >> 2;
  const int gg = lane & 3;

  for (int k0 = 0; k0 < D_; k0 += 32) {
#pragma unroll
    for (int j = 0; j < 2; ++j) {
      int c = wave + 4 * j;                     // 0..7
      int row = c * 16 + grow;                  // 0..127
      int gsrc = (gg ^ ((row >> 1) & 3)) << 3;  // swizzled source col
      size_t soffB = (size_t)(col0 + row) * D_ + k0 + gsrc;
      gload16(Whi + soffB, Bh + c * 512);
      gload16(Wlo + soffB, Bl + c * 512);
      if (XS) {
        size_t soffA = (size_t)(row0 + row) * D_ + k0 + gsrc;
        gload16(Xhi + soffA, Ah + c * 512);
        gload16(Xlo + soffA, Al + c * 512);
      }
    }
    if (!XS) {
#pragma unroll
      for (int rep = 0; rep < 2; ++rep) {
        int task = tid + rep * 256;  // 0..511
        int row = task >> 2;         // 0..127
        int gt = task & 3;           // true col group
        const float* s = X + (size_t)(row0 + row) * D_ + k0 + gt * 8;
        float4 a0 = *(const float4*)s;
        float4 a1 = *(const float4*)(s + 4);
        float av[8] = {a0.x, a0.y, a0.z, a0.w, a1.x, a1.y, a1.z, a1.w};
        short8v hseg, lseg;
#pragma unroll
        for (int e = 0; e < 8; ++e) {
          unsigned short hh = bf16_rne(av[e]);
          hseg[e] = (short)hh;
          lseg[e] = (short)bf16_rne(av[e] - bf16_f32(hh));
        }
        int dst = row * 32 + ((gt ^ ((row >> 1) & 3)) << 3);
        *(short8v*)&Ah[dst] = hseg;
        *(short8v*)&Al[dst] = lseg;
      }
    }
    __syncthreads();

    short8v a_h[4], a_l[4], b_h[4], b_l[4];
    const int hs = lane >> 4;  // true k-group 0..3
#pragma unroll
    for (int mi = 0; mi < 4; ++mi) {
      int rr = wm * 64 + mi * 16 + (lane & 15);
      int off = rr * 32 + ((hs ^ ((rr >> 1) & 3)) << 3);
      a_h[mi] = *(const short8v*)&Ah[off];
      a_l[mi] = *(const short8v*)&Al[off];
    }
#pragma unroll
    for (int ni = 0; ni < 4; ++ni) {
      int rc = wn * 64 + ni * 16 + (lane & 15);
      int off = rc * 32 + ((hs ^ ((rc >> 1) & 3)) << 3);
      b_h[ni] = *(const short8v*)&Bh[off];
      b_l[ni] = *(const short8v*)&Bl[off];
    }
#pragma unroll
    for (int mi = 0; mi < 4; ++mi)
#pragma unroll
      for (int ni = 0; ni < 4; ++ni) {
        acc[mi][ni] = __builtin_amdgcn_mfma_f32_16x16x32_bf16(
            a_h[mi], b_h[ni], acc[mi][ni], 0, 0, 0);
        acc[mi][ni] = __builtin_amdgcn_mfma_f32_16x16x32_bf16(
            a_h[mi], b_l[ni], acc[mi][ni], 0, 0, 0);
        acc[mi][ni] = __builtin_amdgcn_mfma_f32_16x16x32_bf16(
            a_l[mi], b_h[ni], acc[mi][ni], 0, 0, 0);
      }
    __syncthreads();
  }

#pragma unroll
  for (int ni = 0; ni < 4; ++ni) {
    int c = col0 + wn * 64 + ni * 16 + (lane & 15);
    int which = c >> 10;
    int jj = c & (D_ - 1);
    int h = jj >> 6, dh = jj & 63;
    float bias = (c < D_) ? bq[c] : bkv[c - D_];
    float* dst = (which == 0) ? Qo : ((which == 1) ? Ko : Vo);
#pragma unroll
    for (int mi = 0; mi < 4; ++mi) {
#pragma unroll
      for (int reg = 0; reg < 4; ++reg) {
        int r = row0 + wm * 64 + mi * 16 + ((lane >> 4) << 2) + reg;
        int b = r >> 11, l = r & (L_ - 1);
        dst[(((size_t)b * H_ + h) * L_ + l) * DH_ + dh] =
            acc[mi][ni][reg] + bias;
      }
    }
  }
}

// ---------------------------------------------------------------------------
// M[b,h,l] = max_u(QK) - mean_u(QK). Registers-only: wave handles 4 l's,
// lane = (sub_l, d16); Q row = 1 float4/lane; per u gather K row as float4
// (one instr stages 4 rows) and reduce within the 16-lane group via shfl.
// No LDS, no barriers, no register arrays (rule #20 safe).
// ---------------------------------------------------------------------------
__global__ __launch_bounds__(256) void sample_m(
    const float* __restrict__ Q, const float* __restrict__ Kt,
    const int* __restrict__ idx, float* __restrict__ Mv) {
  int t = threadIdx.x;
  int w = t >> 6, lane = t & 63;
  int subl = lane >> 4, d16 = lane & 15;
  int gl = blockIdx.x * 16 + w * 4 + subl;  // bh*L + l
  int bh = gl >> 11, l = gl & (L_ - 1);
  const float4* Kb4 = (const float4*)(Kt + (size_t)bh * L_ * DH_);
  float4 q4 = ((const float4*)(Q + (size_t)gl * DH_))[d16];
  const int* irow = idx + l * U_;
  float mx = -INFINITY, sm = 0.f;
#pragma unroll 8
  for (int u = 0; u < U_; ++u) {
    int kl = irow[u];
    float4 k4 = Kb4[kl * 16 + d16];
    float p = q4.x * k4.x + q4.y * k4.y + q4.z * k4.z + q4.w * k4.w;
    p += __shfl_xor(p, 1);
    p += __shfl_xor(p, 2);
    p += __shfl_xor(p, 4);
    p += __shfl_xor(p, 8);
    mx = fmaxf(mx, p);
    sm += p;
  }
  if (d16 == 0) Mv[gl] = mx - sm * (1.0f / U_);
}

// ---------------------------------------------------------------------------
// Per-(b,h) top-U_ of M: one 64-thread block (one wave) per bh, shfl argmax.
// ---------------------------------------------------------------------------
__global__ __launch_bounds__(64) void topk_kernel(
    const float* __restrict__ Mv, int* __restrict__ topIdx) {
  __shared__ float vals[L_];
  int lane = threadIdx.x;
  int bh = blockIdx.x;
  for (int j = 0; j < 32; ++j)
    vals[j * 64 + lane] = Mv[(size_t)bh * L_ + j * 64 + lane];
  __syncthreads();
  for (int it = 0; it < U_; ++it) {
    float bv = -INFINITY;
    int bi = 0x7fffffff;
    for (int j = 0; j < 32; ++j) {
      int i = j * 64 + lane;
      float v = vals[i];
      if (v > bv) { bv = v; bi = i; }  // j ascending -> ties keep lower index
    }
#pragma unroll
    for (int off = 32; off > 0; off >>= 1) {
      float ov = __shfl_xor(bv, off);
      int oi = __shfl_xor(bi, off);
      if (ov > bv || (ov == bv && oi < bi)) { bv = ov; bi = oi; }
    }
    if (lane == 0) topIdx[bh * U_ + it] = bi;
    vals[bi] = -INFINITY;  // all lanes agree on bi; same-wave LDS is ordered
    __syncthreads();
  }
}

// ---------------------------------------------------------------------------
// Fused attention tail: per (qc, bh) block handles 5 selected queries:
//   pass 1: scores (5 x 2048) into LDS (thread = key)
//   pass 2: in-wave softmax  pass 3: PV with b128-broadcast P reads
// vmean computed by qc==0 blocks while streaming V. S never hits global.
// ---------------------------------------------------------------------------
__global__ __launch_bounds__(256) void attn_fused(
    const float* __restrict__ Q, const float* __restrict__ Kt,
    const float* __restrict__ Vt, const int* __restrict__ topIdx,
    float* __restrict__ ctxUpd, float* __restrict__ vmeanM) {
  int qc = blockIdx.x;  // 0..7 (5 queries each)
  int bh = blockIdx.y;  // 0..31
  __shared__ float Qs[5][DH_];
  __shared__ float Sv[5][L_];        // 40 KB
  __shared__ float part[4][5][DH_];  // 5 KB
  __shared__ float inv[5];
  __shared__ float vs[4][DH_];
  int t = threadIdx.x;
  int lane = t & 63, w = t >> 6;

  if (t < 80) {  // stage 5 Q rows (float4 tasks)
    int q = t >> 4, c4 = t & 15;
    int ql = topIdx[bh * U_ + qc * 5 + q];
    *(float4*)&Qs[q][c4 * 4] =
        *(const float4*)&Q[((size_t)bh * L_ + ql) * DH_ + c4 * 4];
  }
  __syncthreads();

  // ---- pass 1: scores, thread = key in chunk
  const float* Kb = Kt + (size_t)bh * L_ * DH_;
  for (int kc = 0; kc < 8; ++kc) {
    int key = kc * 256 + t;
    const float* kr = Kb + (size_t)key * DH_;
    float acc[5];
#pragma unroll
    for (int q = 0; q < 5; ++q) acc[q] = 0.f;
#pragma unroll
    for (int i4 = 0; i4 < 16; ++i4) {
      float4 k4 = *(const float4*)(kr + i4 * 4);
#pragma unroll
      for (int q = 0; q < 5; ++q) {
        float4 qv = *(const float4*)&Qs[q][i4 * 4];
        acc[q] += k4.x * qv.x + k4.y * qv.y + k4.z * qv.z + k4.w * qv.w;
      }
    }
#pragma unroll
    for (int q = 0; q < 5; ++q) Sv[q][key] = acc[q] * SCALE_;
  }
  __syncthreads();

  // ---- pass 2: softmax. Wave w owns row w; wave 0 also row 4.
#pragma unroll
  for (int rep = 0; rep < 2; ++rep) {
    int r = (rep == 0) ? w : (w == 0 ? 4 : -1);
    if (r >= 0) {
      float mx = -INFINITY;
      for (int j = 0; j < 32; ++j) mx = fmaxf(mx, Sv[r][j * 64 + lane]);
#pragma unroll
      for (int off = 1; off < 64; off <<= 1)
        mx = fmaxf(mx, __shfl_xor(mx, off));
      float sm = 0.f;
      for (int j = 0; j < 32; ++j) {
        float e = __expf(Sv[r][j * 64 + lane] - mx);
        Sv[r][j * 64 + lane] = e;
        sm += e;
      }
#pragma unroll
      for (int off = 1; off < 64; off <<= 1) sm += __shfl_xor(sm, off);
      if (lane == 0) inv[r] = 1.0f / sm;
    }
  }
  __syncthreads();

  // ---- pass 3: PV. Wave w covers keys [w*512, w*512+512), lane = dh.
  {
    const float* vb = Vt + ((size_t)bh * L_ + w * 512) * DH_ + lane;
    float acc[5];
#pragma unroll
    for (int q = 0; q < 5; ++q) acc[q] = 0.f;
    float vsum = 0.f;
    for (int k4 = 0; k4 < 128; ++k4) {
      float v0 = vb[(k4 * 4 + 0) * DH_];
      float v1 = vb[(k4 * 4 + 1) * DH_];
      float v2 = vb[(k4 * 4 + 2) * DH_];
      float v3 = vb[(k4 * 4 + 3) * DH_];
      vsum += (v0 + v1) + (v2 + v3);
      int k = w * 512 + k4 * 4;
#pragma unroll
      for (int q = 0; q < 5; ++q) {
        float4 p4 = *(const float4*)&Sv[q][k];
        acc[q] += p4.x * v0 + p4.y * v1 + p4.z * v2 + p4.w * v3;
      }
    }
#pragma unroll
    for (int q = 0; q < 5; ++q) part[w][q][lane] = acc[q];
    vs[w][lane] = vsum;
  }
  __syncthreads();

  for (int o = t; o < 5 * DH_; o += 256) {
    int q = o >> 6, dh = o & 63;
    float s = (part[0][q][dh] + part[1][q][dh]) +
              (part[2][q][dh] + part[3][q][dh]);
    ctxUpd[((size_t)bh * U_ + qc * 5 + q) * DH_ + dh] = s * inv[q];
  }
  if (qc == 0 && t < DH_)
    vmeanM[bh * DH_ + t] =
        ((vs[0][t] + vs[1][t]) + (vs[2][t] + vs[3][t])) * (1.0f / L_);
}

// ---------------------------------------------------------------------------
// base[b][j] = vmean_flat[b] . Wout[j] + bout[j]
// ---------------------------------------------------------------------------
__global__ __launch_bounds__(256) void base_kernel(
    const float* __restrict__ vmeanM, const float* __restrict__ Wout,
    const float* __restrict__ bout, float* __restrict__ baseOut) {
  int bid = blockIdx.x;
  int b = bid >> 4, jc = bid & 15;
  int t = threadIdx.x;
  int j = jc * 64 + (t & 63);
  int isl = t >> 6;
  __shared__ float vm[D_];
  __shared__ float red[256];
  for (int i = t; i < D_; i += 256) vm[i] = vmeanM[b * D_ + i];
  __syncthreads();
  float s = 0.f;
  const float* wr = Wout + (size_t)j * D_ + isl * 256;
  const float* vv = vm + isl * 256;
  for (int i = 0; i < 256; i += 4) {
    float4 w = *(const float4*)(wr + i);
    s += vv[i] * w.x + vv[i + 1] * w.y + vv[i + 2] * w.z + vv[i + 3] * w.w;
  }
  red[t] = s; __syncthreads();
  if (isl == 0)
    baseOut[b * D_ + j] =
        red[t] + red[t + 64] + red[t + 128] + red[t + 192] + bout[j];
}

// ---------------------------------------------------------------------------
// out[b,l,:] = base[b,:]
// ---------------------------------------------------------------------------
__global__ __launch_bounds__(256) void bcast_out(
    const float* __restrict__ baseIn, float* __restrict__ out) {
  size_t i4 = (size_t)blockIdx.x * 256 + threadIdx.x;
  size_t i = i4 * 4;
  int b = (int)(i >> 21);
  int col = (int)(i & (D_ - 1));
  *(float4*)(out + i) = *(const float4*)(baseIn + b * D_ + col);
}

// ---------------------------------------------------------------------------
// out[b, l_u, :] += (ctxUpd[b,h,u] - vmean[b,h]) . Wout[:, h*64:(h+1)*64]^T
// ---------------------------------------------------------------------------
__global__ __launch_bounds__(256) void corr_kernel(
    const int* __restrict__ topIdx, const float* __restrict__ ctxUpd,
    const float* __restrict__ vmeanM, const float* __restrict__ Wout,
    float* __restrict__ out) {
  int bhu = blockIdx.x;
  int bh = bhu / U_;
  int u = bhu - bh * U_;
  int h = bh & (H_ - 1), b = bh >> 4;
  int l = topIdx[bhu];
  __shared__ float dv[DH_];
  int t = threadIdx.x;
  if (t < DH_)
    dv[t] = ctxUpd[(size_t)bhu * DH_ + t] - vmeanM[bh * DH_ + t];
  __syncthreads();
  int sub = t & 3;
  int jbase = t >> 2;
  float* orow = out + ((size_t)b * L_ + l) * D_;
  const float* dvs = dv + sub * 16;
#pragma unroll
  for (int jc = 0; jc < 16; ++jc) {
    int j = jc * 64 + jbase;
    const float* wr = Wout + (size_t)j * D_ + h * DH_ + sub * 16;
    float s = 0.f;
#pragma unroll
    for (int i = 0; i < 16; i += 4) {
      float4 w = *(const float4*)(wr + i);
      s += dvs[i] * w.x + dvs[i + 1] * w.y + dvs[i + 2] * w.z +
           dvs[i + 3] * w.w;
    }
    s += __shfl_xor(s, 1);
    s += __shfl_xor(s, 2);
    if (sub == 0) atomicAdd(orow + j, s);
  }
}

// ---------------------------------------------------------------------------
extern "C" void kernel_launch(void* const* d_in, const int* in_sizes, int n_in,
                              void* d_out, int out_size, void* d_ws,
                              size_t ws_size, hipStream_t stream) {
  const float* x    = (const float*)d_in[0];
  const float* Wq   = (const float*)d_in[1];
  const float* bq   = (const float*)d_in[2];
  const float* Wkv  = (const float*)d_in[3];
  const float* bkv  = (const float*)d_in[4];
  const float* Wout = (const float*)d_in[5];
  const float* bout = (const float*)d_in[6];
  const int*   idx  = (const int*)d_in[7];
  float* out = (float*)d_out;

  float* ws = (float*)d_ws;
  const size_t NQ = (size_t)B_ * H_ * L_ * DH_;  // 4,194,304 floats
  float* Q  = ws;
  float* Kt = Q + NQ;
  float* Vt = Kt + NQ;
  // W/X split region (live only through the GEMM)
  unsigned short* Whi = (unsigned short*)(Vt + NQ);  // 6 MB
  unsigned short* Wlo = Whi + (size_t)3 * D_ * D_;   // 6 MB
  unsigned short* Xhi = Wlo + (size_t)3 * D_ * D_;   // 8 MB (optional)
  unsigned short* Xlo = Xhi + NQ;                    // 8 MB (optional)
  // phase-2 region (overlaps split region; used only after the GEMM)
  float* Mv     = Vt + NQ;                           // 256 KB
  float* ctxUpd = Mv + (size_t)B_ * H_ * L_;         // 320 KB
  float* vmeanM = ctxUpd + (size_t)32 * U_ * DH_;    // 8 KB
  float* baseB  = vmeanM + 32 * DH_;                 // 8 KB
  int*   topIdx = (int*)(baseB + B_ * D_);           // 5 KB

  const bool xsplit = ws_size >= ((size_t)76 << 20);  // Xhi/Xlo fit?
  const int nW = 3 * D_ * D_ / 4;                     // W quads
  const int nX = (int)(NQ / 4);                       // X quads

  if (xsplit) {
    split_all<<<dim3((nW + nX) / 256), dim3(256), 0, stream>>>(
        Wq, Wkv, x, Whi, Wlo, Xhi, Xlo, nW);
    gemm_qkv_mfma<true>
        <<<dim3(3 * D_ / 128, B_ * L_ / 128), dim3(256), 0, stream>>>(
            x, Xhi, Xlo, Whi, Wlo, bq, bkv, Q, Kt, Vt);
  } else {
    split_all<<<dim3(nW / 256), dim3(256), 0, stream>>>(Wq, Wkv, x, Whi, Wlo,
                                                        Xhi, Xlo, nW);
    gemm_qkv_mfma<false>
        <<<dim3(3 * D_ / 128, B_ * L_ / 128), dim3(256), 0, stream>>>(
            x, Xhi, Xlo, Whi, Wlo, bq, bkv, Q, Kt, Vt);
  }
  sample_m<<<dim3(B_ * H_ * L_ / 16), dim3(256), 0, stream>>>(Q, Kt, idx, Mv);
  topk_kernel<<<dim3(B_ * H_), dim3(64), 0, stream>>>(Mv, topIdx);
  attn_fused<<<dim3(8, 32), dim3(256), 0, stream>>>(Q, Kt, Vt, topIdx, ctxUpd,
                                                    vmeanM);
  base_kernel<<<dim3(B_ * 16), dim3(256), 0, stream>>>(vmeanM, Wout, bout,
                                                       baseB);
  bcast_out<<<dim3(B_ * L_ * D_ / 1024), dim3(256), 0, stream>>>(baseB, out);
  corr_kernel<<<dim3(B_ * H_ * U_), dim3(256), 0, stream>>>(topIdx, ctxUpd,
                                                            vmeanM, Wout, out);
}

// Round 10
// 259.631 us; speedup vs baseline: 1.6457x; 1.0181x over previous
//
#include <hip/hip_runtime.h>
#include <math.h>

// Problem constants (B=2, L=2048, D=1024, H=16, FACTOR=5)
#define B_ 2
#define L_ 2048
#define D_ 1024
#define H_ 16
#define DH_ 64
#define U_ 40
#define SCALE_ 0.125f

typedef __attribute__((ext_vector_type(8))) short short8v;            // 8 bf16
typedef __attribute__((ext_vector_type(4))) float f32x4;
typedef __attribute__((ext_vector_type(4))) unsigned short ushort4v;  // 8 B

static __device__ __forceinline__ unsigned short bf16_rne(float f) {
  unsigned int u = __float_as_uint(f);
  u += 0x7fff + ((u >> 16) & 1);
  return (unsigned short)(u >> 16);
}
static __device__ __forceinline__ float bf16_f32(unsigned short h) {
  return __uint_as_float(((unsigned int)h) << 16);
}

// Async global->LDS, 16 B per lane.
static __device__ __forceinline__ void gload16(const unsigned short* src,
                                               unsigned short* lds) {
  __builtin_amdgcn_global_load_lds(
      (const __attribute__((address_space(1))) void*)src,
      (__attribute__((address_space(3))) void*)lds, 16, 0, 0);
}

// ---------------------------------------------------------------------------
// Pre-split f32 -> (hi,lo) bf16 for W=[Wq;Wkv] (quads [0,nW)) and X (rest).
// Block 0 additionally zeroes the vmean accumulator (living in d_out[0:2048]).
// ---------------------------------------------------------------------------
__global__ __launch_bounds__(256) void split_all(
    const float* __restrict__ Wq, const float* __restrict__ Wkv,
    const float* __restrict__ X, unsigned short* __restrict__ Whi,
    unsigned short* __restrict__ Wlo, unsigned short* __restrict__ Xhi,
    unsigned short* __restrict__ Xlo, float* __restrict__ vmAcc, int nW) {
  if (blockIdx.x == 0) {
    for (int z = threadIdx.x; z < B_ * D_; z += 256) vmAcc[z] = 0.f;
  }
  int i = blockIdx.x * 256 + threadIdx.x;
  const int nq_q = (D_ * D_) / 4;
  float4 v;
  unsigned short *hi, *lo;
  int off;
  if (i < nW) {
    v = (i < nq_q) ? ((const float4*)Wq)[i] : ((const float4*)Wkv)[i - nq_q];
    hi = Whi; lo = Wlo; off = i;
  } else {
    off = i - nW;
    v = ((const float4*)X)[off];
    hi = Xhi; lo = Xlo;
  }
  float vv[4] = {v.x, v.y, v.z, v.w};
  ushort4v h, l;
#pragma unroll
  for (int e = 0; e < 4; ++e) {
    unsigned short hh = bf16_rne(vv[e]);
    h[e] = hh;
    l[e] = bf16_rne(vv[e] - bf16_f32(hh));
  }
  ((ushort4v*)hi)[off] = h;
  ((ushort4v*)lo)[off] = l;
}

// ---------------------------------------------------------------------------
// Split-bf16 MFMA GEMM for QKV (core unchanged: gload_lds staging, XOR
// swizzle, 0 bank conflicts). NEW: V-column blocks accumulate sum_l V into
// vmAcc via 2-shfl row reduce + atomicAdd (bias folded: +64*bias per half).
// ---------------------------------------------------------------------------
template <bool XS>
__global__ __launch_bounds__(256) void gemm_qkv_mfma(
    const float* __restrict__ X,
    const unsigned short* __restrict__ Xhi,
    const unsigned short* __restrict__ Xlo,
    const unsigned short* __restrict__ Whi,
    const unsigned short* __restrict__ Wlo,
    const float* __restrict__ bq, const float* __restrict__ bkv,
    float* __restrict__ Qo, float* __restrict__ Ko, float* __restrict__ Vo,
    float* __restrict__ vmAcc) {
  __shared__ unsigned short Ah[128 * 32];
  __shared__ unsigned short Al[128 * 32];
  __shared__ unsigned short Bh[128 * 32];
  __shared__ unsigned short Bl[128 * 32];
  const int tid = threadIdx.x;
  const int lane = tid & 63;
  const int wave = tid >> 6;
  const int wm = wave >> 1, wn = wave & 1;
  const int row0 = blockIdx.y * 128;
  const int col0 = blockIdx.x * 128;

  f32x4 acc[4][4] = {};

  const int grow = lane >> 2;
  const int gg = lane & 3;

  for (int k0 = 0; k0 < D_; k0 += 32) {
#pragma unroll
    for (int j = 0; j < 2; ++j) {
      int c = wave + 4 * j;                     // 0..7
      int row = c * 16 + grow;                  // 0..127
      int gsrc = (gg ^ ((row >> 1) & 3)) << 3;  // swizzled source col
      size_t soffB = (size_t)(col0 + row) * D_ + k0 + gsrc;
      gload16(Whi + soffB, Bh + c * 512);
      gload16(Wlo + soffB, Bl + c * 512);
      if (XS) {
        size_t soffA = (size_t)(row0 + row) * D_ + k0 + gsrc;
        gload16(Xhi + soffA, Ah + c * 512);
        gload16(Xlo + soffA, Al + c * 512);
      }
    }
    if (!XS) {
#pragma unroll
      for (int rep = 0; rep < 2; ++rep) {
        int task = tid + rep * 256;  // 0..511
        int row = task >> 2;         // 0..127
        int gt = task & 3;           // true col group
        const float* s = X + (size_t)(row0 + row) * D_ + k0 + gt * 8;
        float4 a0 = *(const float4*)s;
        float4 a1 = *(const float4*)(s + 4);
        float av[8] = {a0.x, a0.y, a0.z, a0.w, a1.x, a1.y, a1.z, a1.w};
        short8v hseg, lseg;
#pragma unroll
        for (int e = 0; e < 8; ++e) {
          unsigned short hh = bf16_rne(av[e]);
          hseg[e] = (short)hh;
          lseg[e] = (short)bf16_rne(av[e] - bf16_f32(hh));
        }
        int dst = row * 32 + ((gt ^ ((row >> 1) & 3)) << 3);
        *(short8v*)&Ah[dst] = hseg;
        *(short8v*)&Al[dst] = lseg;
      }
    }
    __syncthreads();

    short8v a_h[4], a_l[4], b_h[4], b_l[4];
    const int hs = lane >> 4;  // true k-group 0..3
#pragma unroll
    for (int mi = 0; mi < 4; ++mi) {
      int rr = wm * 64 + mi * 16 + (lane & 15);
      int off = rr * 32 + ((hs ^ ((rr >> 1) & 3)) << 3);
      a_h[mi] = *(const short8v*)&Ah[off];
      a_l[mi] = *(const short8v*)&Al[off];
    }
#pragma unroll
    for (int ni = 0; ni < 4; ++ni) {
      int rc = wn * 64 + ni * 16 + (lane & 15);
      int off = rc * 32 + ((hs ^ ((rc >> 1) & 3)) << 3);
      b_h[ni] = *(const short8v*)&Bh[off];
      b_l[ni] = *(const short8v*)&Bl[off];
    }
#pragma unroll
    for (int mi = 0; mi < 4; ++mi)
#pragma unroll
      for (int ni = 0; ni < 4; ++ni) {
        acc[mi][ni] = __builtin_amdgcn_mfma_f32_16x16x32_bf16(
            a_h[mi], b_h[ni], acc[mi][ni], 0, 0, 0);
        acc[mi][ni] = __builtin_amdgcn_mfma_f32_16x16x32_bf16(
            a_h[mi], b_l[ni], acc[mi][ni], 0, 0, 0);
        acc[mi][ni] = __builtin_amdgcn_mfma_f32_16x16x32_bf16(
            a_l[mi], b_h[ni], acc[mi][ni], 0, 0, 0);
      }
    __syncthreads();
  }

  // Epilogue: C/D layout col=lane&15, row=(lane>>4)*4+reg.
#pragma unroll
  for (int ni = 0; ni < 4; ++ni) {
    int c = col0 + wn * 64 + ni * 16 + (lane & 15);
    int which = c >> 10;
    int jj = c & (D_ - 1);
    int h = jj >> 6, dh = jj & 63;
    float bias = (c < D_) ? bq[c] : bkv[c - D_];
    float* dst = (which == 0) ? Qo : ((which == 1) ? Ko : Vo);
#pragma unroll
    for (int mi = 0; mi < 4; ++mi) {
#pragma unroll
      for (int reg = 0; reg < 4; ++reg) {
        int r = row0 + wm * 64 + mi * 16 + ((lane >> 4) << 2) + reg;
        int b = r >> 11, l = r & (L_ - 1);
        dst[(((size_t)b * H_ + h) * L_ + l) * DH_ + dh] =
            acc[mi][ni][reg] + bias;
      }
    }
    if (which == 2) {  // accumulate sum over this block's rows of V column c
      float s = 0.f;
#pragma unroll
      for (int mi = 0; mi < 4; ++mi)
#pragma unroll
        for (int reg = 0; reg < 4; ++reg) s += acc[mi][ni][reg];
      s += __shfl_xor(s, 16);
      s += __shfl_xor(s, 32);  // sum over the wave's 64 rows
      if ((lane >> 4) == 0)
        atomicAdd(&vmAcc[(row0 >> 11) * D_ + jj], s + 64.0f * bias);
    }
  }
}

// ---------------------------------------------------------------------------
// base[b][j] = vmean_flat[b] . Wout[j] + bout[j]; vmean = vmAcc/L (bias
// already folded in gemm). Also snapshots vmean into ws (vmeanM) for attn.
// ---------------------------------------------------------------------------
__global__ __launch_bounds__(256) void base_kernel(
    const float* __restrict__ vmAcc, const float* __restrict__ Wout,
    const float* __restrict__ bout, float* __restrict__ baseOut,
    float* __restrict__ vmeanM) {
  int bid = blockIdx.x;
  int b = bid >> 4, jc = bid & 15;
  int t = threadIdx.x;
  int j = jc * 64 + (t & 63);
  int isl = t >> 6;
  __shared__ float vm[D_];
  __shared__ float red[256];
  for (int i = t; i < D_; i += 256) vm[i] = vmAcc[b * D_ + i] * (1.0f / L_);
  __syncthreads();
  if (jc == 0)
    for (int i = t; i < D_; i += 256) vmeanM[b * D_ + i] = vm[i];
  float s = 0.f;
  const float* wr = Wout + (size_t)j * D_ + isl * 256;
  const float* vv = vm + isl * 256;
  for (int i = 0; i < 256; i += 4) {
    float4 w = *(const float4*)(wr + i);
    s += vv[i] * w.x + vv[i + 1] * w.y + vv[i + 2] * w.z + vv[i + 3] * w.w;
  }
  red[t] = s; __syncthreads();
  if (isl == 0)
    baseOut[b * D_ + j] =
        red[t] + red[t + 64] + red[t + 128] + red[t + 192] + bout[j];
}

// ---------------------------------------------------------------------------
// out[b,l,:] = base[b,:]   (overwrites the vmAcc scratch region too)
// ---------------------------------------------------------------------------
__global__ __launch_bounds__(256) void bcast_out(
    const float* __restrict__ baseIn, float* __restrict__ out) {
  size_t i4 = (size_t)blockIdx.x * 256 + threadIdx.x;
  size_t i = i4 * 4;
  int b = (int)(i >> 21);
  int col = (int)(i & (D_ - 1));
  *(float4*)(out + i) = *(const float4*)(baseIn + b * D_ + col);
}

// ---------------------------------------------------------------------------
// M[b,h,l] = max_u(QK) - mean_u(QK). Registers-only (round 9 version).
// ---------------------------------------------------------------------------
__global__ __launch_bounds__(256) void sample_m(
    const float* __restrict__ Q, const float* __restrict__ Kt,
    const int* __restrict__ idx, float* __restrict__ Mv) {
  int t = threadIdx.x;
  int w = t >> 6, lane = t & 63;
  int subl = lane >> 4, d16 = lane & 15;
  int gl = blockIdx.x * 16 + w * 4 + subl;  // bh*L + l
  int bh = gl >> 11, l = gl & (L_ - 1);
  const float4* Kb4 = (const float4*)(Kt + (size_t)bh * L_ * DH_);
  float4 q4 = ((const float4*)(Q + (size_t)gl * DH_))[d16];
  const int* irow = idx + l * U_;
  float mx = -INFINITY, sm = 0.f;
#pragma unroll 8
  for (int u = 0; u < U_; ++u) {
    int kl = irow[u];
    float4 k4 = Kb4[kl * 16 + d16];
    float p = q4.x * k4.x + q4.y * k4.y + q4.z * k4.z + q4.w * k4.w;
    p += __shfl_xor(p, 1);
    p += __shfl_xor(p, 2);
    p += __shfl_xor(p, 4);
    p += __shfl_xor(p, 8);
    mx = fmaxf(mx, p);
    sm += p;
  }
  if (d16 == 0) Mv[gl] = mx - sm * (1.0f / U_);
}

// ---------------------------------------------------------------------------
// Per-(b,h) top-U_ of M: one wave per bh, shfl argmax.
// ---------------------------------------------------------------------------
__global__ __launch_bounds__(64) void topk_kernel(
    const float* __restrict__ Mv, int* __restrict__ topIdx) {
  __shared__ float vals[L_];
  int lane = threadIdx.x;
  int bh = blockIdx.x;
  for (int j = 0; j < 32; ++j)
    vals[j * 64 + lane] = Mv[(size_t)bh * L_ + j * 64 + lane];
  __syncthreads();
  for (int it = 0; it < U_; ++it) {
    float bv = -INFINITY;
    int bi = 0x7fffffff;
    for (int j = 0; j < 32; ++j) {
      int i = j * 64 + lane;
      float v = vals[i];
      if (v > bv) { bv = v; bi = i; }  // j ascending -> ties keep lower index
    }
#pragma unroll
    for (int off = 32; off > 0; off >>= 1) {
      float ov = __shfl_xor(bv, off);
      int oi = __shfl_xor(bi, off);
      if (ov > bv || (ov == bv && oi < bi)) { bv = ov; bi = oi; }
    }
    if (lane == 0) topIdx[bh * U_ + it] = bi;
    vals[bi] = -INFINITY;
    __syncthreads();
  }
}

// ---------------------------------------------------------------------------
// Fused attention + output correction. Per (qc, bh) block, 5 queries:
//   pass1 scores->LDS, pass2 in-wave softmax, pass3 PV,
//   then dv = ctx - vmean and out[b,l_q,:] += dv . Wout[:,h*64:+64]^T.
// Wout slice is shared by all 5 queries -> read once per block.
// ---------------------------------------------------------------------------
__global__ __launch_bounds__(256) void attn_corr(
    const float* __restrict__ Q, const float* __restrict__ Kt,
    const float* __restrict__ Vt, const int* __restrict__ topIdx,
    const float* __restrict__ vmeanM, const float* __restrict__ Wout,
    float* __restrict__ out) {
  int qc = blockIdx.x;  // 0..7 (5 queries each)
  int bh = blockIdx.y;  // 0..31
  int b = bh >> 4, h = bh & (H_ - 1);
  __shared__ float Qs[5][DH_];
  __shared__ float Sv[5][L_];        // 40 KB
  __shared__ float part[4][5][DH_];  // 5 KB
  __shared__ float inv[5];
  __shared__ float dv[5][DH_];
  __shared__ int lq[5];
  int t = threadIdx.x;
  int lane = t & 63, w = t >> 6;

  if (t < 80) {
    int q = t >> 4, c4 = t & 15;
    int ql = topIdx[bh * U_ + qc * 5 + q];
    *(float4*)&Qs[q][c4 * 4] =
        *(const float4*)&Q[((size_t)bh * L_ + ql) * DH_ + c4 * 4];
  }
  if (t < 5) lq[t] = topIdx[bh * U_ + qc * 5 + t];
  __syncthreads();

  // ---- pass 1: scores, thread = key in chunk
  const float* Kb = Kt + (size_t)bh * L_ * DH_;
  for (int kc = 0; kc < 8; ++kc) {
    int key = kc * 256 + t;
    const float* kr = Kb + (size_t)key * DH_;
    float acc[5];
#pragma unroll
    for (int q = 0; q < 5; ++q) acc[q] = 0.f;
#pragma unroll
    for (int i4 = 0; i4 < 16; ++i4) {
      float4 k4 = *(const float4*)(kr + i4 * 4);
#pragma unroll
      for (int q = 0; q < 5; ++q) {
        float4 qv = *(const float4*)&Qs[q][i4 * 4];
        acc[q] += k4.x * qv.x + k4.y * qv.y + k4.z * qv.z + k4.w * qv.w;
      }
    }
#pragma unroll
    for (int q = 0; q < 5; ++q) Sv[q][key] = acc[q] * SCALE_;
  }
  __syncthreads();

  // ---- pass 2: softmax. Wave w owns row w; wave 0 also row 4.
#pragma unroll
  for (int rep = 0; rep < 2; ++rep) {
    int r = (rep == 0) ? w : (w == 0 ? 4 : -1);
    if (r >= 0) {
      float mx = -INFINITY;
      for (int j = 0; j < 32; ++j) mx = fmaxf(mx, Sv[r][j * 64 + lane]);
#pragma unroll
      for (int off = 1; off < 64; off <<= 1)
        mx = fmaxf(mx, __shfl_xor(mx, off));
      float sm = 0.f;
      for (int j = 0; j < 32; ++j) {
        float e = __expf(Sv[r][j * 64 + lane] - mx);
        Sv[r][j * 64 + lane] = e;
        sm += e;
      }
#pragma unroll
      for (int off = 1; off < 64; off <<= 1) sm += __shfl_xor(sm, off);
      if (lane == 0) inv[r] = 1.0f / sm;
    }
  }
  __syncthreads();

  // ---- pass 3: PV. Wave w covers keys [w*512, w*512+512), lane = dh.
  {
    const float* vb = Vt + ((size_t)bh * L_ + w * 512) * DH_ + lane;
    float acc[5];
#pragma unroll
    for (int q = 0; q < 5; ++q) acc[q] = 0.f;
    for (int k4 = 0; k4 < 128; ++k4) {
      float v0 = vb[(k4 * 4 + 0) * DH_];
      float v1 = vb[(k4 * 4 + 1) * DH_];
      float v2 = vb[(k4 * 4 + 2) * DH_];
      float v3 = vb[(k4 * 4 + 3) * DH_];
      int k = w * 512 + k4 * 4;
#pragma unroll
      for (int q = 0; q < 5; ++q) {
        float4 p4 = *(const float4*)&Sv[q][k];
        acc[q] += p4.x * v0 + p4.y * v1 + p4.z * v2 + p4.w * v3;
      }
    }
#pragma unroll
    for (int q = 0; q < 5; ++q) part[w][q][lane] = acc[q];
  }
  __syncthreads();

  // dv = ctx - vmean
  for (int o = t; o < 5 * DH_; o += 256) {
    int q = o >> 6, dh = o & 63;
    float s = (part[0][q][dh] + part[1][q][dh]) +
              (part[2][q][dh] + part[3][q][dh]);
    dv[q][dh] = s * inv[q] - vmeanM[b * D_ + h * DH_ + dh];
  }
  __syncthreads();

  // ---- correction GEMV: out[b, l_q, :] += dv[q] . Wout[:, h*64:+64]^T
  int sub = t & 3;
  int jbase = t >> 2;
#pragma unroll
  for (int jc = 0; jc < 16; ++jc) {
    int j = jc * 64 + jbase;
    const float* wr = Wout + (size_t)j * D_ + h * DH_ + sub * 16;
    float4 w0 = ((const float4*)wr)[0];
    float4 w1 = ((const float4*)wr)[1];
    float4 w2 = ((const float4*)wr)[2];
    float4 w3 = ((const float4*)wr)[3];
#pragma unroll
    for (int q = 0; q < 5; ++q) {
      const float* dq = &dv[q][sub * 16];
      float s = dq[0] * w0.x + dq[1] * w0.y + dq[2] * w0.z + dq[3] * w0.w +
                dq[4] * w1.x + dq[5] * w1.y + dq[6] * w1.z + dq[7] * w1.w +
                dq[8] * w2.x + dq[9] * w2.y + dq[10] * w2.z + dq[11] * w2.w +
                dq[12] * w3.x + dq[13] * w3.y + dq[14] * w3.z + dq[15] * w3.w;
      s += __shfl_xor(s, 1);
      s += __shfl_xor(s, 2);
      if (sub == 0)
        atomicAdd(out + ((size_t)b * L_ + lq[q]) * D_ + j, s);
    }
  }
}

// ---------------------------------------------------------------------------
extern "C" void kernel_launch(void* const* d_in, const int* in_sizes, int n_in,
                              void* d_out, int out_size, void* d_ws,
                              size_t ws_size, hipStream_t stream) {
  const float* x    = (const float*)d_in[0];
  const float* Wq   = (const float*)d_in[1];
  const float* bq   = (const float*)d_in[2];
  const float* Wkv  = (const float*)d_in[3];
  const float* bkv  = (const float*)d_in[4];
  const float* Wout = (const float*)d_in[5];
  const float* bout = (const float*)d_in[6];
  const int*   idx  = (const int*)d_in[7];
  float* out = (float*)d_out;

  float* ws = (float*)d_ws;
  const size_t NQ = (size_t)B_ * H_ * L_ * DH_;  // 4,194,304 floats
  float* Q  = ws;
  float* Kt = Q + NQ;
  float* Vt = Kt + NQ;
  // W/X split region (live only through the GEMM)
  unsigned short* Whi = (unsigned short*)(Vt + NQ);  // 6 MB
  unsigned short* Wlo = Whi + (size_t)3 * D_ * D_;   // 6 MB
  unsigned short* Xhi = Wlo + (size_t)3 * D_ * D_;   // 8 MB (optional)
  unsigned short* Xlo = Xhi + NQ;                    // 8 MB (optional)
  // phase-2 region (overlaps split region; used only after the GEMM)
  float* Mv     = Vt + NQ;                           // 256 KB
  float* vmeanM = Mv + (size_t)B_ * H_ * L_;         // 8 KB
  float* baseB  = vmeanM + B_ * D_;                  // 8 KB
  int*   topIdx = (int*)(baseB + B_ * D_);           // 5 KB
  // vmean accumulator lives in d_out[0:2048] (zeroed by split_all, consumed
  // by base_kernel, then overwritten by bcast_out).
  float* vmAcc = out;

  const bool xsplit = ws_size >= ((size_t)76 << 20);  // Xhi/Xlo fit?
  const int nW = 3 * D_ * D_ / 4;                     // W quads
  const int nX = (int)(NQ / 4);                       // X quads

  if (xsplit) {
    split_all<<<dim3((nW + nX) / 256), dim3(256), 0, stream>>>(
        Wq, Wkv, x, Whi, Wlo, Xhi, Xlo, vmAcc, nW);
    gemm_qkv_mfma<true>
        <<<dim3(3 * D_ / 128, B_ * L_ / 128), dim3(256), 0, stream>>>(
            x, Xhi, Xlo, Whi, Wlo, bq, bkv, Q, Kt, Vt, vmAcc);
  } else {
    split_all<<<dim3(nW / 256), dim3(256), 0, stream>>>(Wq, Wkv, x, Whi, Wlo,
                                                        Xhi, Xlo, vmAcc, nW);
    gemm_qkv_mfma<false>
        <<<dim3(3 * D_ / 128, B_ * L_ / 128), dim3(256), 0, stream>>>(
            x, Xhi, Xlo, Whi, Wlo, bq, bkv, Q, Kt, Vt, vmAcc);
  }
  base_kernel<<<dim3(B_ * 16), dim3(256), 0, stream>>>(vmAcc, Wout, bout,
                                                       baseB, vmeanM);
  bcast_out<<<dim3(B_ * L_ * D_ / 1024), dim3(256), 0, stream>>>(baseB, out);
  sample_m<<<dim3(B_ * H_ * L_ / 16), dim3(256), 0, stream>>>(Q, Kt, idx, Mv);
  topk_kernel<<<dim3(B_ * H_), dim3(64), 0, stream>>>(Mv, topIdx);
  attn_corr<<<dim3(8, 32), dim3(256), 0, stream>>>(Q, Kt, Vt, topIdx, vmeanM,
                                                   Wout, out);
}

// Round 11
// 245.488 us; speedup vs baseline: 1.7405x; 1.0576x over previous
//
#include <hip/hip_runtime.h>
#include <math.h>

// Problem constants (B=2, L=2048, D=1024, H=16, FACTOR=5)
#define B_ 2
#define L_ 2048
#define D_ 1024
#define H_ 16
#define DH_ 64
#define U_ 40
#define SCALE_ 0.125f

typedef __attribute__((ext_vector_type(8))) short short8v;            // 8 bf16
typedef __attribute__((ext_vector_type(4))) float f32x4;
typedef __attribute__((ext_vector_type(4))) unsigned short ushort4v;  // 8 B

static __device__ __forceinline__ unsigned short bf16_rne(float f) {
  unsigned int u = __float_as_uint(f);
  u += 0x7fff + ((u >> 16) & 1);
  return (unsigned short)(u >> 16);
}
static __device__ __forceinline__ float bf16_f32(unsigned short h) {
  return __uint_as_float(((unsigned int)h) << 16);
}

// Async global->LDS, 16 B per lane.
static __device__ __forceinline__ void gload16(const unsigned short* src,
                                               unsigned short* lds) {
  __builtin_amdgcn_global_load_lds(
      (const __attribute__((address_space(1))) void*)src,
      (__attribute__((address_space(3))) void*)lds, 16, 0, 0);
}

#define FENCE asm volatile("" ::: "memory")
#define BARRIER                        \
  do {                                 \
    FENCE;                             \
    __builtin_amdgcn_s_barrier();      \
    FENCE;                             \
  } while (0)
#define LGKM0                                             \
  do {                                                    \
    asm volatile("s_waitcnt lgkmcnt(0)" ::: "memory");    \
    __builtin_amdgcn_sched_barrier(0);                    \
  } while (0)

// ---------------------------------------------------------------------------
// Pre-split f32 -> (hi,lo) bf16 for W=[Wq;Wkv] (quads [0,nW)) and X (rest).
// Block 0 additionally zeroes the vmean accumulator (in d_out[0:2048]).
// ---------------------------------------------------------------------------
__global__ __launch_bounds__(256) void split_all(
    const float* __restrict__ Wq, const float* __restrict__ Wkv,
    const float* __restrict__ X, unsigned short* __restrict__ Whi,
    unsigned short* __restrict__ Wlo, unsigned short* __restrict__ Xhi,
    unsigned short* __restrict__ Xlo, float* __restrict__ vmAcc, int nW) {
  if (blockIdx.x == 0) {
    for (int z = threadIdx.x; z < B_ * D_; z += 256) vmAcc[z] = 0.f;
  }
  int i = blockIdx.x * 256 + threadIdx.x;
  const int nq_q = (D_ * D_) / 4;
  float4 v;
  unsigned short *hi, *lo;
  int off;
  if (i < nW) {
    v = (i < nq_q) ? ((const float4*)Wq)[i] : ((const float4*)Wkv)[i - nq_q];
    hi = Whi; lo = Wlo; off = i;
  } else {
    off = i - nW;
    v = ((const float4*)X)[off];
    hi = Xhi; lo = Xlo;
  }
  float vv[4] = {v.x, v.y, v.z, v.w};
  ushort4v h, l;
#pragma unroll
  for (int e = 0; e < 4; ++e) {
    unsigned short hh = bf16_rne(vv[e]);
    h[e] = hh;
    l[e] = bf16_rne(vv[e] - bf16_f32(hh));
  }
  ((ushort4v*)hi)[off] = h;
  ((ushort4v*)lo)[off] = l;
}

// ---------------------------------------------------------------------------
// 8-phase-style split-bf16 MFMA GEMM (T3+T4+T5): C = X @ W^T + bias.
// Tile 128x192, BK=32, 8 waves (2Mx4N, per-wave 64x48 = 4x3 frags).
// 3 LDS buffers x 40 KB (Ah|Al|Bh|Bl), counted vmcnt(5) pipeline, 2 tiles
// in flight. 3 phases/step with triangular fragment availability.
// Swizzle: source col_group ^= (row>>1)&3, same XOR on read (R7-proven).
// ---------------------------------------------------------------------------
__global__ __launch_bounds__(512, 2) void gemm_qkv_8ph(
    const unsigned short* __restrict__ Xhi,
    const unsigned short* __restrict__ Xlo,
    const unsigned short* __restrict__ Whi,
    const unsigned short* __restrict__ Wlo,
    const float* __restrict__ bq, const float* __restrict__ bkv,
    float* __restrict__ Qo, float* __restrict__ Ko, float* __restrict__ Vo,
    float* __restrict__ vmAcc) {
  // Per buffer (shorts): Ah[128*32]=4096 @0, Al @4096, Bh[192*32]=6144 @8192,
  // Bl @14336; total 20480 shorts = 40 KB. 3 buffers = 120 KB.
  __shared__ unsigned short LDS[3][20480];
  const int tid = threadIdx.x;  // 0..511
  const int lane = tid & 63;
  const int wave = tid >> 6;            // 0..7
  const int wm = wave >> 2, wn = wave & 3;
  const int row0 = blockIdx.y * 128;    // M = 4096 -> 32 blocks
  const int col0 = blockIdx.x * 192;    // N = 3072 -> 16 blocks

  f32x4 acc[4][3] = {};

  // ---- flat staging: 40 calls of 1 KB; call c = wave + 8*r, r=0..4.
  // c<8: Ah rows c*16.. ; c<16: Al ; c<28: Bh rows (c-16)*16 ; else Bl.
  const unsigned short* gsrc[5];
#pragma unroll
  for (int r = 0; r < 5; ++r) {
    int c = wave + 8 * r;
    const unsigned short* base;
    int rowin, isA;
    if (c < 8)       { base = Xhi; rowin = c * 16;        isA = 1; }
    else if (c < 16) { base = Xlo; rowin = (c - 8) * 16;  isA = 1; }
    else if (c < 28) { base = Whi; rowin = (c - 16) * 16; isA = 0; }
    else             { base = Wlo; rowin = (c - 28) * 16; isA = 0; }
    rowin += (lane >> 2);
    int grow = (isA ? row0 : col0) + rowin;
    int seg = (lane & 3) ^ ((rowin >> 1) & 3);
    gsrc[r] = base + (size_t)grow * D_ + seg * 8;
  }

  const int fr_r = lane & 15;
  const int hs = lane >> 4;

#define RD_A(mi)                                                     \
  {                                                                  \
    int rr = wm * 64 + (mi) * 16 + fr_r;                             \
    int off = rr * 32 + ((hs ^ ((rr >> 1) & 3)) << 3);               \
    a_h[mi] = *(const short8v*)&Lc[off];                             \
    a_l[mi] = *(const short8v*)&Lc[4096 + off];                      \
  }
#define RD_B(ni)                                                     \
  {                                                                  \
    int rc = wn * 48 + (ni) * 16 + fr_r;                             \
    int off = rc * 32 + ((hs ^ ((rc >> 1) & 3)) << 3);               \
    b_h[ni] = *(const short8v*)&Lc[8192 + off];                      \
    b_l[ni] = *(const short8v*)&Lc[14336 + off];                     \
  }
#define MM3(mi, ni)                                                  \
  acc[mi][ni] = __builtin_amdgcn_mfma_f32_16x16x32_bf16(             \
      a_h[mi], b_h[ni], acc[mi][ni], 0, 0, 0);                       \
  acc[mi][ni] = __builtin_amdgcn_mfma_f32_16x16x32_bf16(             \
      a_h[mi], b_l[ni], acc[mi][ni], 0, 0, 0);                       \
  acc[mi][ni] = __builtin_amdgcn_mfma_f32_16x16x32_bf16(             \
      a_l[mi], b_h[ni], acc[mi][ni], 0, 0, 0);
#define STG(r, k0s, Ls) \
  gload16(gsrc[r] + (k0s), (Ls) + (wave + 8 * (r)) * 512)

  // ---- prologue: stage tiles 0 and 1 into buffers 0, 1.
  {
    unsigned short* L0 = &LDS[0][0];
    unsigned short* L1 = &LDS[1][0];
    STG(0, 0, L0); STG(1, 0, L0); STG(2, 0, L0); STG(3, 0, L0); STG(4, 0, L0);
    STG(0, 32, L1); STG(1, 32, L1); STG(2, 32, L1); STG(3, 32, L1);
    STG(4, 32, L1);
  }
  asm volatile("s_waitcnt vmcnt(5)" ::: "memory");
  BARRIER;

  for (int ks = 0; ks < 32; ++ks) {
    int cur = ks % 3;
    int stg = (ks + 2) % 3;
    int k0s = (ks + 2) * 32;
    unsigned short* Lc = &LDS[cur][0];
    unsigned short* Ls = &LDS[stg][0];
    short8v a_h[4], a_l[4], b_h[3], b_l[3];

    // ---- phase 0: A0,A1,B0 ; 2 gloads ; pairs (0,0)(1,0)
    RD_A(0) RD_A(1) RD_B(0)
    if (ks < 30) { STG(0, k0s, Ls); STG(1, k0s, Ls); }
    BARRIER;
    LGKM0;
    __builtin_amdgcn_s_setprio(1);
    MM3(0, 0) MM3(1, 0)
    __builtin_amdgcn_s_setprio(0);
    BARRIER;

    // ---- phase 1: A2,B1 ; 2 gloads ; pairs (2,0)(0,1)(1,1)(2,1)
    RD_A(2) RD_B(1)
    if (ks < 30) { STG(2, k0s, Ls); STG(3, k0s, Ls); }
    BARRIER;
    LGKM0;
    __builtin_amdgcn_s_setprio(1);
    MM3(2, 0) MM3(0, 1) MM3(1, 1) MM3(2, 1)
    __builtin_amdgcn_s_setprio(0);
    BARRIER;

    // ---- phase 2: A3,B2 ; 1 gload ; pairs (3,0)(3,1)(0,2)(1,2)(2,2)(3,2)
    RD_A(3) RD_B(2)
    if (ks < 30) { STG(4, k0s, Ls); }
    BARRIER;
    LGKM0;
    __builtin_amdgcn_s_setprio(1);
    MM3(3, 0) MM3(3, 1) MM3(0, 2) MM3(1, 2) MM3(2, 2) MM3(3, 2)
    __builtin_amdgcn_s_setprio(0);
    // counted vmcnt: keep this step's 5 staging loads in flight.
    if (ks < 30) {
      asm volatile("s_waitcnt vmcnt(5)" ::: "memory");
    } else {
      asm volatile("s_waitcnt vmcnt(0)" ::: "memory");
    }
    BARRIER;
  }

  // ---- epilogue: C/D layout col=lane&15, row=(lane>>4)*4+reg.
#pragma unroll
  for (int ni = 0; ni < 3; ++ni) {
    int c = col0 + wn * 48 + ni * 16 + (lane & 15);
    int which = c >> 10;
    int jj = c & (D_ - 1);
    int h = jj >> 6, dh = jj & 63;
    float bias = (c < D_) ? bq[c] : bkv[c - D_];
    float* dst = (which == 0) ? Qo : ((which == 1) ? Ko : Vo);
#pragma unroll
    for (int mi = 0; mi < 4; ++mi) {
#pragma unroll
      for (int reg = 0; reg < 4; ++reg) {
        int r = row0 + wm * 64 + mi * 16 + ((lane >> 4) << 2) + reg;
        int b = r >> 11, l = r & (L_ - 1);
        dst[(((size_t)b * H_ + h) * L_ + l) * DH_ + dh] =
            acc[mi][ni][reg] + bias;
      }
    }
    if (which == 2) {  // vmean partial: sum over this wave's 64 rows
      float s = 0.f;
#pragma unroll
      for (int mi = 0; mi < 4; ++mi)
#pragma unroll
        for (int reg = 0; reg < 4; ++reg) s += acc[mi][ni][reg];
      s += __shfl_xor(s, 16);
      s += __shfl_xor(s, 32);
      if ((lane >> 4) == 0)
        atomicAdd(&vmAcc[(row0 >> 11) * D_ + jj], s + 64.0f * bias);
    }
  }
#undef RD_A
#undef RD_B
#undef MM3
#undef STG
}

// ---------------------------------------------------------------------------
// Fallback GEMM (R10 structure) — used only when ws can't hold Xhi/Xlo.
// ---------------------------------------------------------------------------
__global__ __launch_bounds__(256) void gemm_qkv_fallback(
    const float* __restrict__ X,
    const unsigned short* __restrict__ Whi,
    const unsigned short* __restrict__ Wlo,
    const float* __restrict__ bq, const float* __restrict__ bkv,
    float* __restrict__ Qo, float* __restrict__ Ko, float* __restrict__ Vo,
    float* __restrict__ vmAcc) {
  __shared__ unsigned short Ah[128 * 32];
  __shared__ unsigned short Al[128 * 32];
  __shared__ unsigned short Bh[128 * 32];
  __shared__ unsigned short Bl[128 * 32];
  const int tid = threadIdx.x;
  const int lane = tid & 63;
  const int wave = tid >> 6;
  const int wm = wave >> 1, wn = wave & 1;
  const int row0 = blockIdx.y * 128;
  const int col0 = blockIdx.x * 128;

  f32x4 acc[4][4] = {};

  const int grow = lane >> 2;
  const int gg = lane & 3;

  for (int k0 = 0; k0 < D_; k0 += 32) {
#pragma unroll
    for (int j = 0; j < 2; ++j) {
      int c = wave + 4 * j;
      int row = c * 16 + grow;
      int gsrc = (gg ^ ((row >> 1) & 3)) << 3;
      size_t soffB = (size_t)(col0 + row) * D_ + k0 + gsrc;
      gload16(Whi + soffB, Bh + c * 512);
      gload16(Wlo + soffB, Bl + c * 512);
    }
#pragma unroll
    for (int rep = 0; rep < 2; ++rep) {
      int task = tid + rep * 256;
      int row = task >> 2;
      int gt = task & 3;
      const float* s = X + (size_t)(row0 + row) * D_ + k0 + gt * 8;
      float4 a0 = *(const float4*)s;
      float4 a1 = *(const float4*)(s + 4);
      float av[8] = {a0.x, a0.y, a0.z, a0.w, a1.x, a1.y, a1.z, a1.w};
      short8v hseg, lseg;
#pragma unroll
      for (int e = 0; e < 8; ++e) {
        unsigned short hh = bf16_rne(av[e]);
        hseg[e] = (short)hh;
        lseg[e] = (short)bf16_rne(av[e] - bf16_f32(hh));
      }
      int dst = row * 32 + ((gt ^ ((row >> 1) & 3)) << 3);
      *(short8v*)&Ah[dst] = hseg;
      *(short8v*)&Al[dst] = lseg;
    }
    __syncthreads();

    short8v a_h[4], a_l[4], b_h[4], b_l[4];
    const int hs = lane >> 4;
#pragma unroll
    for (int mi = 0; mi < 4; ++mi) {
      int rr = wm * 64 + mi * 16 + (lane & 15);
      int off = rr * 32 + ((hs ^ ((rr >> 1) & 3)) << 3);
      a_h[mi] = *(const short8v*)&Ah[off];
      a_l[mi] = *(const short8v*)&Al[off];
    }
#pragma unroll
    for (int ni = 0; ni < 4; ++ni) {
      int rc = wn * 64 + ni * 16 + (lane & 15);
      int off = rc * 32 + ((hs ^ ((rc >> 1) & 3)) << 3);
      b_h[ni] = *(const short8v*)&Bh[off];
      b_l[ni] = *(const short8v*)&Bl[off];
    }
#pragma unroll
    for (int mi = 0; mi < 4; ++mi)
#pragma unroll
      for (int ni = 0; ni < 4; ++ni) {
        acc[mi][ni] = __builtin_amdgcn_mfma_f32_16x16x32_bf16(
            a_h[mi], b_h[ni], acc[mi][ni], 0, 0, 0);
        acc[mi][ni] = __builtin_amdgcn_mfma_f32_16x16x32_bf16(
            a_h[mi], b_l[ni], acc[mi][ni], 0, 0, 0);
        acc[mi][ni] = __builtin_amdgcn_mfma_f32_16x16x32_bf16(
            a_l[mi], b_h[ni], acc[mi][ni], 0, 0, 0);
      }
    __syncthreads();
  }

#pragma unroll
  for (int ni = 0; ni < 4; ++ni) {
    int c = col0 + wn * 64 + ni * 16 + (lane & 15);
    int which = c >> 10;
    int jj = c & (D_ - 1);
    int h = jj >> 6, dh = jj & 63;
    float bias = (c < D_) ? bq[c] : bkv[c - D_];
    float* dst = (which == 0) ? Qo : ((which == 1) ? Ko : Vo);
#pragma unroll
    for (int mi = 0; mi < 4; ++mi) {
#pragma unroll
      for (int reg = 0; reg < 4; ++reg) {
        int r = row0 + wm * 64 + mi * 16 + ((lane >> 4) << 2) + reg;
        int b = r >> 11, l = r & (L_ - 1);
        dst[(((size_t)b * H_ + h) * L_ + l) * DH_ + dh] =
            acc[mi][ni][reg] + bias;
      }
    }
    if (which == 2) {
      float s = 0.f;
#pragma unroll
      for (int mi = 0; mi < 4; ++mi)
#pragma unroll
        for (int reg = 0; reg < 4; ++reg) s += acc[mi][ni][reg];
      s += __shfl_xor(s, 16);
      s += __shfl_xor(s, 32);
      if ((lane >> 4) == 0)
        atomicAdd(&vmAcc[(row0 >> 11) * D_ + jj], s + 64.0f * bias);
    }
  }
}

// ---------------------------------------------------------------------------
// base[b][j] = vmean_flat[b] . Wout[j] + bout[j]; also snapshots vmean.
// ---------------------------------------------------------------------------
__global__ __launch_bounds__(256) void base_kernel(
    const float* __restrict__ vmAcc, const float* __restrict__ Wout,
    const float* __restrict__ bout, float* __restrict__ baseOut,
    float* __restrict__ vmeanM) {
  int bid = blockIdx.x;
  int b = bid >> 4, jc = bid & 15;
  int t = threadIdx.x;
  int j = jc * 64 + (t & 63);
  int isl = t >> 6;
  __shared__ float vm[D_];
  __shared__ float red[256];
  for (int i = t; i < D_; i += 256) vm[i] = vmAcc[b * D_ + i] * (1.0f / L_);
  __syncthreads();
  if (jc == 0)
    for (int i = t; i < D_; i += 256) vmeanM[b * D_ + i] = vm[i];
  float s = 0.f;
  const float* wr = Wout + (size_t)j * D_ + isl * 256;
  const float* vv = vm + isl * 256;
  for (int i = 0; i < 256; i += 4) {
    float4 w = *(const float4*)(wr + i);
    s += vv[i] * w.x + vv[i + 1] * w.y + vv[i + 2] * w.z + vv[i + 3] * w.w;
  }
  red[t] = s; __syncthreads();
  if (isl == 0)
    baseOut[b * D_ + j] =
        red[t] + red[t + 64] + red[t + 128] + red[t + 192] + bout[j];
}

// ---------------------------------------------------------------------------
// out[b,l,:] = base[b,:]
// ---------------------------------------------------------------------------
__global__ __launch_bounds__(256) void bcast_out(
    const float* __restrict__ baseIn, float* __restrict__ out) {
  size_t i4 = (size_t)blockIdx.x * 256 + threadIdx.x;
  size_t i = i4 * 4;
  int b = (int)(i >> 21);
  int col = (int)(i & (D_ - 1));
  *(float4*)(out + i) = *(const float4*)(baseIn + b * D_ + col);
}

// ---------------------------------------------------------------------------
// M[b,h,l] = max_u(QK) - mean_u(QK). Registers-only (R9 version).
// ---------------------------------------------------------------------------
__global__ __launch_bounds__(256) void sample_m(
    const float* __restrict__ Q, const float* __restrict__ Kt,
    const int* __restrict__ idx, float* __restrict__ Mv) {
  int t = threadIdx.x;
  int w = t >> 6, lane = t & 63;
  int subl = lane >> 4, d16 = lane & 15;
  int gl = blockIdx.x * 16 + w * 4 + subl;  // bh*L + l
  int bh = gl >> 11, l = gl & (L_ - 1);
  const float4* Kb4 = (const float4*)(Kt + (size_t)bh * L_ * DH_);
  float4 q4 = ((const float4*)(Q + (size_t)gl * DH_))[d16];
  const int* irow = idx + l * U_;
  float mx = -INFINITY, sm = 0.f;
#pragma unroll 8
  for (int u = 0; u < U_; ++u) {
    int kl = irow[u];
    float4 k4 = Kb4[kl * 16 + d16];
    float p = q4.x * k4.x + q4.y * k4.y + q4.z * k4.z + q4.w * k4.w;
    p += __shfl_xor(p, 1);
    p += __shfl_xor(p, 2);
    p += __shfl_xor(p, 4);
    p += __shfl_xor(p, 8);
    mx = fmaxf(mx, p);
    sm += p;
  }
  if (d16 == 0) Mv[gl] = mx - sm * (1.0f / U_);
}

// ---------------------------------------------------------------------------
// Per-(b,h) top-U_ of M: one wave per bh, shfl argmax.
// ---------------------------------------------------------------------------
__global__ __launch_bounds__(64) void topk_kernel(
    const float* __restrict__ Mv, int* __restrict__ topIdx) {
  __shared__ float vals[L_];
  int lane = threadIdx.x;
  int bh = blockIdx.x;
  for (int j = 0; j < 32; ++j)
    vals[j * 64 + lane] = Mv[(size_t)bh * L_ + j * 64 + lane];
  __syncthreads();
  for (int it = 0; it < U_; ++it) {
    float bv = -INFINITY;
    int bi = 0x7fffffff;
    for (int j = 0; j < 32; ++j) {
      int i = j * 64 + lane;
      float v = vals[i];
      if (v > bv) { bv = v; bi = i; }  // j ascending -> ties keep lower index
    }
#pragma unroll
    for (int off = 32; off > 0; off >>= 1) {
      float ov = __shfl_xor(bv, off);
      int oi = __shfl_xor(bi, off);
      if (ov > bv || (ov == bv && oi < bi)) { bv = ov; bi = oi; }
    }
    if (lane == 0) topIdx[bh * U_ + it] = bi;
    vals[bi] = -INFINITY;
    __syncthreads();
  }
}

// ---------------------------------------------------------------------------
// Fused attention + output correction (R10 version).
// ---------------------------------------------------------------------------
__global__ __launch_bounds__(256) void attn_corr(
    const float* __restrict__ Q, const float* __restrict__ Kt,
    const float* __restrict__ Vt, const int* __restrict__ topIdx,
    const float* __restrict__ vmeanM, const float* __restrict__ Wout,
    float* __restrict__ out) {
  int qc = blockIdx.x;  // 0..7 (5 queries each)
  int bh = blockIdx.y;  // 0..31
  int b = bh >> 4, h = bh & (H_ - 1);
  __shared__ float Qs[5][DH_];
  __shared__ float Sv[5][L_];
  __shared__ float part[4][5][DH_];
  __shared__ float inv[5];
  __shared__ float dv[5][DH_];
  __shared__ int lq[5];
  int t = threadIdx.x;
  int lane = t & 63, w = t >> 6;

  if (t < 80) {
    int q = t >> 4, c4 = t & 15;
    int ql = topIdx[bh * U_ + qc * 5 + q];
    *(float4*)&Qs[q][c4 * 4] =
        *(const float4*)&Q[((size_t)bh * L_ + ql) * DH_ + c4 * 4];
  }
  if (t < 5) lq[t] = topIdx[bh * U_ + qc * 5 + t];
  __syncthreads();

  const float* Kb = Kt + (size_t)bh * L_ * DH_;
  for (int kc = 0; kc < 8; ++kc) {
    int key = kc * 256 + t;
    const float* kr = Kb + (size_t)key * DH_;
    float acc[5];
#pragma unroll
    for (int q = 0; q < 5; ++q) acc[q] = 0.f;
#pragma unroll
    for (int i4 = 0; i4 < 16; ++i4) {
      float4 k4 = *(const float4*)(kr + i4 * 4);
#pragma unroll
      for (int q = 0; q < 5; ++q) {
        float4 qv = *(const float4*)&Qs[q][i4 * 4];
        acc[q] += k4.x * qv.x + k4.y * qv.y + k4.z * qv.z + k4.w * qv.w;
      }
    }
#pragma unroll
    for (int q = 0; q < 5; ++q) Sv[q][key] = acc[q] * SCALE_;
  }
  __syncthreads();

#pragma unroll
  for (int rep = 0; rep < 2; ++rep) {
    int r = (rep == 0) ? w : (w == 0 ? 4 : -1);
    if (r >= 0) {
      float mx = -INFINITY;
      for (int j = 0; j < 32; ++j) mx = fmaxf(mx, Sv[r][j * 64 + lane]);
#pragma unroll
      for (int off = 1; off < 64; off <<= 1)
        mx = fmaxf(mx, __shfl_xor(mx, off));
      float sm = 0.f;
      for (int j = 0; j < 32; ++j) {
        float e = __expf(Sv[r][j * 64 + lane] - mx);
        Sv[r][j * 64 + lane] = e;
        sm += e;
      }
#pragma unroll
      for (int off = 1; off < 64; off <<= 1) sm += __shfl_xor(sm, off);
      if (lane == 0) inv[r] = 1.0f / sm;
    }
  }
  __syncthreads();

  {
    const float* vb = Vt + ((size_t)bh * L_ + w * 512) * DH_ + lane;
    float acc[5];
#pragma unroll
    for (int q = 0; q < 5; ++q) acc[q] = 0.f;
    for (int k4 = 0; k4 < 128; ++k4) {
      float v0 = vb[(k4 * 4 + 0) * DH_];
      float v1 = vb[(k4 * 4 + 1) * DH_];
      float v2 = vb[(k4 * 4 + 2) * DH_];
      float v3 = vb[(k4 * 4 + 3) * DH_];
      int k = w * 512 + k4 * 4;
#pragma unroll
      for (int q = 0; q < 5; ++q) {
        float4 p4 = *(const float4*)&Sv[q][k];
        acc[q] += p4.x * v0 + p4.y * v1 + p4.z * v2 + p4.w * v3;
      }
    }
#pragma unroll
    for (int q = 0; q < 5; ++q) part[w][q][lane] = acc[q];
  }
  __syncthreads();

  for (int o = t; o < 5 * DH_; o += 256) {
    int q = o >> 6, dh = o & 63;
    float s = (part[0][q][dh] + part[1][q][dh]) +
              (part[2][q][dh] + part[3][q][dh]);
    dv[q][dh] = s * inv[q] - vmeanM[b * D_ + h * DH_ + dh];
  }
  __syncthreads();

  int sub = t & 3;
  int jbase = t >> 2;
#pragma unroll
  for (int jc = 0; jc < 16; ++jc) {
    int j = jc * 64 + jbase;
    const float* wr = Wout + (size_t)j * D_ + h * DH_ + sub * 16;
    float4 w0 = ((const float4*)wr)[0];
    float4 w1 = ((const float4*)wr)[1];
    float4 w2 = ((const float4*)wr)[2];
    float4 w3 = ((const float4*)wr)[3];
#pragma unroll
    for (int q = 0; q < 5; ++q) {
      const float* dq = &dv[q][sub * 16];
      float s = dq[0] * w0.x + dq[1] * w0.y + dq[2] * w0.z + dq[3] * w0.w +
                dq[4] * w1.x + dq[5] * w1.y + dq[6] * w1.z + dq[7] * w1.w +
                dq[8] * w2.x + dq[9] * w2.y + dq[10] * w2.z + dq[11] * w2.w +
                dq[12] * w3.x + dq[13] * w3.y + dq[14] * w3.z + dq[15] * w3.w;
      s += __shfl_xor(s, 1);
      s += __shfl_xor(s, 2);
      if (sub == 0)
        atomicAdd(out + ((size_t)b * L_ + lq[q]) * D_ + j, s);
    }
  }
}

// ---------------------------------------------------------------------------
extern "C" void kernel_launch(void* const* d_in, const int* in_sizes, int n_in,
                              void* d_out, int out_size, void* d_ws,
                              size_t ws_size, hipStream_t stream) {
  const float* x    = (const float*)d_in[0];
  const float* Wq   = (const float*)d_in[1];
  const float* bq   = (const float*)d_in[2];
  const float* Wkv  = (const float*)d_in[3];
  const float* bkv  = (const float*)d_in[4];
  const float* Wout = (const float*)d_in[5];
  const float* bout = (const float*)d_in[6];
  const int*   idx  = (const int*)d_in[7];
  float* out = (float*)d_out;

  float* ws = (float*)d_ws;
  const size_t NQ = (size_t)B_ * H_ * L_ * DH_;  // 4,194,304 floats
  float* Q  = ws;
  float* Kt = Q + NQ;
  float* Vt = Kt + NQ;
  // W/X split region (live only through the GEMM)
  unsigned short* Whi = (unsigned short*)(Vt + NQ);  // 6 MB
  unsigned short* Wlo = Whi + (size_t)3 * D_ * D_;   // 6 MB
  unsigned short* Xhi = Wlo + (size_t)3 * D_ * D_;   // 8 MB (optional)
  unsigned short* Xlo = Xhi + NQ;                    // 8 MB (optional)
  // phase-2 region (overlaps split region; used only after the GEMM)
  float* Mv     = Vt + NQ;                           // 256 KB
  float* vmeanM = Mv + (size_t)B_ * H_ * L_;         // 8 KB
  float* baseB  = vmeanM + B_ * D_;                  // 8 KB
  int*   topIdx = (int*)(baseB + B_ * D_);           // 5 KB
  // vmean accumulator lives in d_out[0:2048].
  float* vmAcc = out;

  const bool xsplit = ws_size >= ((size_t)76 << 20);
  const int nW = 3 * D_ * D_ / 4;
  const int nX = (int)(NQ / 4);

  if (xsplit) {
    split_all<<<dim3((nW + nX) / 256), dim3(256), 0, stream>>>(
        Wq, Wkv, x, Whi, Wlo, Xhi, Xlo, vmAcc, nW);
    gemm_qkv_8ph<<<dim3(3 * D_ / 192, B_ * L_ / 128), dim3(512), 0, stream>>>(
        Xhi, Xlo, Whi, Wlo, bq, bkv, Q, Kt, Vt, vmAcc);
  } else {
    split_all<<<dim3(nW / 256), dim3(256), 0, stream>>>(Wq, Wkv, x, Whi, Wlo,
                                                        Xhi, Xlo, vmAcc, nW);
    gemm_qkv_fallback<<<dim3(3 * D_ / 128, B_ * L_ / 128), dim3(256), 0,
                        stream>>>(x, Whi, Wlo, bq, bkv, Q, Kt, Vt, vmAcc);
  }
  base_kernel<<<dim3(B_ * 16), dim3(256), 0, stream>>>(vmAcc, Wout, bout,
                                                       baseB, vmeanM);
  bcast_out<<<dim3(B_ * L_ * D_ / 1024), dim3(256), 0, stream>>>(baseB, out);
  sample_m<<<dim3(B_ * H_ * L_ / 16), dim3(256), 0, stream>>>(Q, Kt, idx, Mv);
  topk_kernel<<<dim3(B_ * H_), dim3(64), 0, stream>>>(Mv, topIdx);
  attn_corr<<<dim3(8, 32), dim3(256), 0, stream>>>(Q, Kt, Vt, topIdx, vmeanM,
                                                   Wout, out);
}

// Round 13
// 238.628 us; speedup vs baseline: 1.7905x; 1.0287x over previous
//
#include <hip/hip_runtime.h>
#include <math.h>

// Problem constants (B=2, L=2048, D=1024, H=16, FACTOR=5)
#define B_ 2
#define L_ 2048
#define D_ 1024
#define H_ 16
#define DH_ 64
#define U_ 40
#define SCALE_ 0.125f

typedef __attribute__((ext_vector_type(8))) short short8v;            // 8 bf16
typedef __attribute__((ext_vector_type(4))) float f32x4;
typedef __attribute__((ext_vector_type(4))) unsigned short ushort4v;  // 8 B

static __device__ __forceinline__ unsigned short bf16_rne(float f) {
  unsigned int u = __float_as_uint(f);
  u += 0x7fff + ((u >> 16) & 1);
  return (unsigned short)(u >> 16);
}
static __device__ __forceinline__ float bf16_f32(unsigned short h) {
  return __uint_as_float(((unsigned int)h) << 16);
}

// Async global->LDS, 16 B per lane.
static __device__ __forceinline__ void gload16(const unsigned short* src,
                                               unsigned short* lds) {
  __builtin_amdgcn_global_load_lds(
      (const __attribute__((address_space(1))) void*)src,
      (__attribute__((address_space(3))) void*)lds, 16, 0, 0);
}

#define BARRIER                                  \
  do {                                           \
    asm volatile("" ::: "memory");               \
    __builtin_amdgcn_s_barrier();                \
    asm volatile("" ::: "memory");               \
  } while (0)
// Rule #18: force all LDS reads to retire and pin instruction movement.
#define LGKM0                                          \
  do {                                                 \
    asm volatile("s_waitcnt lgkmcnt(0)" ::: "memory"); \
    __builtin_amdgcn_sched_barrier(0);                 \
  } while (0)

// ---------------------------------------------------------------------------
// Pre-split f32 -> (hi,lo) bf16 for W=[Wq;Wkv] (quads [0,nW)) and X (rest).
// Block 0 additionally zeroes the vmean accumulator (in d_out[0:2048]).
// ---------------------------------------------------------------------------
__global__ __launch_bounds__(256) void split_all(
    const float* __restrict__ Wq, const float* __restrict__ Wkv,
    const float* __restrict__ X, unsigned short* __restrict__ Whi,
    unsigned short* __restrict__ Wlo, unsigned short* __restrict__ Xhi,
    unsigned short* __restrict__ Xlo, float* __restrict__ vmAcc, int nW) {
  if (blockIdx.x == 0) {
    for (int z = threadIdx.x; z < B_ * D_; z += 256) vmAcc[z] = 0.f;
  }
  int i = blockIdx.x * 256 + threadIdx.x;
  const int nq_q = (D_ * D_) / 4;
  float4 v;
  unsigned short *hi, *lo;
  int off;
  if (i < nW) {
    v = (i < nq_q) ? ((const float4*)Wq)[i] : ((const float4*)Wkv)[i - nq_q];
    hi = Whi; lo = Wlo; off = i;
  } else {
    off = i - nW;
    v = ((const float4*)X)[off];
    hi = Xhi; lo = Xlo;
  }
  float vv[4] = {v.x, v.y, v.z, v.w};
  ushort4v h, l;
#pragma unroll
  for (int e = 0; e < 4; ++e) {
    unsigned short hh = bf16_rne(vv[e]);
    h[e] = hh;
    l[e] = bf16_rne(vv[e] - bf16_f32(hh));
  }
  ((ushort4v*)hi)[off] = h;
  ((ushort4v*)lo)[off] = l;
}

// ---------------------------------------------------------------------------
// Pipelined split-bf16 MFMA GEMM: C = X @ W^T + bias. Tile 128x192, BK=32,
// 8 waves (2Mx4N). 3 LDS buffers x 40 KB, counted vmcnt(5), 2 tiles in
// flight. ONE barrier per K-step; LGKM0 before it guarantees every wave's
// LDS reads retired inside the step (rule #18 — MFMAs are register-only and
// may sink past the asm barrier, deferring the compiler's lgkmcnt).
// ---------------------------------------------------------------------------
__global__ __launch_bounds__(512, 1) void gemm_qkv_pipe(
    const unsigned short* __restrict__ Xhi,
    const unsigned short* __restrict__ Xlo,
    const unsigned short* __restrict__ Whi,
    const unsigned short* __restrict__ Wlo,
    const float* __restrict__ bq, const float* __restrict__ bkv,
    float* __restrict__ Qo, float* __restrict__ Ko, float* __restrict__ Vo,
    float* __restrict__ vmAcc) {
  // Per buffer (shorts): Ah[128*32]@0, Al@4096, Bh[192*32]@8192, Bl@14336.
  __shared__ unsigned short LDS[3][20480];
  const int tid = threadIdx.x;  // 0..511
  const int lane = tid & 63;
  const int wave = tid >> 6;            // 0..7
  const int wm = wave >> 2, wn = wave & 3;
  const int row0 = blockIdx.y * 128;    // M = 4096 -> 32 blocks
  const int col0 = blockIdx.x * 192;    // N = 3072 -> 16 blocks

  f32x4 acc[4][3] = {};

  // Flat staging: 40 x 1KB calls per tile; call c = wave + 8*r, r=0..4.
  const unsigned short* gsrc[5];
#pragma unroll
  for (int r = 0; r < 5; ++r) {
    int c = wave + 8 * r;
    const unsigned short* base;
    int rowin, isA;
    if (c < 8)       { base = Xhi; rowin = c * 16;        isA = 1; }
    else if (c < 16) { base = Xlo; rowin = (c - 8) * 16;  isA = 1; }
    else if (c < 28) { base = Whi; rowin = (c - 16) * 16; isA = 0; }
    else             { base = Wlo; rowin = (c - 28) * 16; isA = 0; }
    rowin += (lane >> 2);
    int grow = (isA ? row0 : col0) + rowin;
    int seg = (lane & 3) ^ ((rowin >> 1) & 3);
    gsrc[r] = base + (size_t)grow * D_ + seg * 8;
  }

  const int fr_r = lane & 15;
  const int hs = lane >> 4;

#define STG(r, k0s, Ls) \
  gload16(gsrc[r] + (k0s), (Ls) + (wave + 8 * (r)) * 512)

  // Prologue: stage tiles 0 and 1 into buffers 0, 1.
  {
    unsigned short* L0 = &LDS[0][0];
    unsigned short* L1 = &LDS[1][0];
    STG(0, 0, L0); STG(1, 0, L0); STG(2, 0, L0); STG(3, 0, L0); STG(4, 0, L0);
    STG(0, 32, L1); STG(1, 32, L1); STG(2, 32, L1); STG(3, 32, L1);
    STG(4, 32, L1);
  }
  asm volatile("s_waitcnt vmcnt(5)" ::: "memory");
  BARRIER;

  for (int ks = 0; ks < 32; ++ks) {
    unsigned short* Lc = &LDS[ks % 3][0];
    unsigned short* Ls = &LDS[(ks + 2) % 3][0];
    int k0s = (ks + 2) * 32;

    // Stage tile ks+2 (fire-and-forget; counted vmcnt at step end)
    if (ks < 30) {
      STG(0, k0s, Ls); STG(1, k0s, Ls); STG(2, k0s, Ls); STG(3, k0s, Ls);
      STG(4, k0s, Ls);
    }

    // Fragment reads (compiler interleaves with MFMA via fine lgkmcnt)
    short8v a_h[4], a_l[4], b_h[3], b_l[3];
#pragma unroll
    for (int mi = 0; mi < 4; ++mi) {
      int rr = wm * 64 + mi * 16 + fr_r;
      int off = rr * 32 + ((hs ^ ((rr >> 1) & 3)) << 3);
      a_h[mi] = *(const short8v*)&Lc[off];
      a_l[mi] = *(const short8v*)&Lc[4096 + off];
    }
#pragma unroll
    for (int ni = 0; ni < 3; ++ni) {
      int rc = wn * 48 + ni * 16 + fr_r;
      int off = rc * 32 + ((hs ^ ((rc >> 1) & 3)) << 3);
      b_h[ni] = *(const short8v*)&Lc[8192 + off];
      b_l[ni] = *(const short8v*)&Lc[14336 + off];
    }

#pragma unroll
    for (int mi = 0; mi < 4; ++mi)
#pragma unroll
      for (int ni = 0; ni < 3; ++ni) {
        acc[mi][ni] = __builtin_amdgcn_mfma_f32_16x16x32_bf16(
            a_h[mi], b_h[ni], acc[mi][ni], 0, 0, 0);
        acc[mi][ni] = __builtin_amdgcn_mfma_f32_16x16x32_bf16(
            a_h[mi], b_l[ni], acc[mi][ni], 0, 0, 0);
        acc[mi][ni] = __builtin_amdgcn_mfma_f32_16x16x32_bf16(
            a_l[mi], b_h[ni], acc[mi][ni], 0, 0, 0);
      }

    // All LDS reads of this step must retire before any wave can cross the
    // barrier and overwrite buffer ks%3 at step ks+1 (rule #18).
    LGKM0;
    // Counted vmcnt: tile ks+1's 5 loads must be complete; this step's 5
    // (tile ks+2) stay in flight.
    if (ks < 30) {
      asm volatile("s_waitcnt vmcnt(5)" ::: "memory");
    } else {
      asm volatile("s_waitcnt vmcnt(0)" ::: "memory");
    }
    BARRIER;
  }

  // Epilogue: C/D layout col=lane&15, row=(lane>>4)*4+reg.
#pragma unroll
  for (int ni = 0; ni < 3; ++ni) {
    int c = col0 + wn * 48 + ni * 16 + (lane & 15);
    int which = c >> 10;
    int jj = c & (D_ - 1);
    int h = jj >> 6, dh = jj & 63;
    float bias = (c < D_) ? bq[c] : bkv[c - D_];
    float* dst = (which == 0) ? Qo : ((which == 1) ? Ko : Vo);
#pragma unroll
    for (int mi = 0; mi < 4; ++mi) {
#pragma unroll
      for (int reg = 0; reg < 4; ++reg) {
        int r = row0 + wm * 64 + mi * 16 + ((lane >> 4) << 2) + reg;
        int b = r >> 11, l = r & (L_ - 1);
        dst[(((size_t)b * H_ + h) * L_ + l) * DH_ + dh] =
            acc[mi][ni][reg] + bias;
      }
    }
    if (which == 2) {  // vmean partial: sum over this wave's 64 rows
      float s = 0.f;
#pragma unroll
      for (int mi = 0; mi < 4; ++mi)
#pragma unroll
        for (int reg = 0; reg < 4; ++reg) s += acc[mi][ni][reg];
      s += __shfl_xor(s, 16);
      s += __shfl_xor(s, 32);
      if ((lane >> 4) == 0)
        atomicAdd(&vmAcc[(row0 >> 11) * D_ + jj], s + 64.0f * bias);
    }
  }
#undef STG
}

// ---------------------------------------------------------------------------
// Fallback GEMM (R10 structure) — used only when ws can't hold Xhi/Xlo.
// ---------------------------------------------------------------------------
__global__ __launch_bounds__(256) void gemm_qkv_fallback(
    const float* __restrict__ X,
    const unsigned short* __restrict__ Whi,
    const unsigned short* __restrict__ Wlo,
    const float* __restrict__ bq, const float* __restrict__ bkv,
    float* __restrict__ Qo, float* __restrict__ Ko, float* __restrict__ Vo,
    float* __restrict__ vmAcc) {
  __shared__ unsigned short Ah[128 * 32];
  __shared__ unsigned short Al[128 * 32];
  __shared__ unsigned short Bh[128 * 32];
  __shared__ unsigned short Bl[128 * 32];
  const int tid = threadIdx.x;
  const int lane = tid & 63;
  const int wave = tid >> 6;
  const int wm = wave >> 1, wn = wave & 1;
  const int row0 = blockIdx.y * 128;
  const int col0 = blockIdx.x * 128;

  f32x4 acc[4][4] = {};

  const int grow = lane >> 2;
  const int gg = lane & 3;

  for (int k0 = 0; k0 < D_; k0 += 32) {
#pragma unroll
    for (int j = 0; j < 2; ++j) {
      int c = wave + 4 * j;
      int row = c * 16 + grow;
      int gsrc = (gg ^ ((row >> 1) & 3)) << 3;
      size_t soffB = (size_t)(col0 + row) * D_ + k0 + gsrc;
      gload16(Whi + soffB, Bh + c * 512);
      gload16(Wlo + soffB, Bl + c * 512);
    }
#pragma unroll
    for (int rep = 0; rep < 2; ++rep) {
      int task = tid + rep * 256;
      int row = task >> 2;
      int gt = task & 3;
      const float* s = X + (size_t)(row0 + row) * D_ + k0 + gt * 8;
      float4 a0 = *(const float4*)s;
      float4 a1 = *(const float4*)(s + 4);
      float av[8] = {a0.x, a0.y, a0.z, a0.w, a1.x, a1.y, a1.z, a1.w};
      short8v hseg, lseg;
#pragma unroll
      for (int e = 0; e < 8; ++e) {
        unsigned short hh = bf16_rne(av[e]);
        hseg[e] = (short)hh;
        lseg[e] = (short)bf16_rne(av[e] - bf16_f32(hh));
      }
      int dst = row * 32 + ((gt ^ ((row >> 1) & 3)) << 3);
      *(short8v*)&Ah[dst] = hseg;
      *(short8v*)&Al[dst] = lseg;
    }
    __syncthreads();

    short8v a_h[4], a_l[4], b_h[4], b_l[4];
    const int hs = lane >> 4;
#pragma unroll
    for (int mi = 0; mi < 4; ++mi) {
      int rr = wm * 64 + mi * 16 + (lane & 15);
      int off = rr * 32 + ((hs ^ ((rr >> 1) & 3)) << 3);
      a_h[mi] = *(const short8v*)&Ah[off];
      a_l[mi] = *(const short8v*)&Al[off];
    }
#pragma unroll
    for (int ni = 0; ni < 4; ++ni) {
      int rc = wn * 64 + ni * 16 + (lane & 15);
      int off = rc * 32 + ((hs ^ ((rc >> 1) & 3)) << 3);
      b_h[ni] = *(const short8v*)&Bh[off];
      b_l[ni] = *(const short8v*)&Bl[off];
    }
#pragma unroll
    for (int mi = 0; mi < 4; ++mi)
#pragma unroll
      for (int ni = 0; ni < 4; ++ni) {
        acc[mi][ni] = __builtin_amdgcn_mfma_f32_16x16x32_bf16(
            a_h[mi], b_h[ni], acc[mi][ni], 0, 0, 0);
        acc[mi][ni] = __builtin_amdgcn_mfma_f32_16x16x32_bf16(
            a_h[mi], b_l[ni], acc[mi][ni], 0, 0, 0);
        acc[mi][ni] = __builtin_amdgcn_mfma_f32_16x16x32_bf16(
            a_l[mi], b_h[ni], acc[mi][ni], 0, 0, 0);
      }
    __syncthreads();
  }

#pragma unroll
  for (int ni = 0; ni < 4; ++ni) {
    int c = col0 + wn * 64 + ni * 16 + (lane & 15);
    int which = c >> 10;
    int jj = c & (D_ - 1);
    int h = jj >> 6, dh = jj & 63;
    float bias = (c < D_) ? bq[c] : bkv[c - D_];
    float* dst = (which == 0) ? Qo : ((which == 1) ? Ko : Vo);
#pragma unroll
    for (int mi = 0; mi < 4; ++mi) {
#pragma unroll
      for (int reg = 0; reg < 4; ++reg) {
        int r = row0 + wm * 64 + mi * 16 + ((lane >> 4) << 2) + reg;
        int b = r >> 11, l = r & (L_ - 1);
        dst[(((size_t)b * H_ + h) * L_ + l) * DH_ + dh] =
            acc[mi][ni][reg] + bias;
      }
    }
    if (which == 2) {
      float s = 0.f;
#pragma unroll
      for (int mi = 0; mi < 4; ++mi)
#pragma unroll
        for (int reg = 0; reg < 4; ++reg) s += acc[mi][ni][reg];
      s += __shfl_xor(s, 16);
      s += __shfl_xor(s, 32);
      if ((lane >> 4) == 0)
        atomicAdd(&vmAcc[(row0 >> 11) * D_ + jj], s + 64.0f * bias);
    }
  }
}

// ---------------------------------------------------------------------------
// Merged kernel A: blocks [0,4096) = sample_m; blocks [4096,4128) = base.
// ---------------------------------------------------------------------------
__global__ __launch_bounds__(256) void sample_base(
    const float* __restrict__ Q, const float* __restrict__ Kt,
    const int* __restrict__ idx, float* __restrict__ Mv,
    const float* __restrict__ vmAcc, const float* __restrict__ Wout,
    const float* __restrict__ bout, float* __restrict__ baseOut,
    float* __restrict__ vmeanM) {
  int t = threadIdx.x;
  if (blockIdx.x < 4096) {
    // ---- sample_m
    int w = t >> 6, lane = t & 63;
    int subl = lane >> 4, d16 = lane & 15;
    int gl = blockIdx.x * 16 + w * 4 + subl;  // bh*L + l
    int bh = gl >> 11, l = gl & (L_ - 1);
    const float4* Kb4 = (const float4*)(Kt + (size_t)bh * L_ * DH_);
    float4 q4 = ((const float4*)(Q + (size_t)gl * DH_))[d16];
    const int* irow = idx + l * U_;
    float mx = -INFINITY, sm = 0.f;
#pragma unroll 8
    for (int u = 0; u < U_; ++u) {
      int kl = irow[u];
      float4 k4 = Kb4[kl * 16 + d16];
      float p = q4.x * k4.x + q4.y * k4.y + q4.z * k4.z + q4.w * k4.w;
      p += __shfl_xor(p, 1);
      p += __shfl_xor(p, 2);
      p += __shfl_xor(p, 4);
      p += __shfl_xor(p, 8);
      mx = fmaxf(mx, p);
      sm += p;
    }
    if (d16 == 0) Mv[gl] = mx - sm * (1.0f / U_);
  } else {
    // ---- base
    int bid = blockIdx.x - 4096;
    int b = bid >> 4, jc = bid & 15;
    int j = jc * 64 + (t & 63);
    int isl = t >> 6;
    __shared__ float vm[D_];
    __shared__ float red[256];
    for (int i = t; i < D_; i += 256) vm[i] = vmAcc[b * D_ + i] * (1.0f / L_);
    __syncthreads();
    if (jc == 0)
      for (int i = t; i < D_; i += 256) vmeanM[b * D_ + i] = vm[i];
    float s = 0.f;
    const float* wr = Wout + (size_t)j * D_ + isl * 256;
    const float* vv = vm + isl * 256;
    for (int i = 0; i < 256; i += 4) {
      float4 w = *(const float4*)(wr + i);
      s += vv[i] * w.x + vv[i + 1] * w.y + vv[i + 2] * w.z + vv[i + 3] * w.w;
    }
    red[t] = s;
    __syncthreads();
    if (isl == 0)
      baseOut[b * D_ + j] =
          red[t] + red[t + 64] + red[t + 128] + red[t + 192] + bout[j];
  }
}

// ---------------------------------------------------------------------------
// Merged kernel B: blocks [0,4096) = bcast_out (4096*1024 = 4M = B*L*D);
// blocks [4096,4128) = topk (one bh each, 4 redundant waves).
// ---------------------------------------------------------------------------
__global__ __launch_bounds__(256) void bcast_topk(
    const float* __restrict__ baseIn, float* __restrict__ out,
    const float* __restrict__ Mv, int* __restrict__ topIdx) {
  int t = threadIdx.x;
  if (blockIdx.x < 4096) {
    size_t i4 = (size_t)blockIdx.x * 256 + t;
    size_t i = i4 * 4;
    int b = (int)(i >> 21);
    int col = (int)(i & (D_ - 1));
    *(float4*)(out + i) = *(const float4*)(baseIn + b * D_ + col);
  } else {
    __shared__ float vals[L_];
    int lane = t & 63;
    int bh = blockIdx.x - 4096;
    for (int j = t; j < L_; j += 256) vals[j] = Mv[(size_t)bh * L_ + j];
    __syncthreads();
    for (int it = 0; it < U_; ++it) {
      float bv = -INFINITY;
      int bi = 0x7fffffff;
      for (int j = 0; j < 32; ++j) {
        int i = j * 64 + lane;
        float v = vals[i];
        if (v > bv) { bv = v; bi = i; }
      }
#pragma unroll
      for (int off = 32; off > 0; off >>= 1) {
        float ov = __shfl_xor(bv, off);
        int oi = __shfl_xor(bi, off);
        if (ov > bv || (ov == bv && oi < bi)) { bv = ov; bi = oi; }
      }
      if (t == 0) topIdx[bh * U_ + it] = bi;
      vals[bi] = -INFINITY;  // all waves compute identical bi
      __syncthreads();
    }
  }
}

// ---------------------------------------------------------------------------
// Fused attention + output correction (unchanged from R10/R11).
// ---------------------------------------------------------------------------
__global__ __launch_bounds__(256) void attn_corr(
    const float* __restrict__ Q, const float* __restrict__ Kt,
    const float* __restrict__ Vt, const int* __restrict__ topIdx,
    const float* __restrict__ vmeanM, const float* __restrict__ Wout,
    float* __restrict__ out) {
  int qc = blockIdx.x;  // 0..7 (5 queries each)
  int bh = blockIdx.y;  // 0..31
  int b = bh >> 4, h = bh & (H_ - 1);
  __shared__ float Qs[5][DH_];
  __shared__ float Sv[5][L_];
  __shared__ float part[4][5][DH_];
  __shared__ float inv[5];
  __shared__ float dv[5][DH_];
  __shared__ int lq[5];
  int t = threadIdx.x;
  int lane = t & 63, w = t >> 6;

  if (t < 80) {
    int q = t >> 4, c4 = t & 15;
    int ql = topIdx[bh * U_ + qc * 5 + q];
    *(float4*)&Qs[q][c4 * 4] =
        *(const float4*)&Q[((size_t)bh * L_ + ql) * DH_ + c4 * 4];
  }
  if (t < 5) lq[t] = topIdx[bh * U_ + qc * 5 + t];
  __syncthreads();

  const float* Kb = Kt + (size_t)bh * L_ * DH_;
  for (int kc = 0; kc < 8; ++kc) {
    int key = kc * 256 + t;
    const float* kr = Kb + (size_t)key * DH_;
    float acc[5];
#pragma unroll
    for (int q = 0; q < 5; ++q) acc[q] = 0.f;
#pragma unroll
    for (int i4 = 0; i4 < 16; ++i4) {
      float4 k4 = *(const float4*)(kr + i4 * 4);
#pragma unroll
      for (int q = 0; q < 5; ++q) {
        float4 qv = *(const float4*)&Qs[q][i4 * 4];
        acc[q] += k4.x * qv.x + k4.y * qv.y + k4.z * qv.z + k4.w * qv.w;
      }
    }
#pragma unroll
    for (int q = 0; q < 5; ++q) Sv[q][key] = acc[q] * SCALE_;
  }
  __syncthreads();

#pragma unroll
  for (int rep = 0; rep < 2; ++rep) {
    int r = (rep == 0) ? w : (w == 0 ? 4 : -1);
    if (r >= 0) {
      float mx = -INFINITY;
      for (int j = 0; j < 32; ++j) mx = fmaxf(mx, Sv[r][j * 64 + lane]);
#pragma unroll
      for (int off = 1; off < 64; off <<= 1)
        mx = fmaxf(mx, __shfl_xor(mx, off));
      float sm = 0.f;
      for (int j = 0; j < 32; ++j) {
        float e = __expf(Sv[r][j * 64 + lane] - mx);
        Sv[r][j * 64 + lane] = e;
        sm += e;
      }
#pragma unroll
      for (int off = 1; off < 64; off <<= 1) sm += __shfl_xor(sm, off);
      if (lane == 0) inv[r] = 1.0f / sm;
    }
  }
  __syncthreads();

  {
    const float* vb = Vt + ((size_t)bh * L_ + w * 512) * DH_ + lane;
    float acc[5];
#pragma unroll
    for (int q = 0; q < 5; ++q) acc[q] = 0.f;
    for (int k4 = 0; k4 < 128; ++k4) {
      float v0 = vb[(k4 * 4 + 0) * DH_];
      float v1 = vb[(k4 * 4 + 1) * DH_];
      float v2 = vb[(k4 * 4 + 2) * DH_];
      float v3 = vb[(k4 * 4 + 3) * DH_];
      int k = w * 512 + k4 * 4;
#pragma unroll
      for (int q = 0; q < 5; ++q) {
        float4 p4 = *(const float4*)&Sv[q][k];
        acc[q] += p4.x * v0 + p4.y * v1 + p4.z * v2 + p4.w * v3;
      }
    }
#pragma unroll
    for (int q = 0; q < 5; ++q) part[w][q][lane] = acc[q];
  }
  __syncthreads();

  for (int o = t; o < 5 * DH_; o += 256) {
    int q = o >> 6, dh = o & 63;
    float s = (part[0][q][dh] + part[1][q][dh]) +
              (part[2][q][dh] + part[3][q][dh]);
    dv[q][dh] = s * inv[q] - vmeanM[b * D_ + h * DH_ + dh];
  }
  __syncthreads();

  int sub = t & 3;
  int jbase = t >> 2;
#pragma unroll
  for (int jc = 0; jc < 16; ++jc) {
    int j = jc * 64 + jbase;
    const float* wr = Wout + (size_t)j * D_ + h * DH_ + sub * 16;
    float4 w0 = ((const float4*)wr)[0];
    float4 w1 = ((const float4*)wr)[1];
    float4 w2 = ((const float4*)wr)[2];
    float4 w3 = ((const float4*)wr)[3];
#pragma unroll
    for (int q = 0; q < 5; ++q) {
      const float* dq = &dv[q][sub * 16];
      float s = dq[0] * w0.x + dq[1] * w0.y + dq[2] * w0.z + dq[3] * w0.w +
                dq[4] * w1.x + dq[5] * w1.y + dq[6] * w1.z + dq[7] * w1.w +
                dq[8] * w2.x + dq[9] * w2.y + dq[10] * w2.z + dq[11] * w2.w +
                dq[12] * w3.x + dq[13] * w3.y + dq[14] * w3.z + dq[15] * w3.w;
      s += __shfl_xor(s, 1);
      s += __shfl_xor(s, 2);
      if (sub == 0)
        atomicAdd(out + ((size_t)b * L_ + lq[q]) * D_ + j, s);
    }
  }
}

// ---------------------------------------------------------------------------
extern "C" void kernel_launch(void* const* d_in, const int* in_sizes, int n_in,
                              void* d_out, int out_size, void* d_ws,
                              size_t ws_size, hipStream_t stream) {
  const float* x    = (const float*)d_in[0];
  const float* Wq   = (const float*)d_in[1];
  const float* bq   = (const float*)d_in[2];
  const float* Wkv  = (const float*)d_in[3];
  const float* bkv  = (const float*)d_in[4];
  const float* Wout = (const float*)d_in[5];
  const float* bout = (const float*)d_in[6];
  const int*   idx  = (const int*)d_in[7];
  float* out = (float*)d_out;

  float* ws = (float*)d_ws;
  const size_t NQ = (size_t)B_ * H_ * L_ * DH_;  // 4,194,304 floats
  float* Q  = ws;
  float* Kt = Q + NQ;
  float* Vt = Kt + NQ;
  // W/X split region (live only through the GEMM)
  unsigned short* Whi = (unsigned short*)(Vt + NQ);  // 6 MB
  unsigned short* Wlo = Whi + (size_t)3 * D_ * D_;   // 6 MB
  unsigned short* Xhi = Wlo + (size_t)3 * D_ * D_;   // 8 MB (optional)
  unsigned short* Xlo = Xhi + NQ;                    // 8 MB (optional)
  // phase-2 region (overlaps split region; used only after the GEMM)
  float* Mv     = Vt + NQ;                           // 256 KB
  float* vmeanM = Mv + (size_t)B_ * H_ * L_;         // 8 KB
  float* baseB  = vmeanM + B_ * D_;                  // 8 KB
  int*   topIdx = (int*)(baseB + B_ * D_);           // 5 KB
  // vmean accumulator lives in d_out[0:2048].
  float* vmAcc = out;

  const bool xsplit = ws_size >= ((size_t)76 << 20);
  const int nW = 3 * D_ * D_ / 4;
  const int nX = (int)(NQ / 4);

  if (xsplit) {
    split_all<<<dim3((nW + nX) / 256), dim3(256), 0, stream>>>(
        Wq, Wkv, x, Whi, Wlo, Xhi, Xlo, vmAcc, nW);
    gemm_qkv_pipe<<<dim3(3 * D_ / 192, B_ * L_ / 128), dim3(512), 0,
                    stream>>>(Xhi, Xlo, Whi, Wlo, bq, bkv, Q, Kt, Vt, vmAcc);
  } else {
    split_all<<<dim3(nW / 256), dim3(256), 0, stream>>>(Wq, Wkv, x, Whi, Wlo,
                                                        Xhi, Xlo, vmAcc, nW);
    gemm_qkv_fallback<<<dim3(3 * D_ / 128, B_ * L_ / 128), dim3(256), 0,
                        stream>>>(x, Whi, Wlo, bq, bkv, Q, Kt, Vt, vmAcc);
  }
  sample_base<<<dim3(4096 + B_ * 16), dim3(256), 0, stream>>>(
      Q, Kt, idx, Mv, vmAcc, Wout, bout, baseB, vmeanM);
  bcast_topk<<<dim3(4096 + B_ * H_), dim3(256), 0, stream>>>(baseB, out, Mv,
                                                             topIdx);
  attn_corr<<<dim3(8, 32), dim3(256), 0, stream>>>(Q, Kt, Vt, topIdx, vmeanM,
                                                   Wout, out);
}

// Round 14
// 229.413 us; speedup vs baseline: 1.8625x; 1.0402x over previous
//
#include <hip/hip_runtime.h>
#include <math.h>

// Problem constants (B=2, L=2048, D=1024, H=16, FACTOR=5)
#define B_ 2
#define L_ 2048
#define D_ 1024
#define H_ 16
#define DH_ 64
#define U_ 40
#define SCALE_ 0.125f

typedef __attribute__((ext_vector_type(8))) short short8v;            // 8 bf16
typedef __attribute__((ext_vector_type(4))) float f32x4;
typedef __attribute__((ext_vector_type(4))) unsigned short ushort4v;  // 8 B

static __device__ __forceinline__ unsigned short bf16_rne(float f) {
  unsigned int u = __float_as_uint(f);
  u += 0x7fff + ((u >> 16) & 1);
  return (unsigned short)(u >> 16);
}
static __device__ __forceinline__ float bf16_f32(unsigned short h) {
  return __uint_as_float(((unsigned int)h) << 16);
}

// Async global->LDS, 16 B per lane.
static __device__ __forceinline__ void gload16(const unsigned short* src,
                                               unsigned short* lds) {
  __builtin_amdgcn_global_load_lds(
      (const __attribute__((address_space(1))) void*)src,
      (__attribute__((address_space(3))) void*)lds, 16, 0, 0);
}

#define BARRIER                                  \
  do {                                           \
    asm volatile("" ::: "memory");               \
    __builtin_amdgcn_s_barrier();                \
    asm volatile("" ::: "memory");               \
  } while (0)
// Rule #18: force all LDS reads to retire and pin instruction movement.
#define LGKM0                                          \
  do {                                                 \
    asm volatile("s_waitcnt lgkmcnt(0)" ::: "memory"); \
    __builtin_amdgcn_sched_barrier(0);                 \
  } while (0)

// ---------------------------------------------------------------------------
// Pre-split f32 -> (hi,lo) bf16 for W=[Wq;Wkv] (quads [0,nW)) and X (rest).
// Block 0 additionally zeroes the vmean accumulator (in d_out[0:2048]).
// ---------------------------------------------------------------------------
__global__ __launch_bounds__(256) void split_all(
    const float* __restrict__ Wq, const float* __restrict__ Wkv,
    const float* __restrict__ X, unsigned short* __restrict__ Whi,
    unsigned short* __restrict__ Wlo, unsigned short* __restrict__ Xhi,
    unsigned short* __restrict__ Xlo, float* __restrict__ vmAcc, int nW) {
  if (blockIdx.x == 0) {
    for (int z = threadIdx.x; z < B_ * D_; z += 256) vmAcc[z] = 0.f;
  }
  int i = blockIdx.x * 256 + threadIdx.x;
  const int nq_q = (D_ * D_) / 4;
  float4 v;
  unsigned short *hi, *lo;
  int off;
  if (i < nW) {
    v = (i < nq_q) ? ((const float4*)Wq)[i] : ((const float4*)Wkv)[i - nq_q];
    hi = Whi; lo = Wlo; off = i;
  } else {
    off = i - nW;
    v = ((const float4*)X)[off];
    hi = Xhi; lo = Xlo;
  }
  float vv[4] = {v.x, v.y, v.z, v.w};
  ushort4v h, l;
#pragma unroll
  for (int e = 0; e < 4; ++e) {
    unsigned short hh = bf16_rne(vv[e]);
    h[e] = hh;
    l[e] = bf16_rne(vv[e] - bf16_f32(hh));
  }
  ((ushort4v*)hi)[off] = h;
  ((ushort4v*)lo)[off] = l;
}

// ---------------------------------------------------------------------------
// Pipelined split-bf16 MFMA GEMM: C = X @ W^T + bias. Tile 256x192, BK=32,
// 8 waves (2Mx4N, per-wave 128x48 = 8x3 frags). 2 LDS buffers x 56 KB,
// prefetch distance 1, one barrier/step. 21-24% fewer LDS bytes per FLOP
// than the 128x192 tile (the binding resource). Grid 16x16 = 1 block/CU.
// ---------------------------------------------------------------------------
__global__ __launch_bounds__(512, 1) void gemm_qkv_256(
    const unsigned short* __restrict__ Xhi,
    const unsigned short* __restrict__ Xlo,
    const unsigned short* __restrict__ Whi,
    const unsigned short* __restrict__ Wlo,
    const float* __restrict__ bq, const float* __restrict__ bkv,
    float* __restrict__ Qo, float* __restrict__ Ko, float* __restrict__ Vo,
    float* __restrict__ vmAcc) {
  // Per buffer (shorts): Ahi[256*32]@0, Alo@8192, Bhi[192*32]@16384,
  // Blo@22528; total 28672 shorts = 56 KB. 2 buffers = 112 KB.
  __shared__ unsigned short LDS[2][28672];
  const int tid = threadIdx.x;  // 0..511
  const int lane = tid & 63;
  const int wave = tid >> 6;            // 0..7
  const int wm = wave >> 2, wn = wave & 3;
  const int row0 = blockIdx.y * 256;    // M = 4096 -> 16 blocks
  const int col0 = blockIdx.x * 192;    // N = 3072 -> 16 blocks

  f32x4 acc[8][3] = {};

  // Flat staging: 56 x 1KB calls per tile; call c = wave + 8*r, r=0..6.
  // c<16: Ahi rows c*16.. ; c<32: Alo ; c<44: Bhi ; else Blo.
  const unsigned short* gsrc[7];
#pragma unroll
  for (int r = 0; r < 7; ++r) {
    int c = wave + 8 * r;
    const unsigned short* base;
    int rowin, isA;
    if (c < 16)      { base = Xhi; rowin = c * 16;        isA = 1; }
    else if (c < 32) { base = Xlo; rowin = (c - 16) * 16; isA = 1; }
    else if (c < 44) { base = Whi; rowin = (c - 32) * 16; isA = 0; }
    else             { base = Wlo; rowin = (c - 44) * 16; isA = 0; }
    rowin += (lane >> 2);
    int grow = (isA ? row0 : col0) + rowin;
    int seg = (lane & 3) ^ ((rowin >> 1) & 3);
    gsrc[r] = base + (size_t)grow * D_ + seg * 8;
  }

  const int fr_r = lane & 15;
  const int hs = lane >> 4;

#define STG(r, k0s, Ls) \
  gload16(gsrc[r] + (k0s), (Ls) + ((wave + 8 * (r)) * 512))

  // Prologue: stage tile 0 into buffer 0.
  {
    unsigned short* L0 = &LDS[0][0];
    STG(0, 0, L0); STG(1, 0, L0); STG(2, 0, L0); STG(3, 0, L0);
    STG(4, 0, L0); STG(5, 0, L0); STG(6, 0, L0);
  }
  asm volatile("s_waitcnt vmcnt(0)" ::: "memory");
  BARRIER;

  for (int ks = 0; ks < 32; ++ks) {
    unsigned short* Lc = &LDS[ks & 1][0];
    unsigned short* Ls = &LDS[(ks + 1) & 1][0];
    int k0s = (ks + 1) * 32;

    // Stage tile ks+1 into the other buffer (readers of it retired at the
    // LGKM0+barrier of step ks-1).
    if (ks < 31) {
      STG(0, k0s, Ls); STG(1, k0s, Ls); STG(2, k0s, Ls); STG(3, k0s, Ls);
      STG(4, k0s, Ls); STG(5, k0s, Ls); STG(6, k0s, Ls);
    }

    // B fragments once; A fragments streamed through the mi loop.
    short8v b_h[3], b_l[3];
#pragma unroll
    for (int ni = 0; ni < 3; ++ni) {
      int rc = wn * 48 + ni * 16 + fr_r;
      int off = rc * 32 + ((hs ^ ((rc >> 1) & 3)) << 3);
      b_h[ni] = *(const short8v*)&Lc[16384 + off];
      b_l[ni] = *(const short8v*)&Lc[22528 + off];
    }
#pragma unroll
    for (int mi = 0; mi < 8; ++mi) {
      int rr = wm * 128 + mi * 16 + fr_r;
      int off = rr * 32 + ((hs ^ ((rr >> 1) & 3)) << 3);
      short8v a_h = *(const short8v*)&Lc[off];
      short8v a_l = *(const short8v*)&Lc[8192 + off];
#pragma unroll
      for (int ni = 0; ni < 3; ++ni) {
        acc[mi][ni] = __builtin_amdgcn_mfma_f32_16x16x32_bf16(
            a_h, b_h[ni], acc[mi][ni], 0, 0, 0);
        acc[mi][ni] = __builtin_amdgcn_mfma_f32_16x16x32_bf16(
            a_h, b_l[ni], acc[mi][ni], 0, 0, 0);
        acc[mi][ni] = __builtin_amdgcn_mfma_f32_16x16x32_bf16(
            a_l, b_h[ni], acc[mi][ni], 0, 0, 0);
      }
    }

    // All LDS reads of this step must retire before any wave can cross the
    // barrier and overwrite buffer ks&1 at step ks+1 (rule #18).
    LGKM0;
    // Staged loads for tile ks+1 must have landed (they had the whole step).
    asm volatile("s_waitcnt vmcnt(0)" ::: "memory");
    BARRIER;
  }

  // Epilogue: C/D layout col=lane&15, row=(lane>>4)*4+reg.
#pragma unroll
  for (int ni = 0; ni < 3; ++ni) {
    int c = col0 + wn * 48 + ni * 16 + (lane & 15);
    int which = c >> 10;
    int jj = c & (D_ - 1);
    int h = jj >> 6, dh = jj & 63;
    float bias = (c < D_) ? bq[c] : bkv[c - D_];
    float* dst = (which == 0) ? Qo : ((which == 1) ? Ko : Vo);
#pragma unroll
    for (int mi = 0; mi < 8; ++mi) {
#pragma unroll
      for (int reg = 0; reg < 4; ++reg) {
        int r = row0 + wm * 128 + mi * 16 + ((lane >> 4) << 2) + reg;
        int b = r >> 11, l = r & (L_ - 1);
        dst[(((size_t)b * H_ + h) * L_ + l) * DH_ + dh] =
            acc[mi][ni][reg] + bias;
      }
    }
    if (which == 2) {  // vmean partial: sum over this wave's 128 rows
      float s = 0.f;
#pragma unroll
      for (int mi = 0; mi < 8; ++mi)
#pragma unroll
        for (int reg = 0; reg < 4; ++reg) s += acc[mi][ni][reg];
      s += __shfl_xor(s, 16);
      s += __shfl_xor(s, 32);
      if ((lane >> 4) == 0)
        atomicAdd(&vmAcc[(row0 >> 11) * D_ + jj], s + 128.0f * bias);
    }
  }
#undef STG
}

// ---------------------------------------------------------------------------
// Fallback GEMM (R10 structure) — used only when ws can't hold Xhi/Xlo.
// ---------------------------------------------------------------------------
__global__ __launch_bounds__(256) void gemm_qkv_fallback(
    const float* __restrict__ X,
    const unsigned short* __restrict__ Whi,
    const unsigned short* __restrict__ Wlo,
    const float* __restrict__ bq, const float* __restrict__ bkv,
    float* __restrict__ Qo, float* __restrict__ Ko, float* __restrict__ Vo,
    float* __restrict__ vmAcc) {
  __shared__ unsigned short Ah[128 * 32];
  __shared__ unsigned short Al[128 * 32];
  __shared__ unsigned short Bh[128 * 32];
  __shared__ unsigned short Bl[128 * 32];
  const int tid = threadIdx.x;
  const int lane = tid & 63;
  const int wave = tid >> 6;
  const int wm = wave >> 1, wn = wave & 1;
  const int row0 = blockIdx.y * 128;
  const int col0 = blockIdx.x * 128;

  f32x4 acc[4][4] = {};

  const int grow = lane >> 2;
  const int gg = lane & 3;

  for (int k0 = 0; k0 < D_; k0 += 32) {
#pragma unroll
    for (int j = 0; j < 2; ++j) {
      int c = wave + 4 * j;
      int row = c * 16 + grow;
      int gsrc = (gg ^ ((row >> 1) & 3)) << 3;
      size_t soffB = (size_t)(col0 + row) * D_ + k0 + gsrc;
      gload16(Whi + soffB, Bh + c * 512);
      gload16(Wlo + soffB, Bl + c * 512);
    }
#pragma unroll
    for (int rep = 0; rep < 2; ++rep) {
      int task = tid + rep * 256;
      int row = task >> 2;
      int gt = task & 3;
      const float* s = X + (size_t)(row0 + row) * D_ + k0 + gt * 8;
      float4 a0 = *(const float4*)s;
      float4 a1 = *(const float4*)(s + 4);
      float av[8] = {a0.x, a0.y, a0.z, a0.w, a1.x, a1.y, a1.z, a1.w};
      short8v hseg, lseg;
#pragma unroll
      for (int e = 0; e < 8; ++e) {
        unsigned short hh = bf16_rne(av[e]);
        hseg[e] = (short)hh;
        lseg[e] = (short)bf16_rne(av[e] - bf16_f32(hh));
      }
      int dst = row * 32 + ((gt ^ ((row >> 1) & 3)) << 3);
      *(short8v*)&Ah[dst] = hseg;
      *(short8v*)&Al[dst] = lseg;
    }
    __syncthreads();

    short8v a_h[4], a_l[4], b_h[4], b_l[4];
    const int hs = lane >> 4;
#pragma unroll
    for (int mi = 0; mi < 4; ++mi) {
      int rr = wm * 64 + mi * 16 + (lane & 15);
      int off = rr * 32 + ((hs ^ ((rr >> 1) & 3)) << 3);
      a_h[mi] = *(const short8v*)&Ah[off];
      a_l[mi] = *(const short8v*)&Al[off];
    }
#pragma unroll
    for (int ni = 0; ni < 4; ++ni) {
      int rc = wn * 64 + ni * 16 + (lane & 15);
      int off = rc * 32 + ((hs ^ ((rc >> 1) & 3)) << 3);
      b_h[ni] = *(const short8v*)&Bh[off];
      b_l[ni] = *(const short8v*)&Bl[off];
    }
#pragma unroll
    for (int mi = 0; mi < 4; ++mi)
#pragma unroll
      for (int ni = 0; ni < 4; ++ni) {
        acc[mi][ni] = __builtin_amdgcn_mfma_f32_16x16x32_bf16(
            a_h[mi], b_h[ni], acc[mi][ni], 0, 0, 0);
        acc[mi][ni] = __builtin_amdgcn_mfma_f32_16x16x32_bf16(
            a_h[mi], b_l[ni], acc[mi][ni], 0, 0, 0);
        acc[mi][ni] = __builtin_amdgcn_mfma_f32_16x16x32_bf16(
            a_l[mi], b_h[ni], acc[mi][ni], 0, 0, 0);
      }
    __syncthreads();
  }

#pragma unroll
  for (int ni = 0; ni < 4; ++ni) {
    int c = col0 + wn * 64 + ni * 16 + (lane & 15);
    int which = c >> 10;
    int jj = c & (D_ - 1);
    int h = jj >> 6, dh = jj & 63;
    float bias = (c < D_) ? bq[c] : bkv[c - D_];
    float* dst = (which == 0) ? Qo : ((which == 1) ? Ko : Vo);
#pragma unroll
    for (int mi = 0; mi < 4; ++mi) {
#pragma unroll
      for (int reg = 0; reg < 4; ++reg) {
        int r = row0 + wm * 64 + mi * 16 + ((lane >> 4) << 2) + reg;
        int b = r >> 11, l = r & (L_ - 1);
        dst[(((size_t)b * H_ + h) * L_ + l) * DH_ + dh] =
            acc[mi][ni][reg] + bias;
      }
    }
    if (which == 2) {
      float s = 0.f;
#pragma unroll
      for (int mi = 0; mi < 4; ++mi)
#pragma unroll
        for (int reg = 0; reg < 4; ++reg) s += acc[mi][ni][reg];
      s += __shfl_xor(s, 16);
      s += __shfl_xor(s, 32);
      if ((lane >> 4) == 0)
        atomicAdd(&vmAcc[(row0 >> 11) * D_ + jj], s + 64.0f * bias);
    }
  }
}

// ---------------------------------------------------------------------------
// Merged kernel A: blocks [0,4096) = sample_m; blocks [4096,4128) = base.
// ---------------------------------------------------------------------------
__global__ __launch_bounds__(256) void sample_base(
    const float* __restrict__ Q, const float* __restrict__ Kt,
    const int* __restrict__ idx, float* __restrict__ Mv,
    const float* __restrict__ vmAcc, const float* __restrict__ Wout,
    const float* __restrict__ bout, float* __restrict__ baseOut,
    float* __restrict__ vmeanM) {
  int t = threadIdx.x;
  if (blockIdx.x < 4096) {
    // ---- sample_m
    int w = t >> 6, lane = t & 63;
    int subl = lane >> 4, d16 = lane & 15;
    int gl = blockIdx.x * 16 + w * 4 + subl;  // bh*L + l
    int bh = gl >> 11, l = gl & (L_ - 1);
    const float4* Kb4 = (const float4*)(Kt + (size_t)bh * L_ * DH_);
    float4 q4 = ((const float4*)(Q + (size_t)gl * DH_))[d16];
    const int* irow = idx + l * U_;
    float mx = -INFINITY, sm = 0.f;
#pragma unroll 8
    for (int u = 0; u < U_; ++u) {
      int kl = irow[u];
      float4 k4 = Kb4[kl * 16 + d16];
      float p = q4.x * k4.x + q4.y * k4.y + q4.z * k4.z + q4.w * k4.w;
      p += __shfl_xor(p, 1);
      p += __shfl_xor(p, 2);
      p += __shfl_xor(p, 4);
      p += __shfl_xor(p, 8);
      mx = fmaxf(mx, p);
      sm += p;
    }
    if (d16 == 0) Mv[gl] = mx - sm * (1.0f / U_);
  } else {
    // ---- base
    int bid = blockIdx.x - 4096;
    int b = bid >> 4, jc = bid & 15;
    int j = jc * 64 + (t & 63);
    int isl = t >> 6;
    __shared__ float vm[D_];
    __shared__ float red[256];
    for (int i = t; i < D_; i += 256) vm[i] = vmAcc[b * D_ + i] * (1.0f / L_);
    __syncthreads();
    if (jc == 0)
      for (int i = t; i < D_; i += 256) vmeanM[b * D_ + i] = vm[i];
    float s = 0.f;
    const float* wr = Wout + (size_t)j * D_ + isl * 256;
    const float* vv = vm + isl * 256;
    for (int i = 0; i < 256; i += 4) {
      float4 w = *(const float4*)(wr + i);
      s += vv[i] * w.x + vv[i + 1] * w.y + vv[i + 2] * w.z + vv[i + 3] * w.w;
    }
    red[t] = s;
    __syncthreads();
    if (isl == 0)
      baseOut[b * D_ + j] =
          red[t] + red[t + 64] + red[t + 128] + red[t + 192] + bout[j];
  }
}

// ---------------------------------------------------------------------------
// Merged kernel B: blocks [0,4096) = bcast_out (covers all B*L*D);
// blocks [4096,4128) = topk (one bh each, 4 redundant waves).
// ---------------------------------------------------------------------------
__global__ __launch_bounds__(256) void bcast_topk(
    const float* __restrict__ baseIn, float* __restrict__ out,
    const float* __restrict__ Mv, int* __restrict__ topIdx) {
  int t = threadIdx.x;
  if (blockIdx.x < 4096) {
    size_t i4 = (size_t)blockIdx.x * 256 + t;
    size_t i = i4 * 4;
    int b = (int)(i >> 21);
    int col = (int)(i & (D_ - 1));
    *(float4*)(out + i) = *(const float4*)(baseIn + b * D_ + col);
  } else {
    __shared__ float vals[L_];
    int lane = t & 63;
    int bh = blockIdx.x - 4096;
    for (int j = t; j < L_; j += 256) vals[j] = Mv[(size_t)bh * L_ + j];
    __syncthreads();
    for (int it = 0; it < U_; ++it) {
      float bv = -INFINITY;
      int bi = 0x7fffffff;
      for (int j = 0; j < 32; ++j) {
        int i = j * 64 + lane;
        float v = vals[i];
        if (v > bv) { bv = v; bi = i; }
      }
#pragma unroll
      for (int off = 32; off > 0; off >>= 1) {
        float ov = __shfl_xor(bv, off);
        int oi = __shfl_xor(bi, off);
        if (ov > bv || (ov == bv && oi < bi)) { bv = ov; bi = oi; }
      }
      if (t == 0) topIdx[bh * U_ + it] = bi;
      vals[bi] = -INFINITY;  // all waves compute identical bi
      __syncthreads();
    }
  }
}

// ---------------------------------------------------------------------------
// Fused attention + output correction (unchanged).
// ---------------------------------------------------------------------------
__global__ __launch_bounds__(256) void attn_corr(
    const float* __restrict__ Q, const float* __restrict__ Kt,
    const float* __restrict__ Vt, const int* __restrict__ topIdx,
    const float* __restrict__ vmeanM, const float* __restrict__ Wout,
    float* __restrict__ out) {
  int qc = blockIdx.x;  // 0..7 (5 queries each)
  int bh = blockIdx.y;  // 0..31
  int b = bh >> 4, h = bh & (H_ - 1);
  __shared__ float Qs[5][DH_];
  __shared__ float Sv[5][L_];
  __shared__ float part[4][5][DH_];
  __shared__ float inv[5];
  __shared__ float dv[5][DH_];
  __shared__ int lq[5];
  int t = threadIdx.x;
  int lane = t & 63, w = t >> 6;

  if (t < 80) {
    int q = t >> 4, c4 = t & 15;
    int ql = topIdx[bh * U_ + qc * 5 + q];
    *(float4*)&Qs[q][c4 * 4] =
        *(const float4*)&Q[((size_t)bh * L_ + ql) * DH_ + c4 * 4];
  }
  if (t < 5) lq[t] = topIdx[bh * U_ + qc * 5 + t];
  __syncthreads();

  const float* Kb = Kt + (size_t)bh * L_ * DH_;
  for (int kc = 0; kc < 8; ++kc) {
    int key = kc * 256 + t;
    const float* kr = Kb + (size_t)key * DH_;
    float acc[5];
#pragma unroll
    for (int q = 0; q < 5; ++q) acc[q] = 0.f;
#pragma unroll
    for (int i4 = 0; i4 < 16; ++i4) {
      float4 k4 = *(const float4*)(kr + i4 * 4);
#pragma unroll
      for (int q = 0; q < 5; ++q) {
        float4 qv = *(const float4*)&Qs[q][i4 * 4];
        acc[q] += k4.x * qv.x + k4.y * qv.y + k4.z * qv.z + k4.w * qv.w;
      }
    }
#pragma unroll
    for (int q = 0; q < 5; ++q) Sv[q][key] = acc[q] * SCALE_;
  }
  __syncthreads();

#pragma unroll
  for (int rep = 0; rep < 2; ++rep) {
    int r = (rep == 0) ? w : (w == 0 ? 4 : -1);
    if (r >= 0) {
      float mx = -INFINITY;
      for (int j = 0; j < 32; ++j) mx = fmaxf(mx, Sv[r][j * 64 + lane]);
#pragma unroll
      for (int off = 1; off < 64; off <<= 1)
        mx = fmaxf(mx, __shfl_xor(mx, off));
      float sm = 0.f;
      for (int j = 0; j < 32; ++j) {
        float e = __expf(Sv[r][j * 64 + lane] - mx);
        Sv[r][j * 64 + lane] = e;
        sm += e;
      }
#pragma unroll
      for (int off = 1; off < 64; off <<= 1) sm += __shfl_xor(sm, off);
      if (lane == 0) inv[r] = 1.0f / sm;
    }
  }
  __syncthreads();

  {
    const float* vb = Vt + ((size_t)bh * L_ + w * 512) * DH_ + lane;
    float acc[5];
#pragma unroll
    for (int q = 0; q < 5; ++q) acc[q] = 0.f;
    for (int k4 = 0; k4 < 128; ++k4) {
      float v0 = vb[(k4 * 4 + 0) * DH_];
      float v1 = vb[(k4 * 4 + 1) * DH_];
      float v2 = vb[(k4 * 4 + 2) * DH_];
      float v3 = vb[(k4 * 4 + 3) * DH_];
      int k = w * 512 + k4 * 4;
#pragma unroll
      for (int q = 0; q < 5; ++q) {
        float4 p4 = *(const float4*)&Sv[q][k];
        acc[q] += p4.x * v0 + p4.y * v1 + p4.z * v2 + p4.w * v3;
      }
    }
#pragma unroll
    for (int q = 0; q < 5; ++q) part[w][q][lane] = acc[q];
  }
  __syncthreads();

  for (int o = t; o < 5 * DH_; o += 256) {
    int q = o >> 6, dh = o & 63;
    float s = (part[0][q][dh] + part[1][q][dh]) +
              (part[2][q][dh] + part[3][q][dh]);
    dv[q][dh] = s * inv[q] - vmeanM[b * D_ + h * DH_ + dh];
  }
  __syncthreads();

  int sub = t & 3;
  int jbase = t >> 2;
#pragma unroll
  for (int jc = 0; jc < 16; ++jc) {
    int j = jc * 64 + jbase;
    const float* wr = Wout + (size_t)j * D_ + h * DH_ + sub * 16;
    float4 w0 = ((const float4*)wr)[0];
    float4 w1 = ((const float4*)wr)[1];
    float4 w2 = ((const float4*)wr)[2];
    float4 w3 = ((const float4*)wr)[3];
#pragma unroll
    for (int q = 0; q < 5; ++q) {
      const float* dq = &dv[q][sub * 16];
      float s = dq[0] * w0.x + dq[1] * w0.y + dq[2] * w0.z + dq[3] * w0.w +
                dq[4] * w1.x + dq[5] * w1.y + dq[6] * w1.z + dq[7] * w1.w +
                dq[8] * w2.x + dq[9] * w2.y + dq[10] * w2.z + dq[11] * w2.w +
                dq[12] * w3.x + dq[13] * w3.y + dq[14] * w3.z + dq[15] * w3.w;
      s += __shfl_xor(s, 1);
      s += __shfl_xor(s, 2);
      if (sub == 0)
        atomicAdd(out + ((size_t)b * L_ + lq[q]) * D_ + j, s);
    }
  }
}

// ---------------------------------------------------------------------------
extern "C" void kernel_launch(void* const* d_in, const int* in_sizes, int n_in,
                              void* d_out, int out_size, void* d_ws,
                              size_t ws_size, hipStream_t stream) {
  const float* x    = (const float*)d_in[0];
  const float* Wq   = (const float*)d_in[1];
  const float* bq   = (const float*)d_in[2];
  const float* Wkv  = (const float*)d_in[3];
  const float* bkv  = (const float*)d_in[4];
  const float* Wout = (const float*)d_in[5];
  const float* bout = (const float*)d_in[6];
  const int*   idx  = (const int*)d_in[7];
  float* out = (float*)d_out;

  float* ws = (float*)d_ws;
  const size_t NQ = (size_t)B_ * H_ * L_ * DH_;  // 4,194,304 floats
  float* Q  = ws;
  float* Kt = Q + NQ;
  float* Vt = Kt + NQ;
  // W/X split region (live only through the GEMM)
  unsigned short* Whi = (unsigned short*)(Vt + NQ);  // 6 MB
  unsigned short* Wlo = Whi + (size_t)3 * D_ * D_;   // 6 MB
  unsigned short* Xhi = Wlo + (size_t)3 * D_ * D_;   // 8 MB (optional)
  unsigned short* Xlo = Xhi + NQ;                    // 8 MB (optional)
  // phase-2 region (overlaps split region; used only after the GEMM)
  float* Mv     = Vt + NQ;                           // 256 KB
  float* vmeanM = Mv + (size_t)B_ * H_ * L_;         // 8 KB
  float* baseB  = vmeanM + B_ * D_;                  // 8 KB
  int*   topIdx = (int*)(baseB + B_ * D_);           // 5 KB
  // vmean accumulator lives in d_out[0:2048].
  float* vmAcc = out;

  const bool xsplit = ws_size >= ((size_t)76 << 20);
  const int nW = 3 * D_ * D_ / 4;
  const int nX = (int)(NQ / 4);

  if (xsplit) {
    split_all<<<dim3((nW + nX) / 256), dim3(256), 0, stream>>>(
        Wq, Wkv, x, Whi, Wlo, Xhi, Xlo, vmAcc, nW);
    gemm_qkv_256<<<dim3(3 * D_ / 192, B_ * L_ / 256), dim3(512), 0,
                   stream>>>(Xhi, Xlo, Whi, Wlo, bq, bkv, Q, Kt, Vt, vmAcc);
  } else {
    split_all<<<dim3(nW / 256), dim3(256), 0, stream>>>(Wq, Wkv, x, Whi, Wlo,
                                                        Xhi, Xlo, vmAcc, nW);
    gemm_qkv_fallback<<<dim3(3 * D_ / 128, B_ * L_ / 128), dim3(256), 0,
                        stream>>>(x, Whi, Wlo, bq, bkv, Q, Kt, Vt, vmAcc);
  }
  sample_base<<<dim3(4096 + B_ * 16), dim3(256), 0, stream>>>(
      Q, Kt, idx, Mv, vmAcc, Wout, bout, baseB, vmeanM);
  bcast_topk<<<dim3(4096 + B_ * H_), dim3(256), 0, stream>>>(baseB, out, Mv,
                                                             topIdx);
  attn_corr<<<dim3(8, 32), dim3(256), 0, stream>>>(Q, Kt, Vt, topIdx, vmeanM,
                                                   Wout, out);
}

// Round 16
// 228.667 us; speedup vs baseline: 1.8685x; 1.0033x over previous
//
#include <hip/hip_runtime.h>
#include <math.h>

// Problem constants (B=2, L=2048, D=1024, H=16, FACTOR=5)
#define B_ 2
#define L_ 2048
#define D_ 1024
#define H_ 16
#define DH_ 64
#define U_ 40
#define SCALE_ 0.125f

typedef __attribute__((ext_vector_type(8))) short short8v;            // 8 bf16
typedef __attribute__((ext_vector_type(4))) float f32x4;
typedef __attribute__((ext_vector_type(4))) unsigned short ushort4v;  // 8 B

static __device__ __forceinline__ unsigned short bf16_rne(float f) {
  unsigned int u = __float_as_uint(f);
  u += 0x7fff + ((u >> 16) & 1);
  return (unsigned short)(u >> 16);
}
static __device__ __forceinline__ float bf16_f32(unsigned short h) {
  return __uint_as_float(((unsigned int)h) << 16);
}

// Async global->LDS, 16 B per lane.
static __device__ __forceinline__ void gload16(const unsigned short* src,
                                               unsigned short* lds) {
  __builtin_amdgcn_global_load_lds(
      (const __attribute__((address_space(1))) void*)src,
      (__attribute__((address_space(3))) void*)lds, 16, 0, 0);
}

#define BARRIER                                  \
  do {                                           \
    asm volatile("" ::: "memory");               \
    __builtin_amdgcn_s_barrier();                \
    asm volatile("" ::: "memory");               \
  } while (0)
// Rule #18: force all LDS reads to retire and pin instruction movement.
#define LGKM0                                          \
  do {                                                 \
    asm volatile("s_waitcnt lgkmcnt(0)" ::: "memory"); \
    __builtin_amdgcn_sched_barrier(0);                 \
  } while (0)

// ---------------------------------------------------------------------------
// Pre-split f32 -> (hi,lo) bf16 for W=[Wq;Wkv] (quads [0,nW)) and X (rest).
// Block 0 additionally zeroes the vmean accumulator (in d_out[0:2048]).
// ---------------------------------------------------------------------------
__global__ __launch_bounds__(256) void split_all(
    const float* __restrict__ Wq, const float* __restrict__ Wkv,
    const float* __restrict__ X, unsigned short* __restrict__ Whi,
    unsigned short* __restrict__ Wlo, unsigned short* __restrict__ Xhi,
    unsigned short* __restrict__ Xlo, float* __restrict__ vmAcc, int nW) {
  if (blockIdx.x == 0) {
    for (int z = threadIdx.x; z < B_ * D_; z += 256) vmAcc[z] = 0.f;
  }
  int i = blockIdx.x * 256 + threadIdx.x;
  const int nq_q = (D_ * D_) / 4;
  float4 v;
  unsigned short *hi, *lo;
  int off;
  if (i < nW) {
    v = (i < nq_q) ? ((const float4*)Wq)[i] : ((const float4*)Wkv)[i - nq_q];
    hi = Whi; lo = Wlo; off = i;
  } else {
    off = i - nW;
    v = ((const float4*)X)[off];
    hi = Xhi; lo = Xlo;
  }
  float vv[4] = {v.x, v.y, v.z, v.w};
  ushort4v h, l;
#pragma unroll
  for (int e = 0; e < 4; ++e) {
    unsigned short hh = bf16_rne(vv[e]);
    h[e] = hh;
    l[e] = bf16_rne(vv[e] - bf16_f32(hh));
  }
  ((ushort4v*)hi)[off] = h;
  ((ushort4v*)lo)[off] = l;
}

// ---------------------------------------------------------------------------
// Pipelined split-bf16 MFMA GEMM: C = X @ W^T + bias. Tile 256x192, BK=32,
// 16 waves (4Mx4N, per-wave 64x48 = 4x3 frags) -> 4 waves/SIMD so LDS reads
// of one wave overlap MFMAs of the others (m114). 2 LDS buffers x 56 KB,
// prefetch distance 1, one barrier/step. Grid 16x16 = 1 block/CU.
// R16 fix: r=3 staging slot uses c = 48+(wave&7) so every slot forms a
// valid in-bounds address — the R15 clamp corrupted A rows 192-255.
// ---------------------------------------------------------------------------
__global__ __launch_bounds__(1024, 1) void gemm_qkv_16w(
    const unsigned short* __restrict__ Xhi,
    const unsigned short* __restrict__ Xlo,
    const unsigned short* __restrict__ Whi,
    const unsigned short* __restrict__ Wlo,
    const float* __restrict__ bq, const float* __restrict__ bkv,
    float* __restrict__ Qo, float* __restrict__ Ko, float* __restrict__ Vo,
    float* __restrict__ vmAcc) {
  // Per buffer (shorts): Ahi[256*32]@0, Alo@8192, Bhi[192*32]@16384,
  // Blo@22528; total 28672 shorts = 56 KB. 2 buffers = 112 KB.
  __shared__ unsigned short LDS[2][28672];
  const int tid = threadIdx.x;  // 0..1023
  const int lane = tid & 63;
  const int wave = tid >> 6;            // 0..15
  const int wm = wave >> 2, wn = wave & 3;
  const int row0 = blockIdx.y * 256;    // M = 4096 -> 16 blocks
  const int col0 = blockIdx.x * 192;    // N = 3072 -> 16 blocks

  f32x4 acc[4][3] = {};

  // Flat staging: 56 x 1KB calls per tile; wave w takes c = {w, w+16, w+32}
  // and (w<8) c = 48+w. c<16: Ahi rows c*16 ; c<32: Alo ; c<44: Bhi ; Blo.
  const unsigned short* gsrc[4];
  int gcv[4];
#pragma unroll
  for (int r = 0; r < 4; ++r) {
    int c = (r < 3) ? (wave + 16 * r) : (48 + (wave & 7));
    gcv[r] = c;
    const unsigned short* base;
    int rowin, isA;
    if (c < 16)      { base = Xhi; rowin = c * 16;        isA = 1; }
    else if (c < 32) { base = Xlo; rowin = (c - 16) * 16; isA = 1; }
    else if (c < 44) { base = Whi; rowin = (c - 32) * 16; isA = 0; }
    else             { base = Wlo; rowin = (c - 44) * 16; isA = 0; }
    rowin += (lane >> 2);
    int grow = (isA ? row0 : col0) + rowin;
    int seg = (lane & 3) ^ ((rowin >> 1) & 3);
    gsrc[r] = base + (size_t)grow * D_ + seg * 8;
  }

  const int fr_r = lane & 15;
  const int hs = lane >> 4;

#define STG_ALL(k0s, Ls)                                        \
  do {                                                          \
    gload16(gsrc[0] + (k0s), (Ls) + gcv[0] * 512);              \
    gload16(gsrc[1] + (k0s), (Ls) + gcv[1] * 512);              \
    gload16(gsrc[2] + (k0s), (Ls) + gcv[2] * 512);              \
    if (wave < 8) gload16(gsrc[3] + (k0s), (Ls) + gcv[3] * 512);\
  } while (0)

  // Prologue: stage tile 0 into buffer 0.
  STG_ALL(0, &LDS[0][0]);
  asm volatile("s_waitcnt vmcnt(0)" ::: "memory");
  BARRIER;

  for (int ks = 0; ks < 32; ++ks) {
    unsigned short* Lc = &LDS[ks & 1][0];
    unsigned short* Ls = &LDS[(ks + 1) & 1][0];

    // Stage tile ks+1 into the other buffer (its readers retired at the
    // LGKM0+barrier of step ks-1).
    if (ks < 31) STG_ALL((ks + 1) * 32, Ls);

    // Fragment reads, all upfront (ILP; compiler interleaves via lgkmcnt).
    short8v a_h[4], a_l[4], b_h[3], b_l[3];
#pragma unroll
    for (int ni = 0; ni < 3; ++ni) {
      int rc = wn * 48 + ni * 16 + fr_r;
      int off = rc * 32 + ((hs ^ ((rc >> 1) & 3)) << 3);
      b_h[ni] = *(const short8v*)&Lc[16384 + off];
      b_l[ni] = *(const short8v*)&Lc[22528 + off];
    }
#pragma unroll
    for (int mi = 0; mi < 4; ++mi) {
      int rr = wm * 64 + mi * 16 + fr_r;
      int off = rr * 32 + ((hs ^ ((rr >> 1) & 3)) << 3);
      a_h[mi] = *(const short8v*)&Lc[off];
      a_l[mi] = *(const short8v*)&Lc[8192 + off];
    }

#pragma unroll
    for (int mi = 0; mi < 4; ++mi)
#pragma unroll
      for (int ni = 0; ni < 3; ++ni) {
        acc[mi][ni] = __builtin_amdgcn_mfma_f32_16x16x32_bf16(
            a_h[mi], b_h[ni], acc[mi][ni], 0, 0, 0);
        acc[mi][ni] = __builtin_amdgcn_mfma_f32_16x16x32_bf16(
            a_h[mi], b_l[ni], acc[mi][ni], 0, 0, 0);
        acc[mi][ni] = __builtin_amdgcn_mfma_f32_16x16x32_bf16(
            a_l[mi], b_h[ni], acc[mi][ni], 0, 0, 0);
      }

    // All LDS reads of this step must retire before any wave can cross the
    // barrier and overwrite buffer ks&1 at step ks+1 (rule #18).
    LGKM0;
    // Staged loads for tile ks+1 must have landed (they had the whole step).
    asm volatile("s_waitcnt vmcnt(0)" ::: "memory");
    BARRIER;
  }

  // Epilogue: C/D layout col=lane&15, row=(lane>>4)*4+reg.
#pragma unroll
  for (int ni = 0; ni < 3; ++ni) {
    int c = col0 + wn * 48 + ni * 16 + (lane & 15);
    int which = c >> 10;
    int jj = c & (D_ - 1);
    int h = jj >> 6, dh = jj & 63;
    float bias = (c < D_) ? bq[c] : bkv[c - D_];
    float* dst = (which == 0) ? Qo : ((which == 1) ? Ko : Vo);
#pragma unroll
    for (int mi = 0; mi < 4; ++mi) {
#pragma unroll
      for (int reg = 0; reg < 4; ++reg) {
        int r = row0 + wm * 64 + mi * 16 + ((lane >> 4) << 2) + reg;
        int b = r >> 11, l = r & (L_ - 1);
        dst[(((size_t)b * H_ + h) * L_ + l) * DH_ + dh] =
            acc[mi][ni][reg] + bias;
      }
    }
    if (which == 2) {  // vmean partial: sum over this wave's 64 rows
      float s = 0.f;
#pragma unroll
      for (int mi = 0; mi < 4; ++mi)
#pragma unroll
        for (int reg = 0; reg < 4; ++reg) s += acc[mi][ni][reg];
      s += __shfl_xor(s, 16);
      s += __shfl_xor(s, 32);
      if ((lane >> 4) == 0)
        atomicAdd(&vmAcc[(row0 >> 11) * D_ + jj], s + 64.0f * bias);
    }
  }
#undef STG_ALL
}

// ---------------------------------------------------------------------------
// Fallback GEMM (R10 structure) — used only when ws can't hold Xhi/Xlo.
// ---------------------------------------------------------------------------
__global__ __launch_bounds__(256) void gemm_qkv_fallback(
    const float* __restrict__ X,
    const unsigned short* __restrict__ Whi,
    const unsigned short* __restrict__ Wlo,
    const float* __restrict__ bq, const float* __restrict__ bkv,
    float* __restrict__ Qo, float* __restrict__ Ko, float* __restrict__ Vo,
    float* __restrict__ vmAcc) {
  __shared__ unsigned short Ah[128 * 32];
  __shared__ unsigned short Al[128 * 32];
  __shared__ unsigned short Bh[128 * 32];
  __shared__ unsigned short Bl[128 * 32];
  const int tid = threadIdx.x;
  const int lane = tid & 63;
  const int wave = tid >> 6;
  const int wm = wave >> 1, wn = wave & 1;
  const int row0 = blockIdx.y * 128;
  const int col0 = blockIdx.x * 128;

  f32x4 acc[4][4] = {};

  const int grow = lane >> 2;
  const int gg = lane & 3;

  for (int k0 = 0; k0 < D_; k0 += 32) {
#pragma unroll
    for (int j = 0; j < 2; ++j) {
      int c = wave + 4 * j;
      int row = c * 16 + grow;
      int gsrc = (gg ^ ((row >> 1) & 3)) << 3;
      size_t soffB = (size_t)(col0 + row) * D_ + k0 + gsrc;
      gload16(Whi + soffB, Bh + c * 512);
      gload16(Wlo + soffB, Bl + c * 512);
    }
#pragma unroll
    for (int rep = 0; rep < 2; ++rep) {
      int task = tid + rep * 256;
      int row = task >> 2;
      int gt = task & 3;
      const float* s = X + (size_t)(row0 + row) * D_ + k0 + gt * 8;
      float4 a0 = *(const float4*)s;
      float4 a1 = *(const float4*)(s + 4);
      float av[8] = {a0.x, a0.y, a0.z, a0.w, a1.x, a1.y, a1.z, a1.w};
      short8v hseg, lseg;
#pragma unroll
      for (int e = 0; e < 8; ++e) {
        unsigned short hh = bf16_rne(av[e]);
        hseg[e] = (short)hh;
        lseg[e] = (short)bf16_rne(av[e] - bf16_f32(hh));
      }
      int dst = row * 32 + ((gt ^ ((row >> 1) & 3)) << 3);
      *(short8v*)&Ah[dst] = hseg;
      *(short8v*)&Al[dst] = lseg;
    }
    __syncthreads();

    short8v a_h[4], a_l[4], b_h[4], b_l[4];
    const int hs = lane >> 4;
#pragma unroll
    for (int mi = 0; mi < 4; ++mi) {
      int rr = wm * 64 + mi * 16 + (lane & 15);
      int off = rr * 32 + ((hs ^ ((rr >> 1) & 3)) << 3);
      a_h[mi] = *(const short8v*)&Ah[off];
      a_l[mi] = *(const short8v*)&Al[off];
    }
#pragma unroll
    for (int ni = 0; ni < 4; ++ni) {
      int rc = wn * 64 + ni * 16 + (lane & 15);
      int off = rc * 32 + ((hs ^ ((rc >> 1) & 3)) << 3);
      b_h[ni] = *(const short8v*)&Bh[off];
      b_l[ni] = *(const short8v*)&Bl[off];
    }
#pragma unroll
    for (int mi = 0; mi < 4; ++mi)
#pragma unroll
      for (int ni = 0; ni < 4; ++ni) {
        acc[mi][ni] = __builtin_amdgcn_mfma_f32_16x16x32_bf16(
            a_h[mi], b_h[ni], acc[mi][ni], 0, 0, 0);
        acc[mi][ni] = __builtin_amdgcn_mfma_f32_16x16x32_bf16(
            a_h[mi], b_l[ni], acc[mi][ni], 0, 0, 0);
        acc[mi][ni] = __builtin_amdgcn_mfma_f32_16x16x32_bf16(
            a_l[mi], b_h[ni], acc[mi][ni], 0, 0, 0);
      }
    __syncthreads();
  }

#pragma unroll
  for (int ni = 0; ni < 4; ++ni) {
    int c = col0 + wn * 64 + ni * 16 + (lane & 15);
    int which = c >> 10;
    int jj = c & (D_ - 1);
    int h = jj >> 6, dh = jj & 63;
    float bias = (c < D_) ? bq[c] : bkv[c - D_];
    float* dst = (which == 0) ? Qo : ((which == 1) ? Ko : Vo);
#pragma unroll
    for (int mi = 0; mi < 4; ++mi) {
#pragma unroll
      for (int reg = 0; reg < 4; ++reg) {
        int r = row0 + wm * 64 + mi * 16 + ((lane >> 4) << 2) + reg;
        int b = r >> 11, l = r & (L_ - 1);
        dst[(((size_t)b * H_ + h) * L_ + l) * DH_ + dh] =
            acc[mi][ni][reg] + bias;
      }
    }
    if (which == 2) {
      float s = 0.f;
#pragma unroll
      for (int mi = 0; mi < 4; ++mi)
#pragma unroll
        for (int reg = 0; reg < 4; ++reg) s += acc[mi][ni][reg];
      s += __shfl_xor(s, 16);
      s += __shfl_xor(s, 32);
      if ((lane >> 4) == 0)
        atomicAdd(&vmAcc[(row0 >> 11) * D_ + jj], s + 64.0f * bias);
    }
  }
}

// ---------------------------------------------------------------------------
// Merged kernel A: blocks [0,4096) = sample_m; blocks [4096,4128) = base.
// ---------------------------------------------------------------------------
__global__ __launch_bounds__(256) void sample_base(
    const float* __restrict__ Q, const float* __restrict__ Kt,
    const int* __restrict__ idx, float* __restrict__ Mv,
    const float* __restrict__ vmAcc, const float* __restrict__ Wout,
    const float* __restrict__ bout, float* __restrict__ baseOut,
    float* __restrict__ vmeanM) {
  int t = threadIdx.x;
  if (blockIdx.x < 4096) {
    // ---- sample_m
    int w = t >> 6, lane = t & 63;
    int subl = lane >> 4, d16 = lane & 15;
    int gl = blockIdx.x * 16 + w * 4 + subl;  // bh*L + l
    int bh = gl >> 11, l = gl & (L_ - 1);
    const float4* Kb4 = (const float4*)(Kt + (size_t)bh * L_ * DH_);
    float4 q4 = ((const float4*)(Q + (size_t)gl * DH_))[d16];
    const int* irow = idx + l * U_;
    float mx = -INFINITY, sm = 0.f;
#pragma unroll 8
    for (int u = 0; u < U_; ++u) {
      int kl = irow[u];
      float4 k4 = Kb4[kl * 16 + d16];
      float p = q4.x * k4.x + q4.y * k4.y + q4.z * k4.z + q4.w * k4.w;
      p += __shfl_xor(p, 1);
      p += __shfl_xor(p, 2);
      p += __shfl_xor(p, 4);
      p += __shfl_xor(p, 8);
      mx = fmaxf(mx, p);
      sm += p;
    }
    if (d16 == 0) Mv[gl] = mx - sm * (1.0f / U_);
  } else {
    // ---- base
    int bid = blockIdx.x - 4096;
    int b = bid >> 4, jc = bid & 15;
    int j = jc * 64 + (t & 63);
    int isl = t >> 6;
    __shared__ float vm[D_];
    __shared__ float red[256];
    for (int i = t; i < D_; i += 256) vm[i] = vmAcc[b * D_ + i] * (1.0f / L_);
    __syncthreads();
    if (jc == 0)
      for (int i = t; i < D_; i += 256) vmeanM[b * D_ + i] = vm[i];
    float s = 0.f;
    const float* wr = Wout + (size_t)j * D_ + isl * 256;
    const float* vv = vm + isl * 256;
    for (int i = 0; i < 256; i += 4) {
      float4 w = *(const float4*)(wr + i);
      s += vv[i] * w.x + vv[i + 1] * w.y + vv[i + 2] * w.z + vv[i + 3] * w.w;
    }
    red[t] = s;
    __syncthreads();
    if (isl == 0)
      baseOut[b * D_ + j] =
          red[t] + red[t + 64] + red[t + 128] + red[t + 192] + bout[j];
  }
}

// ---------------------------------------------------------------------------
// Merged kernel B: blocks [0,4096) = bcast_out (covers all B*L*D);
// blocks [4096,4128) = topk (one bh each, 4 redundant waves).
// ---------------------------------------------------------------------------
__global__ __launch_bounds__(256) void bcast_topk(
    const float* __restrict__ baseIn, float* __restrict__ out,
    const float* __restrict__ Mv, int* __restrict__ topIdx) {
  int t = threadIdx.x;
  if (blockIdx.x < 4096) {
    size_t i4 = (size_t)blockIdx.x * 256 + t;
    size_t i = i4 * 4;
    int b = (int)(i >> 21);
    int col = (int)(i & (D_ - 1));
    *(float4*)(out + i) = *(const float4*)(baseIn + b * D_ + col);
  } else {
    __shared__ float vals[L_];
    int lane = t & 63;
    int bh = blockIdx.x - 4096;
    for (int j = t; j < L_; j += 256) vals[j] = Mv[(size_t)bh * L_ + j];
    __syncthreads();
    for (int it = 0; it < U_; ++it) {
      float bv = -INFINITY;
      int bi = 0x7fffffff;
      for (int j = 0; j < 32; ++j) {
        int i = j * 64 + lane;
        float v = vals[i];
        if (v > bv) { bv = v; bi = i; }
      }
#pragma unroll
      for (int off = 32; off > 0; off >>= 1) {
        float ov = __shfl_xor(bv, off);
        int oi = __shfl_xor(bi, off);
        if (ov > bv || (ov == bv && oi < bi)) { bv = ov; bi = oi; }
      }
      if (t == 0) topIdx[bh * U_ + it] = bi;
      vals[bi] = -INFINITY;  // all waves compute identical bi
      __syncthreads();
    }
  }
}

// ---------------------------------------------------------------------------
// Fused attention + output correction (unchanged).
// ---------------------------------------------------------------------------
__global__ __launch_bounds__(256) void attn_corr(
    const float* __restrict__ Q, const float* __restrict__ Kt,
    const float* __restrict__ Vt, const int* __restrict__ topIdx,
    const float* __restrict__ vmeanM, const float* __restrict__ Wout,
    float* __restrict__ out) {
  int qc = blockIdx.x;  // 0..7 (5 queries each)
  int bh = blockIdx.y;  // 0..31
  int b = bh >> 4, h = bh & (H_ - 1);
  __shared__ float Qs[5][DH_];
  __shared__ float Sv[5][L_];
  __shared__ float part[4][5][DH_];
  __shared__ float inv[5];
  __shared__ float dv[5][DH_];
  __shared__ int lq[5];
  int t = threadIdx.x;
  int lane = t & 63, w = t >> 6;

  if (t < 80) {
    int q = t >> 4, c4 = t & 15;
    int ql = topIdx[bh * U_ + qc * 5 + q];
    *(float4*)&Qs[q][c4 * 4] =
        *(const float4*)&Q[((size_t)bh * L_ + ql) * DH_ + c4 * 4];
  }
  if (t < 5) lq[t] = topIdx[bh * U_ + qc * 5 + t];
  __syncthreads();

  const float* Kb = Kt + (size_t)bh * L_ * DH_;
  for (int kc = 0; kc < 8; ++kc) {
    int key = kc * 256 + t;
    const float* kr = Kb + (size_t)key * DH_;
    float acc[5];
#pragma unroll
    for (int q = 0; q < 5; ++q) acc[q] = 0.f;
#pragma unroll
    for (int i4 = 0; i4 < 16; ++i4) {
      float4 k4 = *(const float4*)(kr + i4 * 4);
#pragma unroll
      for (int q = 0; q < 5; ++q) {
        float4 qv = *(const float4*)&Qs[q][i4 * 4];
        acc[q] += k4.x * qv.x + k4.y * qv.y + k4.z * qv.z + k4.w * qv.w;
      }
    }
#pragma unroll
    for (int q = 0; q < 5; ++q) Sv[q][key] = acc[q] * SCALE_;
  }
  __syncthreads();

#pragma unroll
  for (int rep = 0; rep < 2; ++rep) {
    int r = (rep == 0) ? w : (w == 0 ? 4 : -1);
    if (r >= 0) {
      float mx = -INFINITY;
      for (int j = 0; j < 32; ++j) mx = fmaxf(mx, Sv[r][j * 64 + lane]);
#pragma unroll
      for (int off = 1; off < 64; off <<= 1)
        mx = fmaxf(mx, __shfl_xor(mx, off));
      float sm = 0.f;
      for (int j = 0; j < 32; ++j) {
        float e = __expf(Sv[r][j * 64 + lane] - mx);
        Sv[r][j * 64 + lane] = e;
        sm += e;
      }
#pragma unroll
      for (int off = 1; off < 64; off <<= 1) sm += __shfl_xor(sm, off);
      if (lane == 0) inv[r] = 1.0f / sm;
    }
  }
  __syncthreads();

  {
    const float* vb = Vt + ((size_t)bh * L_ + w * 512) * DH_ + lane;
    float acc[5];
#pragma unroll
    for (int q = 0; q < 5; ++q) acc[q] = 0.f;
    for (int k4 = 0; k4 < 128; ++k4) {
      float v0 = vb[(k4 * 4 + 0) * DH_];
      float v1 = vb[(k4 * 4 + 1) * DH_];
      float v2 = vb[(k4 * 4 + 2) * DH_];
      float v3 = vb[(k4 * 4 + 3) * DH_];
      int k = w * 512 + k4 * 4;
#pragma unroll
      for (int q = 0; q < 5; ++q) {
        float4 p4 = *(const float4*)&Sv[q][k];
        acc[q] += p4.x * v0 + p4.y * v1 + p4.z * v2 + p4.w * v3;
      }
    }
#pragma unroll
    for (int q = 0; q < 5; ++q) part[w][q][lane] = acc[q];
  }
  __syncthreads();

  for (int o = t; o < 5 * DH_; o += 256) {
    int q = o >> 6, dh = o & 63;
    float s = (part[0][q][dh] + part[1][q][dh]) +
              (part[2][q][dh] + part[3][q][dh]);
    dv[q][dh] = s * inv[q] - vmeanM[b * D_ + h * DH_ + dh];
  }
  __syncthreads();

  int sub = t & 3;
  int jbase = t >> 2;
#pragma unroll
  for (int jc = 0; jc < 16; ++jc) {
    int j = jc * 64 + jbase;
    const float* wr = Wout + (size_t)j * D_ + h * DH_ + sub * 16;
    float4 w0 = ((const float4*)wr)[0];
    float4 w1 = ((const float4*)wr)[1];
    float4 w2 = ((const float4*)wr)[2];
    float4 w3 = ((const float4*)wr)[3];
#pragma unroll
    for (int q = 0; q < 5; ++q) {
      const float* dq = &dv[q][sub * 16];
      float s = dq[0] * w0.x + dq[1] * w0.y + dq[2] * w0.z + dq[3] * w0.w +
                dq[4] * w1.x + dq[5] * w1.y + dq[6] * w1.z + dq[7] * w1.w +
                dq[8] * w2.x + dq[9] * w2.y + dq[10] * w2.z + dq[11] * w2.w +
                dq[12] * w3.x + dq[13] * w3.y + dq[14] * w3.z + dq[15] * w3.w;
      s += __shfl_xor(s, 1);
      s += __shfl_xor(s, 2);
      if (sub == 0)
        atomicAdd(out + ((size_t)b * L_ + lq[q]) * D_ + j, s);
    }
  }
}

// ---------------------------------------------------------------------------
extern "C" void kernel_launch(void* const* d_in, const int* in_sizes, int n_in,
                              void* d_out, int out_size, void* d_ws,
                              size_t ws_size, hipStream_t stream) {
  const float* x    = (const float*)d_in[0];
  const float* Wq   = (const float*)d_in[1];
  const float* bq   = (const float*)d_in[2];
  const float* Wkv  = (const float*)d_in[3];
  const float* bkv  = (const float*)d_in[4];
  const float* Wout = (const float*)d_in[5];
  const float* bout = (const float*)d_in[6];
  const int*   idx  = (const int*)d_in[7];
  float* out = (float*)d_out;

  float* ws = (float*)d_ws;
  const size_t NQ = (size_t)B_ * H_ * L_ * DH_;  // 4,194,304 floats
  float* Q  = ws;
  float* Kt = Q + NQ;
  float* Vt = Kt + NQ;
  // W/X split region (live only through the GEMM)
  unsigned short* Whi = (unsigned short*)(Vt + NQ);  // 6 MB
  unsigned short* Wlo = Whi + (size_t)3 * D_ * D_;   // 6 MB
  unsigned short* Xhi = Wlo + (size_t)3 * D_ * D_;   // 8 MB (optional)
  unsigned short* Xlo = Xhi + NQ;                    // 8 MB (optional)
  // phase-2 region (overlaps split region; used only after the GEMM)
  float* Mv     = Vt + NQ;                           // 256 KB
  float* vmeanM = Mv + (size_t)B_ * H_ * L_;         // 8 KB
  float* baseB  = vmeanM + B_ * D_;                  // 8 KB
  int*   topIdx = (int*)(baseB + B_ * D_);           // 5 KB
  // vmean accumulator lives in d_out[0:2048].
  float* vmAcc = out;

  const bool xsplit = ws_size >= ((size_t)76 << 20);
  const int nW = 3 * D_ * D_ / 4;
  const int nX = (int)(NQ / 4);

  if (xsplit) {
    split_all<<<dim3((nW + nX) / 256), dim3(256), 0, stream>>>(
        Wq, Wkv, x, Whi, Wlo, Xhi, Xlo, vmAcc, nW);
    gemm_qkv_16w<<<dim3(3 * D_ / 192, B_ * L_ / 256), dim3(1024), 0,
                   stream>>>(Xhi, Xlo, Whi, Wlo, bq, bkv, Q, Kt, Vt, vmAcc);
  } else {
    split_all<<<dim3(nW / 256), dim3(256), 0, stream>>>(Wq, Wkv, x, Whi, Wlo,
                                                        Xhi, Xlo, vmAcc, nW);
    gemm_qkv_fallback<<<dim3(3 * D_ / 128, B_ * L_ / 128), dim3(256), 0,
                        stream>>>(x, Whi, Wlo, bq, bkv, Q, Kt, Vt, vmAcc);
  }
  sample_base<<<dim3(4096 + B_ * 16), dim3(256), 0, stream>>>(
      Q, Kt, idx, Mv, vmAcc, Wout, bout, baseB, vmeanM);
  bcast_topk<<<dim3(4096 + B_ * H_), dim3(256), 0, stream>>>(baseB, out, Mv,
                                                             topIdx);
  attn_corr<<<dim3(8, 32), dim3(256), 0, stream>>>(Q, Kt, Vt, topIdx, vmeanM,
                                                   Wout, out);
}

// Round 18
// 213.722 us; speedup vs baseline: 1.9992x; 1.0699x over previous
//
#include <hip/hip_runtime.h>
#include <math.h>

// Problem constants (B=2, L=2048, D=1024, H=16, FACTOR=5)
#define B_ 2
#define L_ 2048
#define D_ 1024
#define H_ 16
#define DH_ 64
#define U_ 40
#define SCALE_ 0.125f

typedef __attribute__((ext_vector_type(8))) short short8v;            // 8 bf16
typedef __attribute__((ext_vector_type(4))) float f32x4;
typedef __attribute__((ext_vector_type(4))) unsigned short ushort4v;  // 8 B

static __device__ __forceinline__ unsigned short bf16_rne(float f) {
  unsigned int u = __float_as_uint(f);
  u += 0x7fff + ((u >> 16) & 1);
  return (unsigned short)(u >> 16);
}
static __device__ __forceinline__ float bf16_f32(unsigned short h) {
  return __uint_as_float(((unsigned int)h) << 16);
}

// Async global->LDS, 16 B per lane.
static __device__ __forceinline__ void gload16(const unsigned short* src,
                                               unsigned short* lds) {
  __builtin_amdgcn_global_load_lds(
      (const __attribute__((address_space(1))) void*)src,
      (__attribute__((address_space(3))) void*)lds, 16, 0, 0);
}

#define BARRIER                                  \
  do {                                           \
    asm volatile("" ::: "memory");               \
    __builtin_amdgcn_s_barrier();                \
    asm volatile("" ::: "memory");               \
  } while (0)
// Rule #18: force all LDS reads to retire and pin instruction movement.
#define LGKM0                                          \
  do {                                                 \
    asm volatile("s_waitcnt lgkmcnt(0)" ::: "memory"); \
    __builtin_amdgcn_sched_barrier(0);                 \
  } while (0)

// ---------------------------------------------------------------------------
// Pre-split f32 -> (hi,lo) bf16 for W=[Wq;Wkv] (quads [0,nW)) and X (rest).
// Block 0 additionally zeroes the vmean accumulator (in d_out[0:2048]).
// ---------------------------------------------------------------------------
__global__ __launch_bounds__(256) void split_all(
    const float* __restrict__ Wq, const float* __restrict__ Wkv,
    const float* __restrict__ X, unsigned short* __restrict__ Whi,
    unsigned short* __restrict__ Wlo, unsigned short* __restrict__ Xhi,
    unsigned short* __restrict__ Xlo, float* __restrict__ vmAcc, int nW) {
  if (blockIdx.x == 0) {
    for (int z = threadIdx.x; z < B_ * D_; z += 256) vmAcc[z] = 0.f;
  }
  int i = blockIdx.x * 256 + threadIdx.x;
  const int nq_q = (D_ * D_) / 4;
  float4 v;
  unsigned short *hi, *lo;
  int off;
  if (i < nW) {
    v = (i < nq_q) ? ((const float4*)Wq)[i] : ((const float4*)Wkv)[i - nq_q];
    hi = Whi; lo = Wlo; off = i;
  } else {
    off = i - nW;
    v = ((const float4*)X)[off];
    hi = Xhi; lo = Xlo;
  }
  float vv[4] = {v.x, v.y, v.z, v.w};
  ushort4v h, l;
#pragma unroll
  for (int e = 0; e < 4; ++e) {
    unsigned short hh = bf16_rne(vv[e]);
    h[e] = hh;
    l[e] = bf16_rne(vv[e] - bf16_f32(hh));
  }
  ((ushort4v*)hi)[off] = h;
  ((ushort4v*)lo)[off] = l;
}

// ---------------------------------------------------------------------------
// Pipelined split-bf16 MFMA GEMM (R16 version, unchanged): 256x192 tile,
// 16 waves, 2 LDS buffers, 1 barrier/step.
// ---------------------------------------------------------------------------
__global__ __launch_bounds__(1024, 1) void gemm_qkv_16w(
    const unsigned short* __restrict__ Xhi,
    const unsigned short* __restrict__ Xlo,
    const unsigned short* __restrict__ Whi,
    const unsigned short* __restrict__ Wlo,
    const float* __restrict__ bq, const float* __restrict__ bkv,
    float* __restrict__ Qo, float* __restrict__ Ko, float* __restrict__ Vo,
    float* __restrict__ vmAcc) {
  __shared__ unsigned short LDS[2][28672];
  const int tid = threadIdx.x;
  const int lane = tid & 63;
  const int wave = tid >> 6;
  const int wm = wave >> 2, wn = wave & 3;
  const int row0 = blockIdx.y * 256;
  const int col0 = blockIdx.x * 192;

  f32x4 acc[4][3] = {};

  const unsigned short* gsrc[4];
  int gcv[4];
#pragma unroll
  for (int r = 0; r < 4; ++r) {
    int c = (r < 3) ? (wave + 16 * r) : (48 + (wave & 7));
    gcv[r] = c;
    const unsigned short* base;
    int rowin, isA;
    if (c < 16)      { base = Xhi; rowin = c * 16;        isA = 1; }
    else if (c < 32) { base = Xlo; rowin = (c - 16) * 16; isA = 1; }
    else if (c < 44) { base = Whi; rowin = (c - 32) * 16; isA = 0; }
    else             { base = Wlo; rowin = (c - 44) * 16; isA = 0; }
    rowin += (lane >> 2);
    int grow = (isA ? row0 : col0) + rowin;
    int seg = (lane & 3) ^ ((rowin >> 1) & 3);
    gsrc[r] = base + (size_t)grow * D_ + seg * 8;
  }

  const int fr_r = lane & 15;
  const int hs = lane >> 4;

#define STG_ALL(k0s, Ls)                                        \
  do {                                                          \
    gload16(gsrc[0] + (k0s), (Ls) + gcv[0] * 512);              \
    gload16(gsrc[1] + (k0s), (Ls) + gcv[1] * 512);              \
    gload16(gsrc[2] + (k0s), (Ls) + gcv[2] * 512);              \
    if (wave < 8) gload16(gsrc[3] + (k0s), (Ls) + gcv[3] * 512);\
  } while (0)

  STG_ALL(0, &LDS[0][0]);
  asm volatile("s_waitcnt vmcnt(0)" ::: "memory");
  BARRIER;

  for (int ks = 0; ks < 32; ++ks) {
    unsigned short* Lc = &LDS[ks & 1][0];
    unsigned short* Ls = &LDS[(ks + 1) & 1][0];
    if (ks < 31) STG_ALL((ks + 1) * 32, Ls);

    short8v a_h[4], a_l[4], b_h[3], b_l[3];
#pragma unroll
    for (int ni = 0; ni < 3; ++ni) {
      int rc = wn * 48 + ni * 16 + fr_r;
      int off = rc * 32 + ((hs ^ ((rc >> 1) & 3)) << 3);
      b_h[ni] = *(const short8v*)&Lc[16384 + off];
      b_l[ni] = *(const short8v*)&Lc[22528 + off];
    }
#pragma unroll
    for (int mi = 0; mi < 4; ++mi) {
      int rr = wm * 64 + mi * 16 + fr_r;
      int off = rr * 32 + ((hs ^ ((rr >> 1) & 3)) << 3);
      a_h[mi] = *(const short8v*)&Lc[off];
      a_l[mi] = *(const short8v*)&Lc[8192 + off];
    }

#pragma unroll
    for (int mi = 0; mi < 4; ++mi)
#pragma unroll
      for (int ni = 0; ni < 3; ++ni) {
        acc[mi][ni] = __builtin_amdgcn_mfma_f32_16x16x32_bf16(
            a_h[mi], b_h[ni], acc[mi][ni], 0, 0, 0);
        acc[mi][ni] = __builtin_amdgcn_mfma_f32_16x16x32_bf16(
            a_h[mi], b_l[ni], acc[mi][ni], 0, 0, 0);
        acc[mi][ni] = __builtin_amdgcn_mfma_f32_16x16x32_bf16(
            a_l[mi], b_h[ni], acc[mi][ni], 0, 0, 0);
      }

    LGKM0;
    asm volatile("s_waitcnt vmcnt(0)" ::: "memory");
    BARRIER;
  }

#pragma unroll
  for (int ni = 0; ni < 3; ++ni) {
    int c = col0 + wn * 48 + ni * 16 + (lane & 15);
    int which = c >> 10;
    int jj = c & (D_ - 1);
    int h = jj >> 6, dh = jj & 63;
    float bias = (c < D_) ? bq[c] : bkv[c - D_];
    float* dst = (which == 0) ? Qo : ((which == 1) ? Ko : Vo);
#pragma unroll
    for (int mi = 0; mi < 4; ++mi) {
#pragma unroll
      for (int reg = 0; reg < 4; ++reg) {
        int r = row0 + wm * 64 + mi * 16 + ((lane >> 4) << 2) + reg;
        int b = r >> 11, l = r & (L_ - 1);
        dst[(((size_t)b * H_ + h) * L_ + l) * DH_ + dh] =
            acc[mi][ni][reg] + bias;
      }
    }
    if (which == 2) {
      float s = 0.f;
#pragma unroll
      for (int mi = 0; mi < 4; ++mi)
#pragma unroll
        for (int reg = 0; reg < 4; ++reg) s += acc[mi][ni][reg];
      s += __shfl_xor(s, 16);
      s += __shfl_xor(s, 32);
      if ((lane >> 4) == 0)
        atomicAdd(&vmAcc[(row0 >> 11) * D_ + jj], s + 64.0f * bias);
    }
  }
#undef STG_ALL
}

// ---------------------------------------------------------------------------
// Fallback GEMM (R10 structure) — used only when ws can't hold Xhi/Xlo.
// ---------------------------------------------------------------------------
__global__ __launch_bounds__(256) void gemm_qkv_fallback(
    const float* __restrict__ X,
    const unsigned short* __restrict__ Whi,
    const unsigned short* __restrict__ Wlo,
    const float* __restrict__ bq, const float* __restrict__ bkv,
    float* __restrict__ Qo, float* __restrict__ Ko, float* __restrict__ Vo,
    float* __restrict__ vmAcc) {
  __shared__ unsigned short Ah[128 * 32];
  __shared__ unsigned short Al[128 * 32];
  __shared__ unsigned short Bh[128 * 32];
  __shared__ unsigned short Bl[128 * 32];
  const int tid = threadIdx.x;
  const int lane = tid & 63;
  const int wave = tid >> 6;
  const int wm = wave >> 1, wn = wave & 1;
  const int row0 = blockIdx.y * 128;
  const int col0 = blockIdx.x * 128;

  f32x4 acc[4][4] = {};

  const int grow = lane >> 2;
  const int gg = lane & 3;

  for (int k0 = 0; k0 < D_; k0 += 32) {
#pragma unroll
    for (int j = 0; j < 2; ++j) {
      int c = wave + 4 * j;
      int row = c * 16 + grow;
      int gsrc = (gg ^ ((row >> 1) & 3)) << 3;
      size_t soffB = (size_t)(col0 + row) * D_ + k0 + gsrc;
      gload16(Whi + soffB, Bh + c * 512);
      gload16(Wlo + soffB, Bl + c * 512);
    }
#pragma unroll
    for (int rep = 0; rep < 2; ++rep) {
      int task = tid + rep * 256;
      int row = task >> 2;
      int gt = task & 3;
      const float* s = X + (size_t)(row0 + row) * D_ + k0 + gt * 8;
      float4 a0 = *(const float4*)s;
      float4 a1 = *(const float4*)(s + 4);
      float av[8] = {a0.x, a0.y, a0.z, a0.w, a1.x, a1.y, a1.z, a1.w};
      short8v hseg, lseg;
#pragma unroll
      for (int e = 0; e < 8; ++e) {
        unsigned short hh = bf16_rne(av[e]);
        hseg[e] = (short)hh;
        lseg[e] = (short)bf16_rne(av[e] - bf16_f32(hh));
      }
      int dst = row * 32 + ((gt ^ ((row >> 1) & 3)) << 3);
      *(short8v*)&Ah[dst] = hseg;
      *(short8v*)&Al[dst] = lseg;
    }
    __syncthreads();

    short8v a_h[4], a_l[4], b_h[4], b_l[4];
    const int hs = lane >> 4;
#pragma unroll
    for (int mi = 0; mi < 4; ++mi) {
      int rr = wm * 64 + mi * 16 + (lane & 15);
      int off = rr * 32 + ((hs ^ ((rr >> 1) & 3)) << 3);
      a_h[mi] = *(const short8v*)&Ah[off];
      a_l[mi] = *(const short8v*)&Al[off];
    }
#pragma unroll
    for (int ni = 0; ni < 4; ++ni) {
      int rc = wn * 64 + ni * 16 + (lane & 15);
      int off = rc * 32 + ((hs ^ ((rc >> 1) & 3)) << 3);
      b_h[ni] = *(const short8v*)&Bh[off];
      b_l[ni] = *(const short8v*)&Bl[off];
    }
#pragma unroll
    for (int mi = 0; mi < 4; ++mi)
#pragma unroll
      for (int ni = 0; ni < 4; ++ni) {
        acc[mi][ni] = __builtin_amdgcn_mfma_f32_16x16x32_bf16(
            a_h[mi], b_h[ni], acc[mi][ni], 0, 0, 0);
        acc[mi][ni] = __builtin_amdgcn_mfma_f32_16x16x32_bf16(
            a_h[mi], b_l[ni], acc[mi][ni], 0, 0, 0);
        acc[mi][ni] = __builtin_amdgcn_mfma_f32_16x16x32_bf16(
            a_l[mi], b_h[ni], acc[mi][ni], 0, 0, 0);
      }
    __syncthreads();
  }

#pragma unroll
  for (int ni = 0; ni < 4; ++ni) {
    int c = col0 + wn * 64 + ni * 16 + (lane & 15);
    int which = c >> 10;
    int jj = c & (D_ - 1);
    int h = jj >> 6, dh = jj & 63;
    float bias = (c < D_) ? bq[c] : bkv[c - D_];
    float* dst = (which == 0) ? Qo : ((which == 1) ? Ko : Vo);
#pragma unroll
    for (int mi = 0; mi < 4; ++mi) {
#pragma unroll
      for (int reg = 0; reg < 4; ++reg) {
        int r = row0 + wm * 64 + mi * 16 + ((lane >> 4) << 2) + reg;
        int b = r >> 11, l = r & (L_ - 1);
        dst[(((size_t)b * H_ + h) * L_ + l) * DH_ + dh] =
            acc[mi][ni][reg] + bias;
      }
    }
    if (which == 2) {
      float s = 0.f;
#pragma unroll
      for (int mi = 0; mi < 4; ++mi)
#pragma unroll
        for (int reg = 0; reg < 4; ++reg) s += acc[mi][ni][reg];
      s += __shfl_xor(s, 16);
      s += __shfl_xor(s, 32);
      if ((lane >> 4) == 0)
        atomicAdd(&vmAcc[(row0 >> 11) * D_ + jj], s + 64.0f * bias);
    }
  }
}

// ---------------------------------------------------------------------------
// Merged kernel A: blocks [0,4096) = sample_m; blocks [4096,4128) = base.
// sample_m block mapping is bh-major-in-low-bits: bh = bid&31, so all 128
// blocks of one bh share bid mod 8 -> same XCD -> its K stays in that L2
// (removes ~8x cross-XCD K re-fetch).
// ---------------------------------------------------------------------------
__global__ __launch_bounds__(256) void sample_base(
    const float* __restrict__ Q, const float* __restrict__ Kt,
    const int* __restrict__ idx, float* __restrict__ Mv,
    const float* __restrict__ vmAcc, const float* __restrict__ Wout,
    const float* __restrict__ bout, float* __restrict__ baseOut,
    float* __restrict__ vmeanM) {
  int t = threadIdx.x;
  if (blockIdx.x < 4096) {
    // ---- sample_m: bh = bid&31, chunk = bid>>5 covers l = chunk*16..+15
    int bh = blockIdx.x & 31;
    int chunk = blockIdx.x >> 5;
    int w = t >> 6, lane = t & 63;
    int subl = lane >> 4, d16 = lane & 15;
    int l = chunk * 16 + w * 4 + subl;
    int gl = bh * L_ + l;
    const float4* Kb4 = (const float4*)(Kt + (size_t)bh * L_ * DH_);
    float4 q4 = ((const float4*)(Q + (size_t)gl * DH_))[d16];
    const int* irow = idx + l * U_;
    float mx = -INFINITY, sm = 0.f;
#pragma unroll 8
    for (int u = 0; u < U_; ++u) {
      int kl = irow[u];
      float4 k4 = Kb4[kl * 16 + d16];
      float p = q4.x * k4.x + q4.y * k4.y + q4.z * k4.z + q4.w * k4.w;
      p += __shfl_xor(p, 1);
      p += __shfl_xor(p, 2);
      p += __shfl_xor(p, 4);
      p += __shfl_xor(p, 8);
      mx = fmaxf(mx, p);
      sm += p;
    }
    if (d16 == 0) Mv[gl] = mx - sm * (1.0f / U_);
  } else {
    // ---- base
    int bid = blockIdx.x - 4096;
    int b = bid >> 4, jc = bid & 15;
    int j = jc * 64 + (t & 63);
    int isl = t >> 6;
    __shared__ float vm[D_];
    __shared__ float red[256];
    for (int i = t; i < D_; i += 256) vm[i] = vmAcc[b * D_ + i] * (1.0f / L_);
    __syncthreads();
    if (jc == 0)
      for (int i = t; i < D_; i += 256) vmeanM[b * D_ + i] = vm[i];
    float s = 0.f;
    const float* wr = Wout + (size_t)j * D_ + isl * 256;
    const float* vv = vm + isl * 256;
    for (int i = 0; i < 256; i += 4) {
      float4 w = *(const float4*)(wr + i);
      s += vv[i] * w.x + vv[i + 1] * w.y + vv[i + 2] * w.z + vv[i + 3] * w.w;
    }
    red[t] = s;
    __syncthreads();
    if (isl == 0)
      baseOut[b * D_ + j] =
          red[t] + red[t + 64] + red[t + 128] + red[t + 192] + bout[j];
  }
}

// ---------------------------------------------------------------------------
// Merged kernel B: blocks [0,4096) = bcast_out (covers all B*L*D);
// blocks [4096,4128) = topk (one bh each, 4 redundant waves).
// ---------------------------------------------------------------------------
__global__ __launch_bounds__(256) void bcast_topk(
    const float* __restrict__ baseIn, float* __restrict__ out,
    const float* __restrict__ Mv, int* __restrict__ topIdx) {
  int t = threadIdx.x;
  if (blockIdx.x < 4096) {
    size_t i4 = (size_t)blockIdx.x * 256 + t;
    size_t i = i4 * 4;
    int b = (int)(i >> 21);
    int col = (int)(i & (D_ - 1));
    *(float4*)(out + i) = *(const float4*)(baseIn + b * D_ + col);
  } else {
    __shared__ float vals[L_];
    int lane = t & 63;
    int bh = blockIdx.x - 4096;
    for (int j = t; j < L_; j += 256) vals[j] = Mv[(size_t)bh * L_ + j];
    __syncthreads();
    for (int it = 0; it < U_; ++it) {
      float bv = -INFINITY;
      int bi = 0x7fffffff;
      for (int j = 0; j < 32; ++j) {
        int i = j * 64 + lane;
        float v = vals[i];
        if (v > bv) { bv = v; bi = i; }
      }
#pragma unroll
      for (int off = 32; off > 0; off >>= 1) {
        float ov = __shfl_xor(bv, off);
        int oi = __shfl_xor(bi, off);
        if (ov > bv || (ov == bv && oi < bi)) { bv = ov; bi = oi; }
      }
      if (t == 0) topIdx[bh * U_ + it] = bi;
      vals[bi] = -INFINITY;  // all waves compute identical bi
      __syncthreads();
    }
  }
}

// ---------------------------------------------------------------------------
// Fused attention + output correction. Grid (32, 8): blockIdx.x = bh so the
// 8 qc-blocks of one bh share bid mod 8 -> same XCD -> K+V (1 MB/bh) is
// fetched from HBM once per XCD instead of 8x.
// ---------------------------------------------------------------------------
__global__ __launch_bounds__(256) void attn_corr(
    const float* __restrict__ Q, const float* __restrict__ Kt,
    const float* __restrict__ Vt, const int* __restrict__ topIdx,
    const float* __restrict__ vmeanM, const float* __restrict__ Wout,
    float* __restrict__ out) {
  int bh = blockIdx.x;  // 0..31
  int qc = blockIdx.y;  // 0..7 (5 queries each)
  int b = bh >> 4, h = bh & (H_ - 1);
  __shared__ float Qs[5][DH_];
  __shared__ float Sv[5][L_];
  __shared__ float part[4][5][DH_];
  __shared__ float inv[5];
  __shared__ float dv[5][DH_];
  __shared__ int lq[5];
  int t = threadIdx.x;
  int lane = t & 63, w = t >> 6;

  if (t < 80) {
    int q = t >> 4, c4 = t & 15;
    int ql = topIdx[bh * U_ + qc * 5 + q];
    *(float4*)&Qs[q][c4 * 4] =
        *(const float4*)&Q[((size_t)bh * L_ + ql) * DH_ + c4 * 4];
  }
  if (t < 5) lq[t] = topIdx[bh * U_ + qc * 5 + t];
  __syncthreads();

  const float* Kb = Kt + (size_t)bh * L_ * DH_;
  for (int kc = 0; kc < 8; ++kc) {
    int key = kc * 256 + t;
    const float* kr = Kb + (size_t)key * DH_;
    float acc[5];
#pragma unroll
    for (int q = 0; q < 5; ++q) acc[q] = 0.f;
#pragma unroll
    for (int i4 = 0; i4 < 16; ++i4) {
      float4 k4 = *(const float4*)(kr + i4 * 4);
#pragma unroll
      for (int q = 0; q < 5; ++q) {
        float4 qv = *(const float4*)&Qs[q][i4 * 4];
        acc[q] += k4.x * qv.x + k4.y * qv.y + k4.z * qv.z + k4.w * qv.w;
      }
    }
#pragma unroll
    for (int q = 0; q < 5; ++q) Sv[q][key] = acc[q] * SCALE_;
  }
  __syncthreads();

#pragma unroll
  for (int rep = 0; rep < 2; ++rep) {
    int r = (rep == 0) ? w : (w == 0 ? 4 : -1);
    if (r >= 0) {
      float mx = -INFINITY;
      for (int j = 0; j < 32; ++j) mx = fmaxf(mx, Sv[r][j * 64 + lane]);
#pragma unroll
      for (int off = 1; off < 64; off <<= 1)
        mx = fmaxf(mx, __shfl_xor(mx, off));
      float sm = 0.f;
      for (int j = 0; j < 32; ++j) {
        float e = __expf(Sv[r][j * 64 + lane] - mx);
        Sv[r][j * 64 + lane] = e;
        sm += e;
      }
#pragma unroll
      for (int off = 1; off < 64; off <<= 1) sm += __shfl_xor(sm, off);
      if (lane == 0) inv[r] = 1.0f / sm;
    }
  }
  __syncthreads();

  {
    const float* vb = Vt + ((size_t)bh * L_ + w * 512) * DH_ + lane;
    float acc[5];
#pragma unroll
    for (int q = 0; q < 5; ++q) acc[q] = 0.f;
    for (int k4 = 0; k4 < 128; ++k4) {
      float v0 = vb[(k4 * 4 + 0) * DH_];
      float v1 = vb[(k4 * 4 + 1) * DH_];
      float v2 = vb[(k4 * 4 + 2) * DH_];
      float v3 = vb[(k4 * 4 + 3) * DH_];
      int k = w * 512 + k4 * 4;
#pragma unroll
      for (int q = 0; q < 5; ++q) {
        float4 p4 = *(const float4*)&Sv[q][k];
        acc[q] += p4.x * v0 + p4.y * v1 + p4.z * v2 + p4.w * v3;
      }
    }
#pragma unroll
    for (int q = 0; q < 5; ++q) part[w][q][lane] = acc[q];
  }
  __syncthreads();

  for (int o = t; o < 5 * DH_; o += 256) {
    int q = o >> 6, dh = o & 63;
    float s = (part[0][q][dh] + part[1][q][dh]) +
              (part[2][q][dh] + part[3][q][dh]);
    dv[q][dh] = s * inv[q] - vmeanM[b * D_ + h * DH_ + dh];
  }
  __syncthreads();

  int sub = t & 3;
  int jbase = t >> 2;
#pragma unroll
  for (int jc = 0; jc < 16; ++jc) {
    int j = jc * 64 + jbase;
    const float* wr = Wout + (size_t)j * D_ + h * DH_ + sub * 16;
    float4 w0 = ((const float4*)wr)[0];
    float4 w1 = ((const float4*)wr)[1];
    float4 w2 = ((const float4*)wr)[2];
    float4 w3 = ((const float4*)wr)[3];
#pragma unroll
    for (int q = 0; q < 5; ++q) {
      const float* dq = &dv[q][sub * 16];
      float s = dq[0] * w0.x + dq[1] * w0.y + dq[2] * w0.z + dq[3] * w0.w +
                dq[4] * w1.x + dq[5] * w1.y + dq[6] * w1.z + dq[7] * w1.w +
                dq[8] * w2.x + dq[9] * w2.y + dq[10] * w2.z + dq[11] * w2.w +
                dq[12] * w3.x + dq[13] * w3.y + dq[14] * w3.z + dq[15] * w3.w;
      s += __shfl_xor(s, 1);
      s += __shfl_xor(s, 2);
      if (sub == 0)
        atomicAdd(out + ((size_t)b * L_ + lq[q]) * D_ + j, s);
    }
  }
}

// ---------------------------------------------------------------------------
extern "C" void kernel_launch(void* const* d_in, const int* in_sizes, int n_in,
                              void* d_out, int out_size, void* d_ws,
                              size_t ws_size, hipStream_t stream) {
  const float* x    = (const float*)d_in[0];
  const float* Wq   = (const float*)d_in[1];
  const float* bq   = (const float*)d_in[2];
  const float* Wkv  = (const float*)d_in[3];
  const float* bkv  = (const float*)d_in[4];
  const float* Wout = (const float*)d_in[5];
  const float* bout = (const float*)d_in[6];
  const int*   idx  = (const int*)d_in[7];
  float* out = (float*)d_out;

  float* ws = (float*)d_ws;
  const size_t NQ = (size_t)B_ * H_ * L_ * DH_;  // 4,194,304 floats
  float* Q  = ws;
  float* Kt = Q + NQ;
  float* Vt = Kt + NQ;
  // W/X split region (live only through the GEMM)
  unsigned short* Whi = (unsigned short*)(Vt + NQ);  // 6 MB
  unsigned short* Wlo = Whi + (size_t)3 * D_ * D_;   // 6 MB
  unsigned short* Xhi = Wlo + (size_t)3 * D_ * D_;   // 8 MB (optional)
  unsigned short* Xlo = Xhi + NQ;                    // 8 MB (optional)
  // phase-2 region (overlaps split region; used only after the GEMM)
  float* Mv     = Vt + NQ;                           // 256 KB
  float* vmeanM = Mv + (size_t)B_ * H_ * L_;         // 8 KB
  float* baseB  = vmeanM + B_ * D_;                  // 8 KB
  int*   topIdx = (int*)(baseB + B_ * D_);           // 5 KB
  // vmean accumulator lives in d_out[0:2048].
  float* vmAcc = out;

  const bool xsplit = ws_size >= ((size_t)76 << 20);
  const int nW = 3 * D_ * D_ / 4;
  const int nX = (int)(NQ / 4);

  if (xsplit) {
    split_all<<<dim3((nW + nX) / 256), dim3(256), 0, stream>>>(
        Wq, Wkv, x, Whi, Wlo, Xhi, Xlo, vmAcc, nW);
    gemm_qkv_16w<<<dim3(3 * D_ / 192, B_ * L_ / 256), dim3(1024), 0,
                   stream>>>(Xhi, Xlo, Whi, Wlo, bq, bkv, Q, Kt, Vt, vmAcc);
  } else {
    split_all<<<dim3(nW / 256), dim3(256), 0, stream>>>(Wq, Wkv, x, Whi, Wlo,
                                                        Xhi, Xlo, vmAcc, nW);
    gemm_qkv_fallback<<<dim3(3 * D_ / 128, B_ * L_ / 128), dim3(256), 0,
                        stream>>>(x, Whi, Wlo, bq, bkv, Q, Kt, Vt, vmAcc);
  }
  sample_base<<<dim3(4096 + B_ * 16), dim3(256), 0, stream>>>(
      Q, Kt, idx, Mv, vmAcc, Wout, bout, baseB, vmeanM);
  bcast_topk<<<dim3(4096 + B_ * H_), dim3(256), 0, stream>>>(baseB, out, Mv,
                                                             topIdx);
  attn_corr<<<dim3(32, 8), dim3(256), 0, stream>>>(Q, Kt, Vt, topIdx, vmeanM,
                                                   Wout, out);
}